// Round 3
// baseline (902.572 us; speedup 1.0000x reference)
//
#include <hip/hip_runtime.h>
#include <math.h>

// ---------------------------------------------------------------------------
// Aggre_social on MI355X — round 3: wave-per-instance, zero-barrier core,
// fused uA1/hI2/final. Sizes: NU=NI=50000, NR=5, D=64, B=512, LS=32, LI=64.
// ---------------------------------------------------------------------------

#define NII 50000
#define BB 512
#define LSS 32
#define NT 16896   // 512 self + 16384 neighbor instances

static __device__ __forceinline__ bool mread(const void* p, long i, int mode) {
  if (mode == 0) return ((const int*)p)[i] != 0;       // int32 storage
  if (mode == 2) return ((const float*)p)[i] != 0.0f;  // f32 storage
  return ((const unsigned char*)p)[i] != 0;            // byte storage
}

static __device__ __forceinline__ float wsum(float v) {
#pragma unroll
  for (int s = 1; s < 64; s <<= 1) v += __shfl_xor(v, s);
  return v;
}
static __device__ __forceinline__ float wmax(float v) {
#pragma unroll
  for (int s = 1; s < 64; s <<= 1) v = fmaxf(v, __shfl_xor(v, s));
  return v;
}

// Intra-wave LDS write->read fence (cross-lane data exchange within a wave).
static __device__ __forceinline__ void wave_fence() {
  asm volatile("s_waitcnt lgkmcnt(0)" ::: "memory");
  __builtin_amdgcn_sched_barrier(0);
}

// ---------------------------------------------------------------------------
// K0: detect boolean-mask storage. flag: 0=int32, 1=byte, 2=float32.
// ---------------------------------------------------------------------------
__global__ void detect_mask_kernel(const unsigned int* __restrict__ sm,
                                   int* __restrict__ flag) {
  __shared__ int notInt, notFloat;
  if (threadIdx.x == 0) { notInt = 0; notFloat = 0; }
  __syncthreads();
  int ni = 0, nf = 0;
  for (int i = threadIdx.x; i < 4096; i += 256) {
    unsigned int x = sm[i];
    if (x > 1u) ni = 1;
    if (x != 0u && x != 0x3F800000u) nf = 1;
  }
  if (ni) atomicOr(&notInt, 1);
  if (nf) atomicOr(&notFloat, 1);
  __syncthreads();
  if (threadIdx.x == 0) flag[0] = notInt ? (notFloat ? 1 : 2) : 0;
}

// ---------------------------------------------------------------------------
// K1: RW1g[5][64] = rating_w @ W1[64:128] + i_ln1_b.   <<<1,320>>>
// ---------------------------------------------------------------------------
__global__ void pre_rw_kernel(const float* __restrict__ rating_w,
                              const float* __restrict__ w1,
                              const float* __restrict__ b1,
                              float* __restrict__ RW1g) {
  const int r = threadIdx.x >> 6;
  const int c = threadIdx.x & 63;
  float acc = b1[c];
  for (int k = 0; k < 64; ++k)
    acc = fmaf(rating_w[r * 64 + k], w1[(64 + k) * 64 + c], acc);
  RW1g[r * 64 + c] = acc;
}

// ---------------------------------------------------------------------------
// K2: xbase[50000][64] = item_w @ W1[0:64]  (weights LDS-staged).
// ---------------------------------------------------------------------------
__global__ __launch_bounds__(256, 2)
void pre_xbase_kernel(const float* __restrict__ item_w,
                      const float* __restrict__ w1,
                      float* __restrict__ xbase) {
  __shared__ float sW[64][64];
  __shared__ float sT[32][64];
  const int tid = threadIdx.x, lane = tid & 63, w = tid >> 6;
  for (int i = tid; i < 4096; i += 256) sW[i >> 6][i & 63] = w1[i];
  const long r0 = (long)blockIdx.x * 32;
  for (int i = tid; i < 2048; i += 256) {
    int r = i >> 6, c = i & 63;
    long gr = r0 + r;
    sT[r][c] = (gr < NII) ? item_w[gr * 64 + c] : 0.0f;
  }
  __syncthreads();
  float acc[8];
#pragma unroll
  for (int r = 0; r < 8; ++r) acc[r] = 0.0f;
  for (int k = 0; k < 64; k += 4) {
    float wv0 = sW[k][lane], wv1 = sW[k + 1][lane];
    float wv2 = sW[k + 2][lane], wv3 = sW[k + 3][lane];
#pragma unroll
    for (int r = 0; r < 8; ++r) {
      const float4 xv = *(const float4*)(&sT[w * 8 + r][k]);
      acc[r] = fmaf(xv.x, wv0, acc[r]);
      acc[r] = fmaf(xv.y, wv1, acc[r]);
      acc[r] = fmaf(xv.z, wv2, acc[r]);
      acc[r] = fmaf(xv.w, wv3, acc[r]);
    }
  }
#pragma unroll
  for (int r = 0; r < 8; ++r) {
    long gr = r0 + w * 8 + r;
    if (gr < NII) xbase[gr * 64 + lane] = acc[r];
  }
}

// ---------------------------------------------------------------------------
// K3: compact active instance list.  <<<66,256>>>
// ---------------------------------------------------------------------------
__global__ void build_active_kernel(const int* __restrict__ nodes,
                                    const int* __restrict__ social_hist,
                                    const void* __restrict__ social_mask,
                                    const int* __restrict__ flagp,
                                    int* __restrict__ counter,
                                    int* __restrict__ list,
                                    int* __restrict__ aUid) {
  const int t = blockIdx.x * 256 + threadIdx.x;
  if (t >= NT) return;
  const int mode = flagp[0];
  int uid;
  bool active;
  if (t < BB) {
    active = true;
    uid = nodes[t];
  } else {
    int nb = t - BB;
    int b = nb >> 5, l = nb & 31;
    long mi = (long)nodes[b] * LSS + l;
    active = mread(social_mask, mi, mode);
    uid = active ? social_hist[mi] : 0;
  }
  if (active) {
    int pos = atomicAdd(counter, 1);
    list[pos] = t;
    aUid[pos] = uid;
  }
}

// ---------------------------------------------------------------------------
// K4: CORE — wave-per-instance item_final (fused uA1 + attention + hI2 +
// final MLP). 512 threads = 8 independent waves. No __syncthreads in the
// instance loop; intra-wave LDS exchange uses wave_fence().
// LDS: 32KB shared weights + 2.3KB/wave scratch  => ~52.5KB -> 3 blocks/CU.
// ---------------------------------------------------------------------------
__global__ __launch_bounds__(512, 4)
void core_kernel(const float* __restrict__ user_w,
                 const float* __restrict__ xbase,
                 const float* __restrict__ RW1g,
                 const float* __restrict__ A1w, const float* __restrict__ A1b,
                 const float* __restrict__ A2w, const float* __restrict__ A2b,
                 const float* __restrict__ A3w, const float* __restrict__ A3b,
                 const float* __restrict__ W2w, const float* __restrict__ W2b,
                 const float* __restrict__ W3w, const float* __restrict__ W3b,
                 const int* __restrict__ item_hist,
                 const int* __restrict__ rating_hist,
                 const void* __restrict__ item_mask,
                 const int* __restrict__ flagp,
                 const int* __restrict__ list,
                 const int* __restrict__ aUid,
                 const int* __restrict__ nActp,
                 float* __restrict__ hIbuf) {
  __shared__ float sA1a[64][64];      // i_att1_w rows 0..63 (x-part)
  __shared__ float sA2[64][64];       // i_att2_w
  __shared__ float wbuf[8][8][64];    // per-wave x / h1 / vec scratch
  __shared__ int cidx[8][64];         // per-wave packed (item<<3)|rating
  __shared__ float sA1bias[64], sA2b[64], sA3w[64], sLn2b[64], sLn3b[64];
  __shared__ float sA3b_s;

  const int tid = threadIdx.x, lane = tid & 63, w = tid >> 6;
  const int mode = flagp[0];
  const int nA = nActp[0];

  for (int i = tid; i < 4096; i += 512) {
    sA1a[i >> 6][i & 63] = A1w[i];
    sA2[i >> 6][i & 63] = A2w[i];
  }
  if (tid < 64) {
    sA1bias[tid] = A1b[tid];
    sA2b[tid] = A2b[tid];
    sA3w[tid] = A3w[tid];
    sLn2b[tid] = W2b[tid];
    sLn3b[tid] = W3b[tid];
  }
  if (tid == 0) sA3b_s = A3b[0];
  __syncthreads();   // the only block-wide barrier

  float* xw = &wbuf[w][0][0];
  int* cw = &cidx[w][0];
  const float a3w_l = sA3w[lane];
  const float a2b_l = sA2b[lane];
  const int stride = gridDim.x * 8;

  for (int iw = blockIdx.x * 8 + w; iw < nA; iw += stride) {
    const long uid = aUid[iw];
    const int inst = list[iw];

    // ---- compact item history (lane covers LI=64) ----
    const long mbase = uid * 64;
    bool m = mread(item_mask, mbase + lane, mode);
    unsigned long long bal = __ballot(m);
    const int nact = (int)__popcll(bal);
    int pos = (int)__popcll(bal & ((1ull << lane) - 1ull));
    if (m) cw[pos] = (item_hist[mbase + lane] << 3) | rating_hist[mbase + lane];

    // ---- u and uA1 = u @ A1w[64:128] + A1b ----
    const float ureg = user_w[uid * 64 + lane];
    xw[lane] = ureg;
    wave_fence();
    float uA1 = sA1bias[lane];
#pragma unroll
    for (int kg = 0; kg < 16; ++kg) {
      const float4 uv = *(const float4*)(xw + kg * 4);
      uA1 = fmaf(uv.x, A1w[(64 + kg * 4 + 0) * 64 + lane], uA1);
      uA1 = fmaf(uv.y, A1w[(64 + kg * 4 + 1) * 64 + lane], uA1);
      uA1 = fmaf(uv.z, A1w[(64 + kg * 4 + 2) * 64 + lane], uA1);
      uA1 = fmaf(uv.w, A1w[(64 + kg * 4 + 3) * 64 + lane], uA1);
    }

    // ---- attention rows in groups of 8 ----
    float lgreg = -1e30f;
    const int ng = (nact + 7) >> 3;
    for (int g = 0; g < ng; ++g) {
      wave_fence();  // prior xw reads complete before overwrite
#pragma unroll
      for (int r = 0; r < 8; ++r) {
        int j = g * 8 + r;
        int jj = (j < nact) ? j : (nact - 1);
        int p = cw[jj];
        int it = p >> 3, rt = p & 7;
        float xv = xbase[(long)it * 64 + lane] + RW1g[rt * 64 + lane];
        xw[r * 64 + lane] = fmaxf(xv, 0.0f);
      }
      wave_fence();
      // att1: h1 = relu(x @ A1a + uA1)
      float acc[8];
#pragma unroll
      for (int r = 0; r < 8; ++r) acc[r] = uA1;
#pragma unroll
      for (int kg = 0; kg < 16; ++kg) {
        const float w0 = sA1a[kg * 4 + 0][lane];
        const float w1 = sA1a[kg * 4 + 1][lane];
        const float w2 = sA1a[kg * 4 + 2][lane];
        const float w3 = sA1a[kg * 4 + 3][lane];
#pragma unroll
        for (int r = 0; r < 8; ++r) {
          const float4 xv = *(const float4*)(xw + r * 64 + kg * 4);
          acc[r] = fmaf(xv.x, w0, acc[r]);
          acc[r] = fmaf(xv.y, w1, acc[r]);
          acc[r] = fmaf(xv.z, w2, acc[r]);
          acc[r] = fmaf(xv.w, w3, acc[r]);
        }
      }
      wave_fence();  // att1 reads complete before h1 overwrite
#pragma unroll
      for (int r = 0; r < 8; ++r) xw[r * 64 + lane] = fmaxf(acc[r], 0.0f);
      wave_fence();
      // att2 + logit: h2 = relu(h1 @ A2 + b2); logit = h2 . a3 + b3
      float acc2[8];
#pragma unroll
      for (int r = 0; r < 8; ++r) acc2[r] = a2b_l;
#pragma unroll
      for (int kg = 0; kg < 16; ++kg) {
        const float w0 = sA2[kg * 4 + 0][lane];
        const float w1 = sA2[kg * 4 + 1][lane];
        const float w2 = sA2[kg * 4 + 2][lane];
        const float w3 = sA2[kg * 4 + 3][lane];
#pragma unroll
        for (int r = 0; r < 8; ++r) {
          const float4 hv = *(const float4*)(xw + r * 64 + kg * 4);
          acc2[r] = fmaf(hv.x, w0, acc2[r]);
          acc2[r] = fmaf(hv.y, w1, acc2[r]);
          acc2[r] = fmaf(hv.z, w2, acc2[r]);
          acc2[r] = fmaf(hv.w, w3, acc2[r]);
        }
      }
#pragma unroll
      for (int r = 0; r < 8; ++r) {
        int j = g * 8 + r;
        float t = fmaxf(acc2[r], 0.0f) * a3w_l;
        t = wsum(t);
        if (lane == j && j < nact) lgreg = t + sA3b_s;
      }
    }

    // ---- softmax over lanes (lane j holds logit_j) ----
    const bool valid = (lane < nact);
    float lv = valid ? lgreg : -1e30f;
    float mx = wmax(lv);
    float e = valid ? __expf(lv - mx) : 0.0f;
    float s = wsum(e);
    const float alpha = e / s;

    // ---- hI = sum_j alpha_j * x_j  (re-gather x) ----
    float hi = 0.0f;
    for (int j = 0; j < nact; ++j) {
      float aj = __shfl(alpha, j);
      int p = cw[j];
      int it = p >> 3, rt = p & 7;
      float xv = fmaxf(xbase[(long)it * 64 + lane] + RW1g[rt * 64 + lane], 0.0f);
      hi = fmaf(aj, xv, hi);
    }

    // ---- hI2 = relu(hI @ i_ln2 + b) ----
    wave_fence();
    xw[lane] = hi;
    wave_fence();
    float acc3 = sLn2b[lane];
#pragma unroll
    for (int kg = 0; kg < 16; ++kg) {
      const float4 hv = *(const float4*)(xw + kg * 4);
      acc3 = fmaf(hv.x, W2w[(kg * 4 + 0) * 64 + lane], acc3);
      acc3 = fmaf(hv.y, W2w[(kg * 4 + 1) * 64 + lane], acc3);
      acc3 = fmaf(hv.z, W2w[(kg * 4 + 2) * 64 + lane], acc3);
      acc3 = fmaf(hv.w, W2w[(kg * 4 + 3) * 64 + lane], acc3);
    }
    const float hI2 = fmaxf(acc3, 0.0f);

    // ---- out = relu([u ; hI2] @ i_ln3 + b) ----
    wave_fence();
    xw[lane] = ureg;
    xw[64 + lane] = hI2;
    wave_fence();
    float acc4 = sLn3b[lane];
#pragma unroll
    for (int kg = 0; kg < 32; ++kg) {
      const float4 xv = *(const float4*)(xw + kg * 4);
      acc4 = fmaf(xv.x, W3w[(kg * 4 + 0) * 64 + lane], acc4);
      acc4 = fmaf(xv.y, W3w[(kg * 4 + 1) * 64 + lane], acc4);
      acc4 = fmaf(xv.z, W3w[(kg * 4 + 2) * 64 + lane], acc4);
      acc4 = fmaf(xv.w, W3w[(kg * 4 + 3) * 64 + lane], acc4);
    }
    hIbuf[(long)inst * 64 + lane] = fmaxf(acc4, 0.0f);
  }
}

// ---------------------------------------------------------------------------
// K5: social aggregation + final MLP. One block per batch element.
// ---------------------------------------------------------------------------
__global__ __launch_bounds__(256, 2)
void social_kernel(const float* __restrict__ user_w,
                   const float* __restrict__ hIbuf,
                   const float* __restrict__ A1w, const float* __restrict__ A1b,
                   const float* __restrict__ A2w, const float* __restrict__ A2b,
                   const float* __restrict__ A3w, const float* __restrict__ A3b,
                   const float* __restrict__ L1w, const float* __restrict__ L1b,
                   const float* __restrict__ L2w, const float* __restrict__ L2b,
                   const float* __restrict__ L3w, const float* __restrict__ L3b,
                   const int* __restrict__ nodes,
                   const void* __restrict__ social_mask,
                   const int* __restrict__ flagp,
                   float* __restrict__ out) {
  __shared__ float sA1a[64][64], sA2[64][64];
  __shared__ float hv[32][64];
  __shared__ float h1w[4][8][64];
  __shared__ float uvec[64], uA1[64], selfv[64], vecA[64], vecB[64];
  __shared__ float red[4][64], logit[32], alpha[32];
  __shared__ float sA2b[64], sA3w[64];
  __shared__ float sA3b;
  __shared__ int cslot[32], nval_s;
  const int tid = threadIdx.x, lane = tid & 63, w = tid >> 6;
  const int mode = flagp[0];
  const int b = blockIdx.x;
  const long uid = nodes[b];

  for (int i = tid; i < 4096; i += 256) {
    sA1a[i >> 6][i & 63] = A1w[i];
    sA2[i >> 6][i & 63] = A2w[i];
  }
  if (tid == 0) sA3b = A3b[0];
  if (w == 0) {
    bool m = false;
    if (lane < 32) m = mread(social_mask, uid * LSS + lane, mode);
    unsigned long long bal = __ballot(m);
    int pos = __popcll(bal & ((1ull << lane) - 1ull));
    if (m) cslot[pos] = lane;
    if (lane == 0) nval_s = (int)__popcll(bal);
  } else if (w == 1) {
    uvec[lane] = user_w[uid * 64 + lane];
    sA2b[lane] = A2b[lane];
  } else if (w == 2) {
    selfv[lane] = hIbuf[(long)b * 64 + lane];
    sA3w[lane] = A3w[lane];
  }
  __syncthreads();
  const int nval = nval_s;

  {
    float acc = 0.0f;
#pragma unroll
    for (int kk = 0; kk < 16; ++kk) {
      int k = w * 16 + kk;
      acc = fmaf(uvec[k], A1w[(64 + k) * 64 + lane], acc);
    }
    red[w][lane] = acc;
  }
  for (int j = w; j < nval; j += 4)
    hv[j][lane] = hIbuf[(512L + (long)b * 32 + cslot[j]) * 64 + lane];
  __syncthreads();
  if (tid < 64)
    uA1[tid] = red[0][tid] + red[1][tid] + red[2][tid] + red[3][tid] + A1b[tid];
  __syncthreads();

  {
    const float base = uA1[lane];
    float acc[8];
#pragma unroll
    for (int r = 0; r < 8; ++r) acc[r] = base;
    for (int k = 0; k < 64; k += 4) {
      float wv0 = sA1a[k][lane], wv1 = sA1a[k + 1][lane];
      float wv2 = sA1a[k + 2][lane], wv3 = sA1a[k + 3][lane];
#pragma unroll
      for (int r = 0; r < 8; ++r) {
        const float4 xv = *(const float4*)(&hv[w * 8 + r][k]);
        acc[r] = fmaf(xv.x, wv0, acc[r]);
        acc[r] = fmaf(xv.y, wv1, acc[r]);
        acc[r] = fmaf(xv.z, wv2, acc[r]);
        acc[r] = fmaf(xv.w, wv3, acc[r]);
      }
    }
#pragma unroll
    for (int r = 0; r < 8; ++r) h1w[w][r][lane] = fmaxf(acc[r], 0.0f);
  }
  __syncthreads();

  {
    float acc2[8];
#pragma unroll
    for (int r = 0; r < 8; ++r) acc2[r] = sA2b[lane];
    for (int k = 0; k < 64; k += 4) {
      float wv0 = sA2[k][lane], wv1 = sA2[k + 1][lane];
      float wv2 = sA2[k + 2][lane], wv3 = sA2[k + 3][lane];
#pragma unroll
      for (int r = 0; r < 8; ++r) {
        const float4 hvv = *(const float4*)(&h1w[w][r][k]);
        acc2[r] = fmaf(hvv.x, wv0, acc2[r]);
        acc2[r] = fmaf(hvv.y, wv1, acc2[r]);
        acc2[r] = fmaf(hvv.z, wv2, acc2[r]);
        acc2[r] = fmaf(hvv.w, wv3, acc2[r]);
      }
    }
#pragma unroll
    for (int r = 0; r < 8; ++r) {
      int j = w * 8 + r;
      float p = fmaxf(acc2[r], 0.0f) * sA3w[lane];
      p = wsum(p);
      if (lane == 0 && j < nval) logit[j] = p + sA3b;
    }
  }
  __syncthreads();

  if (w == 0) {
    float lv = (lane < nval) ? logit[lane] : -1e30f;
    float mx = wmax(lv);
    float e = (lane < nval) ? __expf(lv - mx) : 0.0f;
    float s = wsum(e);
    if (lane < 32) alpha[lane] = e / s;
  }
  __syncthreads();

  {
    float acc = 0.0f;
    for (int j = w; j < nval; j += 4) acc = fmaf(alpha[j], hv[j][lane], acc);
    red[w][lane] = acc;
  }
  __syncthreads();
  if (tid < 64) vecA[tid] = red[0][tid] + red[1][tid] + red[2][tid] + red[3][tid];
  __syncthreads();

  {
    float acc = 0.0f;
#pragma unroll
    for (int kk = 0; kk < 16; ++kk) {
      int k = w * 16 + kk;
      acc = fmaf(vecA[k], L1w[k * 64 + lane], acc);
    }
    red[w][lane] = acc;
  }
  __syncthreads();
  if (tid < 64)
    vecB[tid] = fmaxf(red[0][tid] + red[1][tid] + red[2][tid] + red[3][tid] + L1b[tid], 0.0f);
  __syncthreads();

  {
    float acc = 0.0f;
#pragma unroll
    for (int kk = 0; kk < 32; ++kk) {
      int k = w * 32 + kk;
      float xv = (k < 64) ? selfv[k] : vecB[k - 64];
      acc = fmaf(xv, L2w[k * 64 + lane], acc);
    }
    red[w][lane] = acc;
  }
  __syncthreads();
  if (tid < 64)
    vecA[tid] = fmaxf(red[0][tid] + red[1][tid] + red[2][tid] + red[3][tid] + L2b[tid], 0.0f);
  __syncthreads();

  {
    float acc = 0.0f;
#pragma unroll
    for (int kk = 0; kk < 16; ++kk) {
      int k = w * 16 + kk;
      acc = fmaf(vecA[k], L3w[k * 64 + lane], acc);
    }
    red[w][lane] = acc;
  }
  __syncthreads();
  if (tid < 64)
    out[(long)b * 64 + tid] =
        fmaxf(red[0][tid] + red[1][tid] + red[2][tid] + red[3][tid] + L3b[tid], 0.0f);
}

// ---------------------------------------------------------------------------
extern "C" void kernel_launch(void* const* d_in, const int* in_sizes, int n_in,
                              void* d_out, int out_size, void* d_ws, size_t ws_size,
                              hipStream_t stream) {
  const float* user_w   = (const float*)d_in[0];
  const float* item_w   = (const float*)d_in[1];
  const float* rating_w = (const float*)d_in[2];
  const float* i_ln1_w  = (const float*)d_in[3];
  const float* i_ln1_b  = (const float*)d_in[4];
  const float* i_ln2_w  = (const float*)d_in[5];
  const float* i_ln2_b  = (const float*)d_in[6];
  const float* i_ln3_w  = (const float*)d_in[7];
  const float* i_ln3_b  = (const float*)d_in[8];
  const float* i_att1_w = (const float*)d_in[9];
  const float* i_att1_b = (const float*)d_in[10];
  const float* i_att2_w = (const float*)d_in[11];
  const float* i_att2_b = (const float*)d_in[12];
  const float* i_att3_w = (const float*)d_in[13];
  const float* i_att3_b = (const float*)d_in[14];
  const float* s_ln1_w  = (const float*)d_in[15];
  const float* s_ln1_b  = (const float*)d_in[16];
  const float* s_ln2_w  = (const float*)d_in[17];
  const float* s_ln2_b  = (const float*)d_in[18];
  const float* s_ln3_w  = (const float*)d_in[19];
  const float* s_ln3_b  = (const float*)d_in[20];
  const float* s_att1_w = (const float*)d_in[21];
  const float* s_att1_b = (const float*)d_in[22];
  const float* s_att2_w = (const float*)d_in[23];
  const float* s_att2_b = (const float*)d_in[24];
  const float* s_att3_w = (const float*)d_in[25];
  const float* s_att3_b = (const float*)d_in[26];
  const int*  nodes       = (const int*)d_in[27];
  const int*  social_hist = (const int*)d_in[28];
  const void* social_mask = d_in[29];
  const int*  item_hist   = (const int*)d_in[30];
  const int*  rating_hist = (const int*)d_in[31];
  const void* item_mask   = d_in[32];

  // workspace layout (bytes)
  char* ws = (char*)d_ws;
  int*   flag    = (int*)(ws + 0);          // 256
  int*   counter = (int*)(ws + 256);        // 256
  int*   list    = (int*)(ws + 512);        // NT*4 = 67584
  int*   aUid    = (int*)(ws + 68096);      // 67584
  float* hIbuf   = (float*)(ws + 135680);   // NT*64*4 = 4325376
  float* xbase   = (float*)(ws + 4461056);  // 50000*64*4 = 12800000
  float* RW1g    = (float*)(ws + 17261056); // 5*64*4

  hipMemsetAsync(counter, 0, 4, stream);
  detect_mask_kernel<<<1, 256, 0, stream>>>((const unsigned int*)social_mask, flag);
  pre_rw_kernel<<<1, 320, 0, stream>>>(rating_w, i_ln1_w, i_ln1_b, RW1g);
  pre_xbase_kernel<<<(NII + 31) / 32, 256, 0, stream>>>(item_w, i_ln1_w, xbase);
  build_active_kernel<<<NT / 256, 256, 0, stream>>>(
      nodes, social_hist, social_mask, flag, counter, list, aUid);
  core_kernel<<<768, 512, 0, stream>>>(
      user_w, xbase, RW1g,
      i_att1_w, i_att1_b, i_att2_w, i_att2_b, i_att3_w, i_att3_b,
      i_ln2_w, i_ln2_b, i_ln3_w, i_ln3_b,
      item_hist, rating_hist, item_mask, flag, list, aUid, counter, hIbuf);
  social_kernel<<<BB, 256, 0, stream>>>(
      user_w, hIbuf,
      s_att1_w, s_att1_b, s_att2_w, s_att2_b, s_att3_w, s_att3_b,
      s_ln1_w, s_ln1_b, s_ln2_w, s_ln2_b, s_ln3_w, s_ln3_b,
      nodes, social_mask, flag, (float*)d_out);
}

// Round 4
// 399.399 us; speedup vs baseline: 2.2598x; 2.2598x over previous
//
#include <hip/hip_runtime.h>
#include <math.h>

// ---------------------------------------------------------------------------
// Aggre_social on MI355X — round 4: MFMA bf16 attention core (wave-per-
// instance, zero-barrier), f32 value path, batched aux GEMMs.
// Sizes: NU=NI=50000, NR=5, D=64, B=512, LS=32, LI=64.
// ---------------------------------------------------------------------------

#define NII 50000
#define BB 512
#define LSS 32
#define NT 16896   // 512 self + 16384 neighbor instances

typedef short short8 __attribute__((ext_vector_type(8)));
typedef float f32x4 __attribute__((ext_vector_type(4)));

static __device__ __forceinline__ bool mread(const void* p, long i, int mode) {
  if (mode == 0) return ((const int*)p)[i] != 0;       // int32 storage
  if (mode == 2) return ((const float*)p)[i] != 0.0f;  // f32 storage
  return ((const unsigned char*)p)[i] != 0;            // byte storage
}

static __device__ __forceinline__ float wsum(float v) {
#pragma unroll
  for (int s = 1; s < 64; s <<= 1) v += __shfl_xor(v, s);
  return v;
}
static __device__ __forceinline__ float wmax(float v) {
#pragma unroll
  for (int s = 1; s < 64; s <<= 1) v = fmaxf(v, __shfl_xor(v, s));
  return v;
}
static __device__ __forceinline__ float rsum16(float v) {
#pragma unroll
  for (int s = 1; s < 16; s <<= 1) v += __shfl_xor(v, s);
  return v;
}

// f32 -> bf16 (round-to-nearest-even), as raw short.
static __device__ __forceinline__ short bf16rne(float f) {
  unsigned u = __float_as_uint(f);
  u = (u + 0x7FFFu + ((u >> 16) & 1u)) >> 16;
  return (short)u;
}

// Intra-wave LDS write->read fence.
static __device__ __forceinline__ void wave_fence() {
  asm volatile("s_waitcnt lgkmcnt(0)" ::: "memory");
  __builtin_amdgcn_sched_barrier(0);
}

// ---------------------------------------------------------------------------
// K0: detect boolean-mask storage. flag: 0=int32, 1=byte, 2=float32.
// ---------------------------------------------------------------------------
__global__ void detect_mask_kernel(const unsigned int* __restrict__ sm,
                                   int* __restrict__ flag) {
  __shared__ int notInt, notFloat;
  if (threadIdx.x == 0) { notInt = 0; notFloat = 0; }
  __syncthreads();
  int ni = 0, nf = 0;
  for (int i = threadIdx.x; i < 4096; i += 256) {
    unsigned int x = sm[i];
    if (x > 1u) ni = 1;
    if (x != 0u && x != 0x3F800000u) nf = 1;
  }
  if (ni) atomicOr(&notInt, 1);
  if (nf) atomicOr(&notFloat, 1);
  __syncthreads();
  if (threadIdx.x == 0) flag[0] = notInt ? (notFloat ? 1 : 2) : 0;
}

// ---------------------------------------------------------------------------
// K1: RW1g[5][64] = rating_w @ W1[64:128] + i_ln1_b.   <<<1,320>>>
// ---------------------------------------------------------------------------
__global__ void pre_rw_kernel(const float* __restrict__ rating_w,
                              const float* __restrict__ w1,
                              const float* __restrict__ b1,
                              float* __restrict__ RW1g) {
  const int r = threadIdx.x >> 6;
  const int c = threadIdx.x & 63;
  float acc = b1[c];
  for (int k = 0; k < 64; ++k)
    acc = fmaf(rating_w[r * 64 + k], w1[(64 + k) * 64 + c], acc);
  RW1g[r * 64 + c] = acc;
}

// ---------------------------------------------------------------------------
// K1b: pre-pack MFMA B-fragment images (bf16) for A1a (i_att1_w rows 0..63)
// and A2 (i_att2_w). Layout: idx = ((kb*4+nb)*64 + lane)*8 + e, where the
// fragment element is B[k = kb*32 + (lane>>4)*8 + e][col = nb*16 + (lane&15)].
// ---------------------------------------------------------------------------
__global__ void prepack_kernel(const float* __restrict__ A1w,
                               const float* __restrict__ A2w,
                               short* __restrict__ B1,
                               short* __restrict__ B2) {
  for (int idx = threadIdx.x; idx < 4096; idx += 256) {
    int e = idx & 7, g = idx >> 3;
    int l = g & 63, q = g >> 6;          // q = kb*4+nb
    int kb = q >> 2, nb = q & 3;
    int k = kb * 32 + ((l >> 4) & 3) * 8 + e;
    int col = nb * 16 + (l & 15);
    B1[idx] = bf16rne(A1w[k * 64 + col]);
    B2[idx] = bf16rne(A2w[k * 64 + col]);
  }
}

// ---------------------------------------------------------------------------
// K2: xbase[50000][64] = item_w @ W1[0:64]  (weights LDS-staged).
// ---------------------------------------------------------------------------
__global__ __launch_bounds__(256, 2)
void pre_xbase_kernel(const float* __restrict__ item_w,
                      const float* __restrict__ w1,
                      float* __restrict__ xbase) {
  __shared__ float sW[64][64];
  __shared__ float sT[32][64];
  const int tid = threadIdx.x, lane = tid & 63, w = tid >> 6;
  for (int i = tid; i < 4096; i += 256) sW[i >> 6][i & 63] = w1[i];
  const long r0 = (long)blockIdx.x * 32;
  for (int i = tid; i < 2048; i += 256) {
    int r = i >> 6, c = i & 63;
    long gr = r0 + r;
    sT[r][c] = (gr < NII) ? item_w[gr * 64 + c] : 0.0f;
  }
  __syncthreads();
  float acc[8];
#pragma unroll
  for (int r = 0; r < 8; ++r) acc[r] = 0.0f;
  for (int k = 0; k < 64; k += 4) {
    float wv0 = sW[k][lane], wv1 = sW[k + 1][lane];
    float wv2 = sW[k + 2][lane], wv3 = sW[k + 3][lane];
#pragma unroll
    for (int r = 0; r < 8; ++r) {
      const float4 xv = *(const float4*)(&sT[w * 8 + r][k]);
      acc[r] = fmaf(xv.x, wv0, acc[r]);
      acc[r] = fmaf(xv.y, wv1, acc[r]);
      acc[r] = fmaf(xv.z, wv2, acc[r]);
      acc[r] = fmaf(xv.w, wv3, acc[r]);
    }
  }
#pragma unroll
  for (int r = 0; r < 8; ++r) {
    long gr = r0 + w * 8 + r;
    if (gr < NII) xbase[gr * 64 + lane] = acc[r];
  }
}

// ---------------------------------------------------------------------------
// K3: compact active instance list.  <<<66,256>>>
// ---------------------------------------------------------------------------
__global__ void build_active_kernel(const int* __restrict__ nodes,
                                    const int* __restrict__ social_hist,
                                    const void* __restrict__ social_mask,
                                    const int* __restrict__ flagp,
                                    int* __restrict__ counter,
                                    int* __restrict__ list,
                                    int* __restrict__ aUid) {
  const int t = blockIdx.x * 256 + threadIdx.x;
  if (t >= NT) return;
  const int mode = flagp[0];
  int uid;
  bool active;
  if (t < BB) {
    active = true;
    uid = nodes[t];
  } else {
    int nb = t - BB;
    int b = nb >> 5, l = nb & 31;
    long mi = (long)nodes[b] * LSS + l;
    active = mread(social_mask, mi, mode);
    uid = active ? social_hist[mi] : 0;
  }
  if (active) {
    int pos = atomicAdd(counter, 1);
    list[pos] = t;
    aUid[pos] = uid;
  }
}

// ---------------------------------------------------------------------------
// K4: uA1buf[idx] = user_w[aUid[idx]] @ A1w[64:128] + A1b.   64 rows / block.
// ---------------------------------------------------------------------------
__global__ __launch_bounds__(256, 2)
void uA1_kernel(const float* __restrict__ user_w,
                const float* __restrict__ A1w, const float* __restrict__ A1b,
                const int* __restrict__ aUid, const int* __restrict__ nActp,
                float* __restrict__ uA1buf) {
  const int tid = threadIdx.x, lane = tid & 63, w = tid >> 6;
  const int i0 = blockIdx.x * 64;
  const int nA = nActp[0];
  if (i0 >= nA) return;
  __shared__ float sW[64][64], sU[64][64];
  __shared__ float sb[64];
  __shared__ int sUid[64];
  for (int i = tid; i < 4096; i += 256) sW[i >> 6][i & 63] = A1w[4096 + i];
  if (tid < 64) {
    sb[tid] = A1b[tid];
    sUid[tid] = (i0 + tid < nA) ? aUid[i0 + tid] : 0;
  }
  __syncthreads();
  for (int i = tid; i < 4096; i += 256) {
    int r = i >> 6, c = i & 63;
    sU[r][c] = user_w[(long)sUid[r] * 64 + c];
  }
  __syncthreads();
  float acc[16];
#pragma unroll
  for (int r = 0; r < 16; ++r) acc[r] = sb[lane];
  for (int k = 0; k < 64; k += 4) {
    float wv0 = sW[k][lane], wv1 = sW[k + 1][lane];
    float wv2 = sW[k + 2][lane], wv3 = sW[k + 3][lane];
#pragma unroll
    for (int r = 0; r < 16; ++r) {
      const float4 xv = *(const float4*)(&sU[w * 16 + r][k]);
      acc[r] = fmaf(xv.x, wv0, acc[r]);
      acc[r] = fmaf(xv.y, wv1, acc[r]);
      acc[r] = fmaf(xv.z, wv2, acc[r]);
      acc[r] = fmaf(xv.w, wv3, acc[r]);
    }
  }
#pragma unroll
  for (int r = 0; r < 16; ++r) {
    int row = i0 + w * 16 + r;
    if (row < nA) uA1buf[(long)row * 64 + lane] = acc[r];
  }
}

// ---------------------------------------------------------------------------
// K5: CORE — wave-per-instance attention with MFMA bf16 logits.
// 256 threads = 4 independent waves, no __syncthreads at all.
// Per-wave LDS 3KB: H1 round-trip [16][80] bf16 + logits[64] f32 + cw[64].
// ---------------------------------------------------------------------------
__global__ __launch_bounds__(256)
void core_mfma_kernel(const float* __restrict__ xbase,
                      const float* __restrict__ RW1g,
                      const float* __restrict__ uA1buf,
                      const short* __restrict__ Bimg1,
                      const short* __restrict__ Bimg2,
                      const float* __restrict__ A2b,
                      const float* __restrict__ A3w,
                      const int* __restrict__ item_hist,
                      const int* __restrict__ rating_hist,
                      const void* __restrict__ item_mask,
                      const int* __restrict__ flagp,
                      const int* __restrict__ aUid,
                      const int* __restrict__ nActp,
                      float* __restrict__ hvecbuf) {
  __shared__ __align__(16) char smem[4][3072];
  const int tid = threadIdx.x, lane = tid & 63, w = tid >> 6;
  short* h1w = (short*)(smem[w]);          // [16][80] bf16
  float* lgw = (float*)(smem[w] + 2560);   // [64] logits
  int* cw = (int*)(smem[w] + 2816);        // [64] packed (item<<3)|rating

  const int mode = flagp[0];
  const int nA = nActp[0];
  const float a2bv = A2b[lane];
  const float a3v = A3w[lane];
  const int l15 = lane & 15;
  const int lg4 = lane >> 4;

  for (int idx = blockIdx.x * 4 + w; idx < nA; idx += gridDim.x * 4) {
    wave_fence();  // prior-instance LDS reads complete before overwrite
    const long uid = aUid[idx];

    // ---- compact item history (lane covers LI=64) ----
    const long mbase = uid * 64;
    bool m = mread(item_mask, mbase + lane, mode);
    unsigned long long bal = __ballot(m);
    const int nact = (int)__popcll(bal);
    int pos = (int)__popcll(bal & ((1ull << lane) - 1ull));
    if (m) cw[pos] = (item_hist[mbase + lane] << 3) | rating_hist[mbase + lane];
    const float uA1v = uA1buf[(long)idx * 64 + lane];
    wave_fence();

    // ---- logits via MFMA, 16-row chunks ----
    const int ng = (nact + 15) >> 4;
    for (int mc = 0; mc < ng; ++mc) {
      wave_fence();  // prior chunk's H1 reads done before overwrite
      // X A-fragments (2 K-blocks): lane holds row (l&15), k=(l>>4)*8+e
      int row = mc * 16 + l15;
      if (row >= nact) row = nact - 1;
      const int p = cw[row];
      const long it = p >> 3;
      const int rt = p & 7;
      short8 xa[2];
#pragma unroll
      for (int kb = 0; kb < 2; ++kb) {
        const int koff = kb * 32 + lg4 * 8;
        const float* xp = xbase + it * 64 + koff;
        const float* rp = RW1g + rt * 64 + koff;
        const float4 a = *(const float4*)xp;
        const float4 b = *(const float4*)(xp + 4);
        const float4 c = *(const float4*)rp;
        const float4 d = *(const float4*)(rp + 4);
        short8 f;
        f[0] = bf16rne(fmaxf(a.x + c.x, 0.0f));
        f[1] = bf16rne(fmaxf(a.y + c.y, 0.0f));
        f[2] = bf16rne(fmaxf(a.z + c.z, 0.0f));
        f[3] = bf16rne(fmaxf(a.w + c.w, 0.0f));
        f[4] = bf16rne(fmaxf(b.x + d.x, 0.0f));
        f[5] = bf16rne(fmaxf(b.y + d.y, 0.0f));
        f[6] = bf16rne(fmaxf(b.z + d.z, 0.0f));
        f[7] = bf16rne(fmaxf(b.w + d.w, 0.0f));
        xa[kb] = f;
      }
      // att1: H1 = relu(X @ A1a + uA1), one N-block at a time
#pragma unroll
      for (int nb = 0; nb < 4; ++nb) {
        const float ui = __shfl(uA1v, nb * 16 + l15);
        f32x4 acc = {ui, ui, ui, ui};
        acc = __builtin_amdgcn_mfma_f32_16x16x32_bf16(
            xa[0], *(const short8*)(Bimg1 + ((0 * 4 + nb) * 64 + lane) * 8), acc, 0, 0, 0);
        acc = __builtin_amdgcn_mfma_f32_16x16x32_bf16(
            xa[1], *(const short8*)(Bimg1 + ((1 * 4 + nb) * 64 + lane) * 8), acc, 0, 0, 0);
#pragma unroll
        for (int r = 0; r < 4; ++r)
          h1w[(lg4 * 4 + r) * 80 + nb * 16 + l15] = bf16rne(fmaxf(acc[r], 0.0f));
      }
      wave_fence();
      // att2 + logit
      short8 ha[2];
      ha[0] = *(const short8*)(h1w + l15 * 80 + lg4 * 8);
      ha[1] = *(const short8*)(h1w + l15 * 80 + 32 + lg4 * 8);
      float t0 = 0.0f, t1 = 0.0f, t2 = 0.0f, t3 = 0.0f;
#pragma unroll
      for (int nb = 0; nb < 4; ++nb) {
        const float b2 = __shfl(a2bv, nb * 16 + l15);
        f32x4 acc = {b2, b2, b2, b2};
        acc = __builtin_amdgcn_mfma_f32_16x16x32_bf16(
            ha[0], *(const short8*)(Bimg2 + ((0 * 4 + nb) * 64 + lane) * 8), acc, 0, 0, 0);
        acc = __builtin_amdgcn_mfma_f32_16x16x32_bf16(
            ha[1], *(const short8*)(Bimg2 + ((1 * 4 + nb) * 64 + lane) * 8), acc, 0, 0, 0);
        const float a3c = __shfl(a3v, nb * 16 + l15);
        t0 = fmaf(fmaxf(acc[0], 0.0f), a3c, t0);
        t1 = fmaf(fmaxf(acc[1], 0.0f), a3c, t1);
        t2 = fmaf(fmaxf(acc[2], 0.0f), a3c, t2);
        t3 = fmaf(fmaxf(acc[3], 0.0f), a3c, t3);
      }
      t0 = rsum16(t0); t1 = rsum16(t1); t2 = rsum16(t2); t3 = rsum16(t3);
      if (l15 == 0) {
        const int jb = mc * 16 + lg4 * 4;
        lgw[jb + 0] = t0;
        lgw[jb + 1] = t1;
        lgw[jb + 2] = t2;
        lgw[jb + 3] = t3;
      }
    }
    wave_fence();

    // ---- softmax over lanes (lane j holds logit_j; b3 dropped: invariant) ----
    const bool valid = (lane < nact);
    float lv = valid ? lgw[lane] : -1e30f;
    float mx = wmax(lv);
    float e = valid ? __expf(lv - mx) : 0.0f;
    float s = wsum(e);
    const float alpha = e / s;

    // ---- hI = sum_j alpha_j * x_j  (exact f32 re-gather) ----
    float hi = 0.0f;
    for (int j = 0; j < nact; ++j) {
      const float aj = __shfl(alpha, j);
      const int p = cw[j];
      const float xv =
          fmaxf(xbase[(long)(p >> 3) * 64 + lane] + RW1g[(p & 7) * 64 + lane], 0.0f);
      hi = fmaf(aj, xv, hi);
    }
    hvecbuf[(long)idx * 64 + lane] = hi;
  }
}

// ---------------------------------------------------------------------------
// K6: hI2buf[idx] = relu(hvecbuf[idx] @ i_ln2 + b).  64 rows / block.
// ---------------------------------------------------------------------------
__global__ __launch_bounds__(256, 2)
void hI2_kernel(const float* __restrict__ hvecbuf,
                const float* __restrict__ W2w, const float* __restrict__ W2b,
                const int* __restrict__ nActp, float* __restrict__ hI2buf) {
  const int tid = threadIdx.x, lane = tid & 63, w = tid >> 6;
  const int i0 = blockIdx.x * 64;
  const int nA = nActp[0];
  if (i0 >= nA) return;
  __shared__ float sW[64][64], sX[64][64];
  __shared__ float sb[64];
  for (int i = tid; i < 4096; i += 256) sW[i >> 6][i & 63] = W2w[i];
  if (tid < 64) sb[tid] = W2b[tid];
  for (int i = tid; i < 4096; i += 256) {
    int r = i >> 6, c = i & 63;
    sX[r][c] = (i0 + r < nA) ? hvecbuf[(long)(i0 + r) * 64 + c] : 0.0f;
  }
  __syncthreads();
  float acc[16];
#pragma unroll
  for (int r = 0; r < 16; ++r) acc[r] = sb[lane];
  for (int k = 0; k < 64; k += 4) {
    float wv0 = sW[k][lane], wv1 = sW[k + 1][lane];
    float wv2 = sW[k + 2][lane], wv3 = sW[k + 3][lane];
#pragma unroll
    for (int r = 0; r < 16; ++r) {
      const float4 xv = *(const float4*)(&sX[w * 16 + r][k]);
      acc[r] = fmaf(xv.x, wv0, acc[r]);
      acc[r] = fmaf(xv.y, wv1, acc[r]);
      acc[r] = fmaf(xv.z, wv2, acc[r]);
      acc[r] = fmaf(xv.w, wv3, acc[r]);
    }
  }
#pragma unroll
  for (int r = 0; r < 16; ++r) {
    int row = i0 + w * 16 + r;
    if (row < nA) hI2buf[(long)row * 64 + lane] = fmaxf(acc[r], 0.0f);
  }
}

// ---------------------------------------------------------------------------
// K7: hIbuf[inst] = relu([u ; hI2] @ i_ln3 + b).  32 rows / block (k=128).
// ---------------------------------------------------------------------------
__global__ __launch_bounds__(256, 2)
void final_kernel(const float* __restrict__ hI2buf,
                  const float* __restrict__ user_w,
                  const float* __restrict__ W3w, const float* __restrict__ W3b,
                  const int* __restrict__ list, const int* __restrict__ aUid,
                  const int* __restrict__ nActp, float* __restrict__ hIbuf) {
  const int tid = threadIdx.x, lane = tid & 63, w = tid >> 6;
  const int i0 = blockIdx.x * 32;
  const int nA = nActp[0];
  if (i0 >= nA) return;
  __shared__ float sW[128][64];
  __shared__ float sX[32][128];
  __shared__ float sb[64];
  __shared__ int sUid[32], sInst[32];
  for (int i = tid; i < 8192; i += 256) sW[i >> 6][i & 63] = W3w[i];
  if (tid < 64) sb[tid] = W3b[tid];
  if (tid < 32) {
    bool ok = (i0 + tid) < nA;
    sUid[tid] = ok ? aUid[i0 + tid] : 0;
    sInst[tid] = ok ? list[i0 + tid] : 0;
  }
  __syncthreads();
  for (int i = tid; i < 4096; i += 256) {
    int r = i >> 7, c = i & 127;
    sX[r][c] = (c < 64) ? user_w[(long)sUid[r] * 64 + c]
                        : hI2buf[(long)(i0 + r) * 64 + (c - 64)];
  }
  __syncthreads();
  float acc[8];
#pragma unroll
  for (int r = 0; r < 8; ++r) acc[r] = sb[lane];
  for (int k = 0; k < 128; k += 4) {
    float wv0 = sW[k][lane], wv1 = sW[k + 1][lane];
    float wv2 = sW[k + 2][lane], wv3 = sW[k + 3][lane];
#pragma unroll
    for (int r = 0; r < 8; ++r) {
      const float4 xv = *(const float4*)(&sX[w * 8 + r][k]);
      acc[r] = fmaf(xv.x, wv0, acc[r]);
      acc[r] = fmaf(xv.y, wv1, acc[r]);
      acc[r] = fmaf(xv.z, wv2, acc[r]);
      acc[r] = fmaf(xv.w, wv3, acc[r]);
    }
  }
#pragma unroll
  for (int r = 0; r < 8; ++r) {
    int row = i0 + w * 8 + r;
    if (row < nA)
      hIbuf[(long)sInst[w * 8 + r] * 64 + lane] = fmaxf(acc[r], 0.0f);
  }
}

// ---------------------------------------------------------------------------
// K8: social aggregation + final MLP. One block per batch element.
// ---------------------------------------------------------------------------
__global__ __launch_bounds__(256, 2)
void social_kernel(const float* __restrict__ user_w,
                   const float* __restrict__ hIbuf,
                   const float* __restrict__ A1w, const float* __restrict__ A1b,
                   const float* __restrict__ A2w, const float* __restrict__ A2b,
                   const float* __restrict__ A3w, const float* __restrict__ A3b,
                   const float* __restrict__ L1w, const float* __restrict__ L1b,
                   const float* __restrict__ L2w, const float* __restrict__ L2b,
                   const float* __restrict__ L3w, const float* __restrict__ L3b,
                   const int* __restrict__ nodes,
                   const void* __restrict__ social_mask,
                   const int* __restrict__ flagp,
                   float* __restrict__ out) {
  __shared__ float sA1a[64][64], sA2[64][64];
  __shared__ float hv[32][64];
  __shared__ float h1w[4][8][64];
  __shared__ float uvec[64], uA1[64], selfv[64], vecA[64], vecB[64];
  __shared__ float red[4][64], logit[32], alpha[32];
  __shared__ float sA2b[64], sA3w[64];
  __shared__ float sA3b;
  __shared__ int cslot[32], nval_s;
  const int tid = threadIdx.x, lane = tid & 63, w = tid >> 6;
  const int mode = flagp[0];
  const int b = blockIdx.x;
  const long uid = nodes[b];

  for (int i = tid; i < 4096; i += 256) {
    sA1a[i >> 6][i & 63] = A1w[i];
    sA2[i >> 6][i & 63] = A2w[i];
  }
  if (tid == 0) sA3b = A3b[0];
  if (w == 0) {
    bool m = false;
    if (lane < 32) m = mread(social_mask, uid * LSS + lane, mode);
    unsigned long long bal = __ballot(m);
    int pos = __popcll(bal & ((1ull << lane) - 1ull));
    if (m) cslot[pos] = lane;
    if (lane == 0) nval_s = (int)__popcll(bal);
  } else if (w == 1) {
    uvec[lane] = user_w[uid * 64 + lane];
    sA2b[lane] = A2b[lane];
  } else if (w == 2) {
    selfv[lane] = hIbuf[(long)b * 64 + lane];
    sA3w[lane] = A3w[lane];
  }
  __syncthreads();
  const int nval = nval_s;

  {
    float acc = 0.0f;
#pragma unroll
    for (int kk = 0; kk < 16; ++kk) {
      int k = w * 16 + kk;
      acc = fmaf(uvec[k], A1w[(64 + k) * 64 + lane], acc);
    }
    red[w][lane] = acc;
  }
  for (int j = w; j < nval; j += 4)
    hv[j][lane] = hIbuf[(512L + (long)b * 32 + cslot[j]) * 64 + lane];
  __syncthreads();
  if (tid < 64)
    uA1[tid] = red[0][tid] + red[1][tid] + red[2][tid] + red[3][tid] + A1b[tid];
  __syncthreads();

  {
    const float base = uA1[lane];
    float acc[8];
#pragma unroll
    for (int r = 0; r < 8; ++r) acc[r] = base;
    for (int k = 0; k < 64; k += 4) {
      float wv0 = sA1a[k][lane], wv1 = sA1a[k + 1][lane];
      float wv2 = sA1a[k + 2][lane], wv3 = sA1a[k + 3][lane];
#pragma unroll
      for (int r = 0; r < 8; ++r) {
        const float4 xv = *(const float4*)(&hv[w * 8 + r][k]);
        acc[r] = fmaf(xv.x, wv0, acc[r]);
        acc[r] = fmaf(xv.y, wv1, acc[r]);
        acc[r] = fmaf(xv.z, wv2, acc[r]);
        acc[r] = fmaf(xv.w, wv3, acc[r]);
      }
    }
#pragma unroll
    for (int r = 0; r < 8; ++r) h1w[w][r][lane] = fmaxf(acc[r], 0.0f);
  }
  __syncthreads();

  {
    float acc2[8];
#pragma unroll
    for (int r = 0; r < 8; ++r) acc2[r] = sA2b[lane];
    for (int k = 0; k < 64; k += 4) {
      float wv0 = sA2[k][lane], wv1 = sA2[k + 1][lane];
      float wv2 = sA2[k + 2][lane], wv3 = sA2[k + 3][lane];
#pragma unroll
      for (int r = 0; r < 8; ++r) {
        const float4 hvv = *(const float4*)(&h1w[w][r][k]);
        acc2[r] = fmaf(hvv.x, wv0, acc2[r]);
        acc2[r] = fmaf(hvv.y, wv1, acc2[r]);
        acc2[r] = fmaf(hvv.z, wv2, acc2[r]);
        acc2[r] = fmaf(hvv.w, wv3, acc2[r]);
      }
    }
#pragma unroll
    for (int r = 0; r < 8; ++r) {
      int j = w * 8 + r;
      float p = fmaxf(acc2[r], 0.0f) * sA3w[lane];
      p = wsum(p);
      if (lane == 0 && j < nval) logit[j] = p + sA3b;
    }
  }
  __syncthreads();

  if (w == 0) {
    float lv = (lane < nval) ? logit[lane] : -1e30f;
    float mx = wmax(lv);
    float e = (lane < nval) ? __expf(lv - mx) : 0.0f;
    float s = wsum(e);
    if (lane < 32) alpha[lane] = e / s;
  }
  __syncthreads();

  {
    float acc = 0.0f;
    for (int j = w; j < nval; j += 4) acc = fmaf(alpha[j], hv[j][lane], acc);
    red[w][lane] = acc;
  }
  __syncthreads();
  if (tid < 64) vecA[tid] = red[0][tid] + red[1][tid] + red[2][tid] + red[3][tid];
  __syncthreads();

  {
    float acc = 0.0f;
#pragma unroll
    for (int kk = 0; kk < 16; ++kk) {
      int k = w * 16 + kk;
      acc = fmaf(vecA[k], L1w[k * 64 + lane], acc);
    }
    red[w][lane] = acc;
  }
  __syncthreads();
  if (tid < 64)
    vecB[tid] = fmaxf(red[0][tid] + red[1][tid] + red[2][tid] + red[3][tid] + L1b[tid], 0.0f);
  __syncthreads();

  {
    float acc = 0.0f;
#pragma unroll
    for (int kk = 0; kk < 32; ++kk) {
      int k = w * 32 + kk;
      float xv = (k < 64) ? selfv[k] : vecB[k - 64];
      acc = fmaf(xv, L2w[k * 64 + lane], acc);
    }
    red[w][lane] = acc;
  }
  __syncthreads();
  if (tid < 64)
    vecA[tid] = fmaxf(red[0][tid] + red[1][tid] + red[2][tid] + red[3][tid] + L2b[tid], 0.0f);
  __syncthreads();

  {
    float acc = 0.0f;
#pragma unroll
    for (int kk = 0; kk < 16; ++kk) {
      int k = w * 16 + kk;
      acc = fmaf(vecA[k], L3w[k * 64 + lane], acc);
    }
    red[w][lane] = acc;
  }
  __syncthreads();
  if (tid < 64)
    out[(long)b * 64 + tid] =
        fmaxf(red[0][tid] + red[1][tid] + red[2][tid] + red[3][tid] + L3b[tid], 0.0f);
}

// ---------------------------------------------------------------------------
extern "C" void kernel_launch(void* const* d_in, const int* in_sizes, int n_in,
                              void* d_out, int out_size, void* d_ws, size_t ws_size,
                              hipStream_t stream) {
  const float* user_w   = (const float*)d_in[0];
  const float* item_w   = (const float*)d_in[1];
  const float* rating_w = (const float*)d_in[2];
  const float* i_ln1_w  = (const float*)d_in[3];
  const float* i_ln1_b  = (const float*)d_in[4];
  const float* i_ln2_w  = (const float*)d_in[5];
  const float* i_ln2_b  = (const float*)d_in[6];
  const float* i_ln3_w  = (const float*)d_in[7];
  const float* i_ln3_b  = (const float*)d_in[8];
  const float* i_att1_w = (const float*)d_in[9];
  const float* i_att1_b = (const float*)d_in[10];
  const float* i_att2_w = (const float*)d_in[11];
  const float* i_att2_b = (const float*)d_in[12];
  const float* i_att3_w = (const float*)d_in[13];
  const float* i_att3_b = (const float*)d_in[14];
  const float* s_ln1_w  = (const float*)d_in[15];
  const float* s_ln1_b  = (const float*)d_in[16];
  const float* s_ln2_w  = (const float*)d_in[17];
  const float* s_ln2_b  = (const float*)d_in[18];
  const float* s_ln3_w  = (const float*)d_in[19];
  const float* s_ln3_b  = (const float*)d_in[20];
  const float* s_att1_w = (const float*)d_in[21];
  const float* s_att1_b = (const float*)d_in[22];
  const float* s_att2_w = (const float*)d_in[23];
  const float* s_att2_b = (const float*)d_in[24];
  const float* s_att3_w = (const float*)d_in[25];
  const float* s_att3_b = (const float*)d_in[26];
  const int*  nodes       = (const int*)d_in[27];
  const int*  social_hist = (const int*)d_in[28];
  const void* social_mask = d_in[29];
  const int*  item_hist   = (const int*)d_in[30];
  const int*  rating_hist = (const int*)d_in[31];
  const void* item_mask   = d_in[32];

  // workspace layout (bytes)
  char* ws = (char*)d_ws;
  int*   flag    = (int*)(ws + 0);          // 256
  int*   counter = (int*)(ws + 256);        // 256
  int*   list    = (int*)(ws + 512);        // NT*4 = 67584
  int*   aUid    = (int*)(ws + 68096);      // 67584
  float* uA1buf  = (float*)(ws + 135680);   // NT*64*4 = 4325376
  float* hI2buf  = uA1buf;                  // alias: uA1 dead before K6
  float* hvecbuf = (float*)(ws + 4461056);  // 4325376
  float* hIbuf   = hvecbuf;                 // alias: hvec dead before K7
  float* xbase   = (float*)(ws + 8786432);  // 50000*64*4 = 12800000
  float* RW1g    = (float*)(ws + 21586432); // 1280
  short* Bimg1   = (short*)(ws + 21587712); // 8192
  short* Bimg2   = (short*)(ws + 21595904); // 8192

  hipMemsetAsync(counter, 0, 4, stream);
  detect_mask_kernel<<<1, 256, 0, stream>>>((const unsigned int*)social_mask, flag);
  pre_rw_kernel<<<1, 320, 0, stream>>>(rating_w, i_ln1_w, i_ln1_b, RW1g);
  prepack_kernel<<<1, 256, 0, stream>>>(i_att1_w, i_att2_w, Bimg1, Bimg2);
  pre_xbase_kernel<<<(NII + 31) / 32, 256, 0, stream>>>(item_w, i_ln1_w, xbase);
  build_active_kernel<<<NT / 256, 256, 0, stream>>>(
      nodes, social_hist, social_mask, flag, counter, list, aUid);
  uA1_kernel<<<NT / 64, 256, 0, stream>>>(user_w, i_att1_w, i_att1_b, aUid, counter, uA1buf);
  core_mfma_kernel<<<NT / 4, 256, 0, stream>>>(
      xbase, RW1g, uA1buf, Bimg1, Bimg2, i_att2_b, i_att3_w,
      item_hist, rating_hist, item_mask, flag, aUid, counter, hvecbuf);
  hI2_kernel<<<NT / 64, 256, 0, stream>>>(hvecbuf, i_ln2_w, i_ln2_b, counter, hI2buf);
  final_kernel<<<NT / 32, 256, 0, stream>>>(hI2buf, user_w, i_ln3_w, i_ln3_b,
                                            list, aUid, counter, hIbuf);
  social_kernel<<<BB, 256, 0, stream>>>(
      user_w, hIbuf,
      s_att1_w, s_att1_b, s_att2_w, s_att2_b, s_att3_w, s_att3_b,
      s_ln1_w, s_ln1_b, s_ln2_w, s_ln2_b, s_ln3_w, s_ln3_b,
      nodes, social_mask, flag, (float*)d_out);
}

// Round 6
// 213.254 us; speedup vs baseline: 4.2324x; 1.8729x over previous
//
#include <hip/hip_runtime.h>
#include <math.h>

// ---------------------------------------------------------------------------
// Aggre_social on MI355X — round 6: identical to round 5 except the workspace
// layout: W1hi/W1lo overlaid into hvecbuf's first 16KB (dead until core runs),
// restoring the round-4-proven 21,604,096-byte ws footprint. Round 5's extra
// 16KB past that mark is the prime suspect for the post-timing divergence
// (overflow corrupting an adjacent input consumed earlier in the stream).
// ---------------------------------------------------------------------------

#define NII 50000
#define BB 512
#define LSS 32
#define NT 16896   // 512 self + 16384 neighbor instances

typedef short short8 __attribute__((ext_vector_type(8)));
typedef float f32x4 __attribute__((ext_vector_type(4)));

static __device__ __forceinline__ bool mread(const void* p, long i, int mode) {
  if (mode == 0) return ((const int*)p)[i] != 0;       // int32 storage
  if (mode == 2) return ((const float*)p)[i] != 0.0f;  // f32 storage
  return ((const unsigned char*)p)[i] != 0;            // byte storage
}

static __device__ __forceinline__ float wsum(float v) {
#pragma unroll
  for (int s = 1; s < 64; s <<= 1) v += __shfl_xor(v, s);
  return v;
}
static __device__ __forceinline__ float wmax(float v) {
#pragma unroll
  for (int s = 1; s < 64; s <<= 1) v = fmaxf(v, __shfl_xor(v, s));
  return v;
}
static __device__ __forceinline__ float rsum16(float v) {
#pragma unroll
  for (int s = 1; s < 16; s <<= 1) v += __shfl_xor(v, s);
  return v;
}

// f32 -> bf16 (round-to-nearest-even), as raw short.
static __device__ __forceinline__ short bf16rne(float f) {
  unsigned u = __float_as_uint(f);
  u = (u + 0x7FFFu + ((u >> 16) & 1u)) >> 16;
  return (short)u;
}
static __device__ __forceinline__ float bf16tof(short h) {
  return __uint_as_float(((unsigned)(unsigned short)h) << 16);
}

// Intra-wave LDS write->read fence.
static __device__ __forceinline__ void wave_fence() {
  asm volatile("s_waitcnt lgkmcnt(0)" ::: "memory");
  __builtin_amdgcn_sched_barrier(0);
}

// ---------------------------------------------------------------------------
// K0: detect boolean-mask storage. flag: 0=int32, 1=byte, 2=float32.
// ---------------------------------------------------------------------------
__global__ void detect_mask_kernel(const unsigned int* __restrict__ sm,
                                   int* __restrict__ flag) {
  __shared__ int notInt, notFloat;
  if (threadIdx.x == 0) { notInt = 0; notFloat = 0; }
  __syncthreads();
  int ni = 0, nf = 0;
  for (int i = threadIdx.x; i < 4096; i += 256) {
    unsigned int x = sm[i];
    if (x > 1u) ni = 1;
    if (x != 0u && x != 0x3F800000u) nf = 1;
  }
  if (ni) atomicOr(&notInt, 1);
  if (nf) atomicOr(&notFloat, 1);
  __syncthreads();
  if (threadIdx.x == 0) flag[0] = notInt ? (notFloat ? 1 : 2) : 0;
}

// ---------------------------------------------------------------------------
// K1: RW1g[5][64] = rating_w @ W1[64:128] + i_ln1_b.   <<<1,320>>>
// ---------------------------------------------------------------------------
__global__ void pre_rw_kernel(const float* __restrict__ rating_w,
                              const float* __restrict__ w1,
                              const float* __restrict__ b1,
                              float* __restrict__ RW1g) {
  const int r = threadIdx.x >> 6;
  const int c = threadIdx.x & 63;
  float acc = b1[c];
  for (int k = 0; k < 64; ++k)
    acc = fmaf(rating_w[r * 64 + k], w1[(64 + k) * 64 + c], acc);
  RW1g[r * 64 + c] = acc;
}

// ---------------------------------------------------------------------------
// K1b: pre-pack MFMA B-fragment images (bf16):
//  - B1/B2: att weights (i_att1_w rows 0..63, i_att2_w), plain bf16
//  - W1hi/W1lo: i_ln1_w rows 0..63 split hi/lo for f32-accurate MFMA
// Layout: idx = ((kb*4+nb)*64 + lane)*8 + e  <->  B[k][col],
//   k = kb*32 + ((lane>>4)&3)*8 + e, col = nb*16 + (lane&15).
// ---------------------------------------------------------------------------
__global__ void prepack_kernel(const float* __restrict__ A1w,
                               const float* __restrict__ A2w,
                               const float* __restrict__ w1,
                               short* __restrict__ B1,
                               short* __restrict__ B2,
                               short* __restrict__ W1hi,
                               short* __restrict__ W1lo) {
  for (int idx = threadIdx.x; idx < 4096; idx += 256) {
    int e = idx & 7, g = idx >> 3;
    int l = g & 63, q = g >> 6;          // q = kb*4+nb
    int kb = q >> 2, nb = q & 3;
    int k = kb * 32 + ((l >> 4) & 3) * 8 + e;
    int col = nb * 16 + (l & 15);
    B1[idx] = bf16rne(A1w[k * 64 + col]);
    B2[idx] = bf16rne(A2w[k * 64 + col]);
    float a = w1[k * 64 + col];
    short h = bf16rne(a);
    W1hi[idx] = h;
    W1lo[idx] = bf16rne(a - bf16tof(h));
  }
}

// ---------------------------------------------------------------------------
// K2: xbase[50000][64] = item_w @ W1[0:64] via split-bf16 MFMA (f32-accurate:
// hi*hi + hi*lo + lo*hi; dropped lo*lo <= 1.5e-5). Wave-independent,
// no LDS, no barriers. 3125 row-tiles of 16.
// ---------------------------------------------------------------------------
__global__ __launch_bounds__(256)
void pre_xbase_mfma_kernel(const float* __restrict__ item_w,
                           const short* __restrict__ W1hi,
                           const short* __restrict__ W1lo,
                           float* __restrict__ xbase) {
  const int lane = threadIdx.x & 63, w = threadIdx.x >> 6;
  const int l15 = lane & 15, lg4 = lane >> 4;
  short8 bh[8], bl[8];                     // [kb*4+nb]
#pragma unroll
  for (int q = 0; q < 8; ++q) {
    bh[q] = *(const short8*)(W1hi + (q * 64 + lane) * 8);
    bl[q] = *(const short8*)(W1lo + (q * 64 + lane) * 8);
  }
  const int wid = blockIdx.x * 4 + w;
  const int nw = gridDim.x * 4;
  for (int tile = wid; tile < 3125; tile += nw) {
    const long r0 = (long)tile * 16;
    const float* ap = item_w + (r0 + l15) * 64 + lg4 * 8;
    short8 ah[2], al[2];
#pragma unroll
    for (int kb = 0; kb < 2; ++kb) {
      const float4 a = *(const float4*)(ap + kb * 32);
      const float4 b = *(const float4*)(ap + kb * 32 + 4);
      float v[8] = {a.x, a.y, a.z, a.w, b.x, b.y, b.z, b.w};
      short8 hi, lo;
#pragma unroll
      for (int e = 0; e < 8; ++e) {
        short h = bf16rne(v[e]);
        hi[e] = h;
        lo[e] = bf16rne(v[e] - bf16tof(h));
      }
      ah[kb] = hi;
      al[kb] = lo;
    }
#pragma unroll
    for (int nb = 0; nb < 4; ++nb) {
      f32x4 acc = {0.0f, 0.0f, 0.0f, 0.0f};
      acc = __builtin_amdgcn_mfma_f32_16x16x32_bf16(ah[0], bh[0 * 4 + nb], acc, 0, 0, 0);
      acc = __builtin_amdgcn_mfma_f32_16x16x32_bf16(ah[1], bh[1 * 4 + nb], acc, 0, 0, 0);
      acc = __builtin_amdgcn_mfma_f32_16x16x32_bf16(ah[0], bl[0 * 4 + nb], acc, 0, 0, 0);
      acc = __builtin_amdgcn_mfma_f32_16x16x32_bf16(ah[1], bl[1 * 4 + nb], acc, 0, 0, 0);
      acc = __builtin_amdgcn_mfma_f32_16x16x32_bf16(al[0], bh[0 * 4 + nb], acc, 0, 0, 0);
      acc = __builtin_amdgcn_mfma_f32_16x16x32_bf16(al[1], bh[1 * 4 + nb], acc, 0, 0, 0);
#pragma unroll
      for (int r = 0; r < 4; ++r)
        xbase[(r0 + lg4 * 4 + r) * 64 + nb * 16 + l15] = acc[r];
    }
  }
}

// ---------------------------------------------------------------------------
// K3: compact active instance list.  <<<66,256>>>
// ---------------------------------------------------------------------------
__global__ void build_active_kernel(const int* __restrict__ nodes,
                                    const int* __restrict__ social_hist,
                                    const void* __restrict__ social_mask,
                                    const int* __restrict__ flagp,
                                    int* __restrict__ counter,
                                    int* __restrict__ list,
                                    int* __restrict__ aUid) {
  const int t = blockIdx.x * 256 + threadIdx.x;
  if (t >= NT) return;
  const int mode = flagp[0];
  int uid;
  bool active;
  if (t < BB) {
    active = true;
    uid = nodes[t];
  } else {
    int nb = t - BB;
    int b = nb >> 5, l = nb & 31;
    long mi = (long)nodes[b] * LSS + l;
    active = mread(social_mask, mi, mode);
    uid = active ? social_hist[mi] : 0;
  }
  if (active) {
    int pos = atomicAdd(counter, 1);
    list[pos] = t;
    aUid[pos] = uid;
  }
}

// ---------------------------------------------------------------------------
// K4: uA1buf[idx] = user_w[aUid[idx]] @ A1w[64:128] + A1b.   64 rows / block.
// ---------------------------------------------------------------------------
__global__ __launch_bounds__(256, 2)
void uA1_kernel(const float* __restrict__ user_w,
                const float* __restrict__ A1w, const float* __restrict__ A1b,
                const int* __restrict__ aUid, const int* __restrict__ nActp,
                float* __restrict__ uA1buf) {
  const int tid = threadIdx.x, lane = tid & 63, w = tid >> 6;
  const int i0 = blockIdx.x * 64;
  const int nA = nActp[0];
  if (i0 >= nA) return;
  __shared__ float sW[64][64], sU[64][64];
  __shared__ float sb[64];
  __shared__ int sUid[64];
  for (int i = tid; i < 4096; i += 256) sW[i >> 6][i & 63] = A1w[4096 + i];
  if (tid < 64) {
    sb[tid] = A1b[tid];
    sUid[tid] = (i0 + tid < nA) ? aUid[i0 + tid] : 0;
  }
  __syncthreads();
  for (int i = tid; i < 4096; i += 256) {
    int r = i >> 6, c = i & 63;
    sU[r][c] = user_w[(long)sUid[r] * 64 + c];
  }
  __syncthreads();
  float acc[16];
#pragma unroll
  for (int r = 0; r < 16; ++r) acc[r] = sb[lane];
  for (int k = 0; k < 64; k += 4) {
    float wv0 = sW[k][lane], wv1 = sW[k + 1][lane];
    float wv2 = sW[k + 2][lane], wv3 = sW[k + 3][lane];
#pragma unroll
    for (int r = 0; r < 16; ++r) {
      const float4 xv = *(const float4*)(&sU[w * 16 + r][k]);
      acc[r] = fmaf(xv.x, wv0, acc[r]);
      acc[r] = fmaf(xv.y, wv1, acc[r]);
      acc[r] = fmaf(xv.z, wv2, acc[r]);
      acc[r] = fmaf(xv.w, wv3, acc[r]);
    }
  }
#pragma unroll
  for (int r = 0; r < 16; ++r) {
    int row = i0 + w * 16 + r;
    if (row < nA) uA1buf[(long)row * 64 + lane] = acc[r];
  }
}

// ---------------------------------------------------------------------------
// K5: CORE — wave-per-instance attention with MFMA bf16 logits.
// 256 threads = 4 independent waves, no __syncthreads at all.
// B-fragment images held in registers (loaded once per wave).
// ---------------------------------------------------------------------------
__global__ __launch_bounds__(256)
void core_mfma_kernel(const float* __restrict__ xbase,
                      const float* __restrict__ RW1g,
                      const float* __restrict__ uA1buf,
                      const short* __restrict__ Bimg1,
                      const short* __restrict__ Bimg2,
                      const float* __restrict__ A2b,
                      const float* __restrict__ A3w,
                      const int* __restrict__ item_hist,
                      const int* __restrict__ rating_hist,
                      const void* __restrict__ item_mask,
                      const int* __restrict__ flagp,
                      const int* __restrict__ aUid,
                      const int* __restrict__ nActp,
                      float* __restrict__ hvecbuf) {
  __shared__ __align__(16) char smem[4][3072];
  const int tid = threadIdx.x, lane = tid & 63, w = tid >> 6;
  short* h1w = (short*)(smem[w]);          // [16][80] bf16
  float* lgw = (float*)(smem[w] + 2560);   // [64] logits
  int* cw = (int*)(smem[w] + 2816);        // [64] packed (item<<3)|rating

  const int mode = flagp[0];
  const int nA = nActp[0];
  const float a2bv = A2b[lane];
  const float a3v = A3w[lane];
  const int l15 = lane & 15;
  const int lg4 = lane >> 4;

  short8 b1f[8], b2f[8];                   // [kb*4+nb], register-resident
#pragma unroll
  for (int q = 0; q < 8; ++q) {
    b1f[q] = *(const short8*)(Bimg1 + (q * 64 + lane) * 8);
    b2f[q] = *(const short8*)(Bimg2 + (q * 64 + lane) * 8);
  }

  for (int idx = blockIdx.x * 4 + w; idx < nA; idx += gridDim.x * 4) {
    wave_fence();  // prior-instance LDS reads complete before overwrite
    const long uid = aUid[idx];

    // ---- compact item history (lane covers LI=64) ----
    const long mbase = uid * 64;
    bool m = mread(item_mask, mbase + lane, mode);
    unsigned long long bal = __ballot(m);
    const int nact = (int)__popcll(bal);
    int pos = (int)__popcll(bal & ((1ull << lane) - 1ull));
    if (m) cw[pos] = (item_hist[mbase + lane] << 3) | rating_hist[mbase + lane];
    const float uA1v = uA1buf[(long)idx * 64 + lane];
    wave_fence();

    // ---- logits via MFMA, 16-row chunks ----
    const int ng = (nact + 15) >> 4;
    for (int mc = 0; mc < ng; ++mc) {
      wave_fence();  // prior chunk's H1 reads done before overwrite
      int row = mc * 16 + l15;
      if (row >= nact) row = nact - 1;
      const int p = cw[row];
      const long it = p >> 3;
      const int rt = p & 7;
      short8 xa[2];
#pragma unroll
      for (int kb = 0; kb < 2; ++kb) {
        const int koff = kb * 32 + lg4 * 8;
        const float* xp = xbase + it * 64 + koff;
        const float* rp = RW1g + rt * 64 + koff;
        const float4 a = *(const float4*)xp;
        const float4 b = *(const float4*)(xp + 4);
        const float4 c = *(const float4*)rp;
        const float4 d = *(const float4*)(rp + 4);
        short8 f;
        f[0] = bf16rne(fmaxf(a.x + c.x, 0.0f));
        f[1] = bf16rne(fmaxf(a.y + c.y, 0.0f));
        f[2] = bf16rne(fmaxf(a.z + c.z, 0.0f));
        f[3] = bf16rne(fmaxf(a.w + c.w, 0.0f));
        f[4] = bf16rne(fmaxf(b.x + d.x, 0.0f));
        f[5] = bf16rne(fmaxf(b.y + d.y, 0.0f));
        f[6] = bf16rne(fmaxf(b.z + d.z, 0.0f));
        f[7] = bf16rne(fmaxf(b.w + d.w, 0.0f));
        xa[kb] = f;
      }
      // att1: H1 = relu(X @ A1a + uA1), one N-block at a time
#pragma unroll
      for (int nb = 0; nb < 4; ++nb) {
        const float ui = __shfl(uA1v, nb * 16 + l15);
        f32x4 acc = {ui, ui, ui, ui};
        acc = __builtin_amdgcn_mfma_f32_16x16x32_bf16(xa[0], b1f[0 * 4 + nb], acc, 0, 0, 0);
        acc = __builtin_amdgcn_mfma_f32_16x16x32_bf16(xa[1], b1f[1 * 4 + nb], acc, 0, 0, 0);
#pragma unroll
        for (int r = 0; r < 4; ++r)
          h1w[(lg4 * 4 + r) * 80 + nb * 16 + l15] = bf16rne(fmaxf(acc[r], 0.0f));
      }
      wave_fence();
      // att2 + logit
      short8 ha[2];
      ha[0] = *(const short8*)(h1w + l15 * 80 + lg4 * 8);
      ha[1] = *(const short8*)(h1w + l15 * 80 + 32 + lg4 * 8);
      float t0 = 0.0f, t1 = 0.0f, t2 = 0.0f, t3 = 0.0f;
#pragma unroll
      for (int nb = 0; nb < 4; ++nb) {
        const float b2 = __shfl(a2bv, nb * 16 + l15);
        f32x4 acc = {b2, b2, b2, b2};
        acc = __builtin_amdgcn_mfma_f32_16x16x32_bf16(ha[0], b2f[0 * 4 + nb], acc, 0, 0, 0);
        acc = __builtin_amdgcn_mfma_f32_16x16x32_bf16(ha[1], b2f[1 * 4 + nb], acc, 0, 0, 0);
        const float a3c = __shfl(a3v, nb * 16 + l15);
        t0 = fmaf(fmaxf(acc[0], 0.0f), a3c, t0);
        t1 = fmaf(fmaxf(acc[1], 0.0f), a3c, t1);
        t2 = fmaf(fmaxf(acc[2], 0.0f), a3c, t2);
        t3 = fmaf(fmaxf(acc[3], 0.0f), a3c, t3);
      }
      t0 = rsum16(t0); t1 = rsum16(t1); t2 = rsum16(t2); t3 = rsum16(t3);
      if (l15 == 0) {
        const int jb = mc * 16 + lg4 * 4;
        lgw[jb + 0] = t0;
        lgw[jb + 1] = t1;
        lgw[jb + 2] = t2;
        lgw[jb + 3] = t3;
      }
    }
    wave_fence();

    // ---- softmax over lanes (lane j holds logit_j; b3 dropped: invariant) ----
    const bool valid = (lane < nact);
    float lv = valid ? lgw[lane] : -1e30f;
    float mx = wmax(lv);
    float e = valid ? __expf(lv - mx) : 0.0f;
    float s = wsum(e);
    const float alpha = e / s;

    // ---- hI = sum_j alpha_j * x_j  (exact f32 re-gather) ----
    float hi = 0.0f;
    for (int j = 0; j < nact; ++j) {
      const float aj = __shfl(alpha, j);
      const int p = cw[j];
      const float xv =
          fmaxf(xbase[(long)(p >> 3) * 64 + lane] + RW1g[(p & 7) * 64 + lane], 0.0f);
      hi = fmaf(aj, xv, hi);
    }
    hvecbuf[(long)idx * 64 + lane] = hi;
  }
}

// ---------------------------------------------------------------------------
// K6: hI2buf[idx] = relu(hvecbuf[idx] @ i_ln2 + b).  64 rows / block.
// ---------------------------------------------------------------------------
__global__ __launch_bounds__(256, 2)
void hI2_kernel(const float* __restrict__ hvecbuf,
                const float* __restrict__ W2w, const float* __restrict__ W2b,
                const int* __restrict__ nActp, float* __restrict__ hI2buf) {
  const int tid = threadIdx.x, lane = tid & 63, w = tid >> 6;
  const int i0 = blockIdx.x * 64;
  const int nA = nActp[0];
  if (i0 >= nA) return;
  __shared__ float sW[64][64], sX[64][64];
  __shared__ float sb[64];
  for (int i = tid; i < 4096; i += 256) sW[i >> 6][i & 63] = W2w[i];
  if (tid < 64) sb[tid] = W2b[tid];
  for (int i = tid; i < 4096; i += 256) {
    int r = i >> 6, c = i & 63;
    sX[r][c] = (i0 + r < nA) ? hvecbuf[(long)(i0 + r) * 64 + c] : 0.0f;
  }
  __syncthreads();
  float acc[16];
#pragma unroll
  for (int r = 0; r < 16; ++r) acc[r] = sb[lane];
  for (int k = 0; k < 64; k += 4) {
    float wv0 = sW[k][lane], wv1 = sW[k + 1][lane];
    float wv2 = sW[k + 2][lane], wv3 = sW[k + 3][lane];
#pragma unroll
    for (int r = 0; r < 16; ++r) {
      const float4 xv = *(const float4*)(&sX[w * 16 + r][k]);
      acc[r] = fmaf(xv.x, wv0, acc[r]);
      acc[r] = fmaf(xv.y, wv1, acc[r]);
      acc[r] = fmaf(xv.z, wv2, acc[r]);
      acc[r] = fmaf(xv.w, wv3, acc[r]);
    }
  }
#pragma unroll
  for (int r = 0; r < 16; ++r) {
    int row = i0 + w * 16 + r;
    if (row < nA) hI2buf[(long)row * 64 + lane] = fmaxf(acc[r], 0.0f);
  }
}

// ---------------------------------------------------------------------------
// K7: hIbuf[inst] = relu([u ; hI2] @ i_ln3 + b).  32 rows / block (k=128).
// ---------------------------------------------------------------------------
__global__ __launch_bounds__(256, 2)
void final_kernel(const float* __restrict__ hI2buf,
                  const float* __restrict__ user_w,
                  const float* __restrict__ W3w, const float* __restrict__ W3b,
                  const int* __restrict__ list, const int* __restrict__ aUid,
                  const int* __restrict__ nActp, float* __restrict__ hIbuf) {
  const int tid = threadIdx.x, lane = tid & 63, w = tid >> 6;
  const int i0 = blockIdx.x * 32;
  const int nA = nActp[0];
  if (i0 >= nA) return;
  __shared__ float sW[128][64];
  __shared__ float sX[32][128];
  __shared__ float sb[64];
  __shared__ int sUid[32], sInst[32];
  for (int i = tid; i < 8192; i += 256) sW[i >> 6][i & 63] = W3w[i];
  if (tid < 64) sb[tid] = W3b[tid];
  if (tid < 32) {
    bool ok = (i0 + tid) < nA;
    sUid[tid] = ok ? aUid[i0 + tid] : 0;
    sInst[tid] = ok ? list[i0 + tid] : 0;
  }
  __syncthreads();
  for (int i = tid; i < 4096; i += 256) {
    int r = i >> 7, c = i & 127;
    sX[r][c] = (c < 64) ? user_w[(long)sUid[r] * 64 + c]
                        : hI2buf[(long)(i0 + r) * 64 + (c - 64)];
  }
  __syncthreads();
  float acc[8];
#pragma unroll
  for (int r = 0; r < 8; ++r) acc[r] = sb[lane];
  for (int k = 0; k < 128; k += 4) {
    float wv0 = sW[k][lane], wv1 = sW[k + 1][lane];
    float wv2 = sW[k + 2][lane], wv3 = sW[k + 3][lane];
#pragma unroll
    for (int r = 0; r < 8; ++r) {
      const float4 xv = *(const float4*)(&sX[w * 8 + r][k]);
      acc[r] = fmaf(xv.x, wv0, acc[r]);
      acc[r] = fmaf(xv.y, wv1, acc[r]);
      acc[r] = fmaf(xv.z, wv2, acc[r]);
      acc[r] = fmaf(xv.w, wv3, acc[r]);
    }
  }
#pragma unroll
  for (int r = 0; r < 8; ++r) {
    int row = i0 + w * 8 + r;
    if (row < nA)
      hIbuf[(long)sInst[w * 8 + r] * 64 + lane] = fmaxf(acc[r], 0.0f);
  }
}

// ---------------------------------------------------------------------------
// K8: social aggregation + final MLP. One block per batch element.
// ---------------------------------------------------------------------------
__global__ __launch_bounds__(256, 2)
void social_kernel(const float* __restrict__ user_w,
                   const float* __restrict__ hIbuf,
                   const float* __restrict__ A1w, const float* __restrict__ A1b,
                   const float* __restrict__ A2w, const float* __restrict__ A2b,
                   const float* __restrict__ A3w, const float* __restrict__ A3b,
                   const float* __restrict__ L1w, const float* __restrict__ L1b,
                   const float* __restrict__ L2w, const float* __restrict__ L2b,
                   const float* __restrict__ L3w, const float* __restrict__ L3b,
                   const int* __restrict__ nodes,
                   const void* __restrict__ social_mask,
                   const int* __restrict__ flagp,
                   float* __restrict__ out) {
  __shared__ float sA1a[64][64], sA2[64][64];
  __shared__ float hv[32][64];
  __shared__ float h1w[4][8][64];
  __shared__ float uvec[64], uA1[64], selfv[64], vecA[64], vecB[64];
  __shared__ float red[4][64], logit[32], alpha[32];
  __shared__ float sA2b[64], sA3w[64];
  __shared__ float sA3b;
  __shared__ int cslot[32], nval_s;
  const int tid = threadIdx.x, lane = tid & 63, w = tid >> 6;
  const int mode = flagp[0];
  const int b = blockIdx.x;
  const long uid = nodes[b];

  for (int i = tid; i < 4096; i += 256) {
    sA1a[i >> 6][i & 63] = A1w[i];
    sA2[i >> 6][i & 63] = A2w[i];
  }
  if (tid == 0) sA3b = A3b[0];
  if (w == 0) {
    bool m = false;
    if (lane < 32) m = mread(social_mask, uid * LSS + lane, mode);
    unsigned long long bal = __ballot(m);
    int pos = __popcll(bal & ((1ull << lane) - 1ull));
    if (m) cslot[pos] = lane;
    if (lane == 0) nval_s = (int)__popcll(bal);
  } else if (w == 1) {
    uvec[lane] = user_w[uid * 64 + lane];
    sA2b[lane] = A2b[lane];
  } else if (w == 2) {
    selfv[lane] = hIbuf[(long)b * 64 + lane];
    sA3w[lane] = A3w[lane];
  }
  __syncthreads();
  const int nval = nval_s;

  {
    float acc = 0.0f;
#pragma unroll
    for (int kk = 0; kk < 16; ++kk) {
      int k = w * 16 + kk;
      acc = fmaf(uvec[k], A1w[(64 + k) * 64 + lane], acc);
    }
    red[w][lane] = acc;
  }
  for (int j = w; j < nval; j += 4)
    hv[j][lane] = hIbuf[(512L + (long)b * 32 + cslot[j]) * 64 + lane];
  __syncthreads();
  if (tid < 64)
    uA1[tid] = red[0][tid] + red[1][tid] + red[2][tid] + red[3][tid] + A1b[tid];
  __syncthreads();

  {
    const float base = uA1[lane];
    float acc[8];
#pragma unroll
    for (int r = 0; r < 8; ++r) acc[r] = base;
    for (int k = 0; k < 64; k += 4) {
      float wv0 = sA1a[k][lane], wv1 = sA1a[k + 1][lane];
      float wv2 = sA1a[k + 2][lane], wv3 = sA1a[k + 3][lane];
#pragma unroll
      for (int r = 0; r < 8; ++r) {
        const float4 xv = *(const float4*)(&hv[w * 8 + r][k]);
        acc[r] = fmaf(xv.x, wv0, acc[r]);
        acc[r] = fmaf(xv.y, wv1, acc[r]);
        acc[r] = fmaf(xv.z, wv2, acc[r]);
        acc[r] = fmaf(xv.w, wv3, acc[r]);
      }
    }
#pragma unroll
    for (int r = 0; r < 8; ++r) h1w[w][r][lane] = fmaxf(acc[r], 0.0f);
  }
  __syncthreads();

  {
    float acc2[8];
#pragma unroll
    for (int r = 0; r < 8; ++r) acc2[r] = sA2b[lane];
    for (int k = 0; k < 64; k += 4) {
      float wv0 = sA2[k][lane], wv1 = sA2[k + 1][lane];
      float wv2 = sA2[k + 2][lane], wv3 = sA2[k + 3][lane];
#pragma unroll
      for (int r = 0; r < 8; ++r) {
        const float4 hvv = *(const float4*)(&h1w[w][r][k]);
        acc2[r] = fmaf(hvv.x, wv0, acc2[r]);
        acc2[r] = fmaf(hvv.y, wv1, acc2[r]);
        acc2[r] = fmaf(hvv.z, wv2, acc2[r]);
        acc2[r] = fmaf(hvv.w, wv3, acc2[r]);
      }
    }
#pragma unroll
    for (int r = 0; r < 8; ++r) {
      int j = w * 8 + r;
      float p = fmaxf(acc2[r], 0.0f) * sA3w[lane];
      p = wsum(p);
      if (lane == 0 && j < nval) logit[j] = p + sA3b;
    }
  }
  __syncthreads();

  if (w == 0) {
    float lv = (lane < nval) ? logit[lane] : -1e30f;
    float mx = wmax(lv);
    float e = (lane < nval) ? __expf(lv - mx) : 0.0f;
    float s = wsum(e);
    if (lane < 32) alpha[lane] = e / s;
  }
  __syncthreads();

  {
    float acc = 0.0f;
    for (int j = w; j < nval; j += 4) acc = fmaf(alpha[j], hv[j][lane], acc);
    red[w][lane] = acc;
  }
  __syncthreads();
  if (tid < 64) vecA[tid] = red[0][tid] + red[1][tid] + red[2][tid] + red[3][tid];
  __syncthreads();

  {
    float acc = 0.0f;
#pragma unroll
    for (int kk = 0; kk < 16; ++kk) {
      int k = w * 16 + kk;
      acc = fmaf(vecA[k], L1w[k * 64 + lane], acc);
    }
    red[w][lane] = acc;
  }
  __syncthreads();
  if (tid < 64)
    vecB[tid] = fmaxf(red[0][tid] + red[1][tid] + red[2][tid] + red[3][tid] + L1b[tid], 0.0f);
  __syncthreads();

  {
    float acc = 0.0f;
#pragma unroll
    for (int kk = 0; kk < 32; ++kk) {
      int k = w * 32 + kk;
      float xv = (k < 64) ? selfv[k] : vecB[k - 64];
      acc = fmaf(xv, L2w[k * 64 + lane], acc);
    }
    red[w][lane] = acc;
  }
  __syncthreads();
  if (tid < 64)
    vecA[tid] = fmaxf(red[0][tid] + red[1][tid] + red[2][tid] + red[3][tid] + L2b[tid], 0.0f);
  __syncthreads();

  {
    float acc = 0.0f;
#pragma unroll
    for (int kk = 0; kk < 16; ++kk) {
      int k = w * 16 + kk;
      acc = fmaf(vecA[k], L3w[k * 64 + lane], acc);
    }
    red[w][lane] = acc;
  }
  __syncthreads();
  if (tid < 64)
    out[(long)b * 64 + tid] =
        fmaxf(red[0][tid] + red[1][tid] + red[2][tid] + red[3][tid] + L3b[tid], 0.0f);
}

// ---------------------------------------------------------------------------
extern "C" void kernel_launch(void* const* d_in, const int* in_sizes, int n_in,
                              void* d_out, int out_size, void* d_ws, size_t ws_size,
                              hipStream_t stream) {
  const float* user_w   = (const float*)d_in[0];
  const float* item_w   = (const float*)d_in[1];
  const float* rating_w = (const float*)d_in[2];
  const float* i_ln1_w  = (const float*)d_in[3];
  const float* i_ln1_b  = (const float*)d_in[4];
  const float* i_ln2_w  = (const float*)d_in[5];
  const float* i_ln2_b  = (const float*)d_in[6];
  const float* i_ln3_w  = (const float*)d_in[7];
  const float* i_ln3_b  = (const float*)d_in[8];
  const float* i_att1_w = (const float*)d_in[9];
  const float* i_att1_b = (const float*)d_in[10];
  const float* i_att2_w = (const float*)d_in[11];
  const float* i_att2_b = (const float*)d_in[12];
  const float* i_att3_w = (const float*)d_in[13];
  const float* i_att3_b = (const float*)d_in[14];
  const float* s_ln1_w  = (const float*)d_in[15];
  const float* s_ln1_b  = (const float*)d_in[16];
  const float* s_ln2_w  = (const float*)d_in[17];
  const float* s_ln2_b  = (const float*)d_in[18];
  const float* s_ln3_w  = (const float*)d_in[19];
  const float* s_ln3_b  = (const float*)d_in[20];
  const float* s_att1_w = (const float*)d_in[21];
  const float* s_att1_b = (const float*)d_in[22];
  const float* s_att2_w = (const float*)d_in[23];
  const float* s_att2_b = (const float*)d_in[24];
  const float* s_att3_w = (const float*)d_in[25];
  const float* s_att3_b = (const float*)d_in[26];
  const int*  nodes       = (const int*)d_in[27];
  const int*  social_hist = (const int*)d_in[28];
  const void* social_mask = d_in[29];
  const int*  item_hist   = (const int*)d_in[30];
  const int*  rating_hist = (const int*)d_in[31];
  const void* item_mask   = d_in[32];

  // workspace layout (bytes) — total 21,604,096 == round-4-proven footprint.
  // W1hi/W1lo live in hvecbuf's first 16KB: written by prepack, consumed by
  // pre_xbase_mfma, dead before core_mfma overwrites hvecbuf (stream-serial).
  char* ws = (char*)d_ws;
  int*   flag    = (int*)(ws + 0);          // 256
  int*   counter = (int*)(ws + 256);        // 256
  int*   list    = (int*)(ws + 512);        // NT*4 = 67584
  int*   aUid    = (int*)(ws + 68096);      // 67584
  float* uA1buf  = (float*)(ws + 135680);   // NT*64*4 = 4325376
  float* hI2buf  = uA1buf;                  // alias: uA1 dead before K6
  float* hvecbuf = (float*)(ws + 4461056);  // 4325376
  float* hIbuf   = hvecbuf;                 // alias: hvec dead before K7
  short* W1hi    = (short*)(ws + 4461056);  // 8192  (alias hvecbuf[0:2048])
  short* W1lo    = (short*)(ws + 4469248);  // 8192  (alias hvecbuf[2048:4096])
  float* xbase   = (float*)(ws + 8786432);  // 50000*64*4 = 12800000
  float* RW1g    = (float*)(ws + 21586432); // 1280
  short* Bimg1   = (short*)(ws + 21587712); // 8192
  short* Bimg2   = (short*)(ws + 21595904); // 8192

  hipMemsetAsync(counter, 0, 4, stream);
  detect_mask_kernel<<<1, 256, 0, stream>>>((const unsigned int*)social_mask, flag);
  pre_rw_kernel<<<1, 320, 0, stream>>>(rating_w, i_ln1_w, i_ln1_b, RW1g);
  prepack_kernel<<<1, 256, 0, stream>>>(i_att1_w, i_att2_w, i_ln1_w,
                                        Bimg1, Bimg2, W1hi, W1lo);
  pre_xbase_mfma_kernel<<<512, 256, 0, stream>>>(item_w, W1hi, W1lo, xbase);
  build_active_kernel<<<NT / 256, 256, 0, stream>>>(
      nodes, social_hist, social_mask, flag, counter, list, aUid);
  uA1_kernel<<<NT / 64, 256, 0, stream>>>(user_w, i_att1_w, i_att1_b, aUid, counter, uA1buf);
  core_mfma_kernel<<<NT / 4, 256, 0, stream>>>(
      xbase, RW1g, uA1buf, Bimg1, Bimg2, i_att2_b, i_att3_w,
      item_hist, rating_hist, item_mask, flag, aUid, counter, hvecbuf);
  hI2_kernel<<<NT / 64, 256, 0, stream>>>(hvecbuf, i_ln2_w, i_ln2_b, counter, hI2buf);
  final_kernel<<<NT / 32, 256, 0, stream>>>(hI2buf, user_w, i_ln3_w, i_ln3_b,
                                            list, aUid, counter, hIbuf);
  social_kernel<<<BB, 256, 0, stream>>>(
      user_w, hIbuf,
      s_att1_w, s_att1_b, s_att2_w, s_att2_b, s_att3_w, s_att3_b,
      s_ln1_w, s_ln1_b, s_ln2_w, s_ln2_b, s_ln3_w, s_ln3_b,
      nodes, social_mask, flag, (float*)d_out);
}

// Round 7
// 172.357 us; speedup vs baseline: 5.2366x; 1.2373x over previous
//
#include <hip/hip_runtime.h>
#include <math.h>

// ---------------------------------------------------------------------------
// Aggre_social on MI355X — round 7: social phase ported to the MFMA
// wave-per-instance recipe (social_attn) + batched 3-stage tail GEMM.
// Workspace footprint unchanged at 21,604,096 B (proven cap; round-5 lesson).
// Sizes: NU=NI=50000, NR=5, D=64, B=512, LS=32, LI=64.
// ---------------------------------------------------------------------------

#define NII 50000
#define BB 512
#define LSS 32
#define NT 16896   // 512 self + 16384 neighbor instances

typedef short short8 __attribute__((ext_vector_type(8)));
typedef float f32x4 __attribute__((ext_vector_type(4)));

static __device__ __forceinline__ bool mread(const void* p, long i, int mode) {
  if (mode == 0) return ((const int*)p)[i] != 0;       // int32 storage
  if (mode == 2) return ((const float*)p)[i] != 0.0f;  // f32 storage
  return ((const unsigned char*)p)[i] != 0;            // byte storage
}

static __device__ __forceinline__ float wsum(float v) {
#pragma unroll
  for (int s = 1; s < 64; s <<= 1) v += __shfl_xor(v, s);
  return v;
}
static __device__ __forceinline__ float wmax(float v) {
#pragma unroll
  for (int s = 1; s < 64; s <<= 1) v = fmaxf(v, __shfl_xor(v, s));
  return v;
}
static __device__ __forceinline__ float rsum16(float v) {
#pragma unroll
  for (int s = 1; s < 16; s <<= 1) v += __shfl_xor(v, s);
  return v;
}

// f32 -> bf16 (round-to-nearest-even), as raw short.
static __device__ __forceinline__ short bf16rne(float f) {
  unsigned u = __float_as_uint(f);
  u = (u + 0x7FFFu + ((u >> 16) & 1u)) >> 16;
  return (short)u;
}
static __device__ __forceinline__ float bf16tof(short h) {
  return __uint_as_float(((unsigned)(unsigned short)h) << 16);
}

// Intra-wave LDS write->read fence.
static __device__ __forceinline__ void wave_fence() {
  asm volatile("s_waitcnt lgkmcnt(0)" ::: "memory");
  __builtin_amdgcn_sched_barrier(0);
}

// ---------------------------------------------------------------------------
// K0: detect boolean-mask storage. flag[0]: 0=int32, 1=byte, 2=float32.
// Also writes flag[1] = 512 (constant row count for the social uA1 GEMM).
// ---------------------------------------------------------------------------
__global__ void detect_mask_kernel(const unsigned int* __restrict__ sm,
                                   int* __restrict__ flag) {
  __shared__ int notInt, notFloat;
  if (threadIdx.x == 0) { notInt = 0; notFloat = 0; }
  __syncthreads();
  int ni = 0, nf = 0;
  for (int i = threadIdx.x; i < 4096; i += 256) {
    unsigned int x = sm[i];
    if (x > 1u) ni = 1;
    if (x != 0u && x != 0x3F800000u) nf = 1;
  }
  if (ni) atomicOr(&notInt, 1);
  if (nf) atomicOr(&notFloat, 1);
  __syncthreads();
  if (threadIdx.x == 0) {
    flag[0] = notInt ? (notFloat ? 1 : 2) : 0;
    flag[1] = BB;
  }
}

// ---------------------------------------------------------------------------
// K1: RW1g[5][64] = rating_w @ W1[64:128] + i_ln1_b.   <<<1,320>>>
// ---------------------------------------------------------------------------
__global__ void pre_rw_kernel(const float* __restrict__ rating_w,
                              const float* __restrict__ w1,
                              const float* __restrict__ b1,
                              float* __restrict__ RW1g) {
  const int r = threadIdx.x >> 6;
  const int c = threadIdx.x & 63;
  float acc = b1[c];
  for (int k = 0; k < 64; ++k)
    acc = fmaf(rating_w[r * 64 + k], w1[(64 + k) * 64 + c], acc);
  RW1g[r * 64 + c] = acc;
}

// ---------------------------------------------------------------------------
// K1b: pre-pack MFMA B-fragment images (bf16):
//  - B1/B2: item att weights (i_att1_w rows 0..63, i_att2_w), plain bf16
//  - W1hi/W1lo: i_ln1_w rows 0..63 split hi/lo for f32-accurate MFMA
// Layout: idx = ((kb*4+nb)*64 + lane)*8 + e  <->  B[k][col],
//   k = kb*32 + ((lane>>4)&3)*8 + e, col = nb*16 + (lane&15).
// ---------------------------------------------------------------------------
__global__ void prepack_kernel(const float* __restrict__ A1w,
                               const float* __restrict__ A2w,
                               const float* __restrict__ w1,
                               short* __restrict__ B1,
                               short* __restrict__ B2,
                               short* __restrict__ W1hi,
                               short* __restrict__ W1lo) {
  for (int idx = threadIdx.x; idx < 4096; idx += 256) {
    int e = idx & 7, g = idx >> 3;
    int l = g & 63, q = g >> 6;          // q = kb*4+nb
    int kb = q >> 2, nb = q & 3;
    int k = kb * 32 + ((l >> 4) & 3) * 8 + e;
    int col = nb * 16 + (l & 15);
    B1[idx] = bf16rne(A1w[k * 64 + col]);
    B2[idx] = bf16rne(A2w[k * 64 + col]);
    float a = w1[k * 64 + col];
    short h = bf16rne(a);
    W1hi[idx] = h;
    W1lo[idx] = bf16rne(a - bf16tof(h));
  }
}

// ---------------------------------------------------------------------------
// K1c: pre-pack social att B-images (s_att1_w rows 0..63, s_att2_w).
// Launched AFTER core_mfma; outputs overlay the then-dead xbase region.
// ---------------------------------------------------------------------------
__global__ void prepack2_kernel(const float* __restrict__ S1w,
                                const float* __restrict__ S2w,
                                short* __restrict__ B1,
                                short* __restrict__ B2) {
  for (int idx = threadIdx.x; idx < 4096; idx += 256) {
    int e = idx & 7, g = idx >> 3;
    int l = g & 63, q = g >> 6;
    int kb = q >> 2, nb = q & 3;
    int k = kb * 32 + ((l >> 4) & 3) * 8 + e;
    int col = nb * 16 + (l & 15);
    B1[idx] = bf16rne(S1w[k * 64 + col]);
    B2[idx] = bf16rne(S2w[k * 64 + col]);
  }
}

// ---------------------------------------------------------------------------
// K2: xbase[50000][64] = item_w @ W1[0:64] via split-bf16 MFMA (f32-accurate:
// hi*hi + hi*lo + lo*hi; dropped lo*lo <= 1.5e-5). Wave-independent,
// no LDS, no barriers. 3125 row-tiles of 16.
// ---------------------------------------------------------------------------
__global__ __launch_bounds__(256)
void pre_xbase_mfma_kernel(const float* __restrict__ item_w,
                           const short* __restrict__ W1hi,
                           const short* __restrict__ W1lo,
                           float* __restrict__ xbase) {
  const int lane = threadIdx.x & 63, w = threadIdx.x >> 6;
  const int l15 = lane & 15, lg4 = lane >> 4;
  short8 bh[8], bl[8];                     // [kb*4+nb]
#pragma unroll
  for (int q = 0; q < 8; ++q) {
    bh[q] = *(const short8*)(W1hi + (q * 64 + lane) * 8);
    bl[q] = *(const short8*)(W1lo + (q * 64 + lane) * 8);
  }
  const int wid = blockIdx.x * 4 + w;
  const int nw = gridDim.x * 4;
  for (int tile = wid; tile < 3125; tile += nw) {
    const long r0 = (long)tile * 16;
    const float* ap = item_w + (r0 + l15) * 64 + lg4 * 8;
    short8 ah[2], al[2];
#pragma unroll
    for (int kb = 0; kb < 2; ++kb) {
      const float4 a = *(const float4*)(ap + kb * 32);
      const float4 b = *(const float4*)(ap + kb * 32 + 4);
      float v[8] = {a.x, a.y, a.z, a.w, b.x, b.y, b.z, b.w};
      short8 hi, lo;
#pragma unroll
      for (int e = 0; e < 8; ++e) {
        short h = bf16rne(v[e]);
        hi[e] = h;
        lo[e] = bf16rne(v[e] - bf16tof(h));
      }
      ah[kb] = hi;
      al[kb] = lo;
    }
#pragma unroll
    for (int nb = 0; nb < 4; ++nb) {
      f32x4 acc = {0.0f, 0.0f, 0.0f, 0.0f};
      acc = __builtin_amdgcn_mfma_f32_16x16x32_bf16(ah[0], bh[0 * 4 + nb], acc, 0, 0, 0);
      acc = __builtin_amdgcn_mfma_f32_16x16x32_bf16(ah[1], bh[1 * 4 + nb], acc, 0, 0, 0);
      acc = __builtin_amdgcn_mfma_f32_16x16x32_bf16(ah[0], bl[0 * 4 + nb], acc, 0, 0, 0);
      acc = __builtin_amdgcn_mfma_f32_16x16x32_bf16(ah[1], bl[1 * 4 + nb], acc, 0, 0, 0);
      acc = __builtin_amdgcn_mfma_f32_16x16x32_bf16(al[0], bh[0 * 4 + nb], acc, 0, 0, 0);
      acc = __builtin_amdgcn_mfma_f32_16x16x32_bf16(al[1], bh[1 * 4 + nb], acc, 0, 0, 0);
#pragma unroll
      for (int r = 0; r < 4; ++r)
        xbase[(r0 + lg4 * 4 + r) * 64 + nb * 16 + l15] = acc[r];
    }
  }
}

// ---------------------------------------------------------------------------
// K3: compact active instance list.  <<<66,256>>>
// ---------------------------------------------------------------------------
__global__ void build_active_kernel(const int* __restrict__ nodes,
                                    const int* __restrict__ social_hist,
                                    const void* __restrict__ social_mask,
                                    const int* __restrict__ flagp,
                                    int* __restrict__ counter,
                                    int* __restrict__ list,
                                    int* __restrict__ aUid) {
  const int t = blockIdx.x * 256 + threadIdx.x;
  if (t >= NT) return;
  const int mode = flagp[0];
  int uid;
  bool active;
  if (t < BB) {
    active = true;
    uid = nodes[t];
  } else {
    int nb = t - BB;
    int b = nb >> 5, l = nb & 31;
    long mi = (long)nodes[b] * LSS + l;
    active = mread(social_mask, mi, mode);
    uid = active ? social_hist[mi] : 0;
  }
  if (active) {
    int pos = atomicAdd(counter, 1);
    list[pos] = t;
    aUid[pos] = uid;
  }
}

// ---------------------------------------------------------------------------
// K4: uA1buf[idx] = user_w[idxsrc[idx]] @ A1w[64:128] + A1b.  64 rows/block.
// Generic: used for the item path (idxsrc=aUid, count=*counter) and the
// social path (idxsrc=nodes, count=flag[1]=512).
// ---------------------------------------------------------------------------
__global__ __launch_bounds__(256, 2)
void uA1_kernel(const float* __restrict__ user_w,
                const float* __restrict__ A1w, const float* __restrict__ A1b,
                const int* __restrict__ idxsrc, const int* __restrict__ nActp,
                float* __restrict__ uA1buf) {
  const int tid = threadIdx.x, lane = tid & 63, w = tid >> 6;
  const int i0 = blockIdx.x * 64;
  const int nA = nActp[0];
  if (i0 >= nA) return;
  __shared__ float sW[64][64], sU[64][64];
  __shared__ float sb[64];
  __shared__ int sUid[64];
  for (int i = tid; i < 4096; i += 256) sW[i >> 6][i & 63] = A1w[4096 + i];
  if (tid < 64) {
    sb[tid] = A1b[tid];
    sUid[tid] = (i0 + tid < nA) ? idxsrc[i0 + tid] : 0;
  }
  __syncthreads();
  for (int i = tid; i < 4096; i += 256) {
    int r = i >> 6, c = i & 63;
    sU[r][c] = user_w[(long)sUid[r] * 64 + c];
  }
  __syncthreads();
  float acc[16];
#pragma unroll
  for (int r = 0; r < 16; ++r) acc[r] = sb[lane];
  for (int k = 0; k < 64; k += 4) {
    float wv0 = sW[k][lane], wv1 = sW[k + 1][lane];
    float wv2 = sW[k + 2][lane], wv3 = sW[k + 3][lane];
#pragma unroll
    for (int r = 0; r < 16; ++r) {
      const float4 xv = *(const float4*)(&sU[w * 16 + r][k]);
      acc[r] = fmaf(xv.x, wv0, acc[r]);
      acc[r] = fmaf(xv.y, wv1, acc[r]);
      acc[r] = fmaf(xv.z, wv2, acc[r]);
      acc[r] = fmaf(xv.w, wv3, acc[r]);
    }
  }
#pragma unroll
  for (int r = 0; r < 16; ++r) {
    int row = i0 + w * 16 + r;
    if (row < nA) uA1buf[(long)row * 64 + lane] = acc[r];
  }
}

// ---------------------------------------------------------------------------
// K5: CORE — wave-per-instance attention with MFMA bf16 logits.
// 256 threads = 4 independent waves, no __syncthreads at all.
// B-fragment images held in registers (loaded once per wave).
// ---------------------------------------------------------------------------
__global__ __launch_bounds__(256)
void core_mfma_kernel(const float* __restrict__ xbase,
                      const float* __restrict__ RW1g,
                      const float* __restrict__ uA1buf,
                      const short* __restrict__ Bimg1,
                      const short* __restrict__ Bimg2,
                      const float* __restrict__ A2b,
                      const float* __restrict__ A3w,
                      const int* __restrict__ item_hist,
                      const int* __restrict__ rating_hist,
                      const void* __restrict__ item_mask,
                      const int* __restrict__ flagp,
                      const int* __restrict__ aUid,
                      const int* __restrict__ nActp,
                      float* __restrict__ hvecbuf) {
  __shared__ __align__(16) char smem[4][3072];
  const int tid = threadIdx.x, lane = tid & 63, w = tid >> 6;
  short* h1w = (short*)(smem[w]);          // [16][80] bf16
  float* lgw = (float*)(smem[w] + 2560);   // [64] logits
  int* cw = (int*)(smem[w] + 2816);        // [64] packed (item<<3)|rating

  const int mode = flagp[0];
  const int nA = nActp[0];
  const float a2bv = A2b[lane];
  const float a3v = A3w[lane];
  const int l15 = lane & 15;
  const int lg4 = lane >> 4;

  short8 b1f[8], b2f[8];                   // [kb*4+nb], register-resident
#pragma unroll
  for (int q = 0; q < 8; ++q) {
    b1f[q] = *(const short8*)(Bimg1 + (q * 64 + lane) * 8);
    b2f[q] = *(const short8*)(Bimg2 + (q * 64 + lane) * 8);
  }

  for (int idx = blockIdx.x * 4 + w; idx < nA; idx += gridDim.x * 4) {
    wave_fence();  // prior-instance LDS reads complete before overwrite
    const long uid = aUid[idx];

    // ---- compact item history (lane covers LI=64) ----
    const long mbase = uid * 64;
    bool m = mread(item_mask, mbase + lane, mode);
    unsigned long long bal = __ballot(m);
    const int nact = (int)__popcll(bal);
    int pos = (int)__popcll(bal & ((1ull << lane) - 1ull));
    if (m) cw[pos] = (item_hist[mbase + lane] << 3) | rating_hist[mbase + lane];
    const float uA1v = uA1buf[(long)idx * 64 + lane];
    wave_fence();

    // ---- logits via MFMA, 16-row chunks ----
    const int ng = (nact + 15) >> 4;
    for (int mc = 0; mc < ng; ++mc) {
      wave_fence();  // prior chunk's H1 reads done before overwrite
      int row = mc * 16 + l15;
      if (row >= nact) row = nact - 1;
      const int p = cw[row];
      const long it = p >> 3;
      const int rt = p & 7;
      short8 xa[2];
#pragma unroll
      for (int kb = 0; kb < 2; ++kb) {
        const int koff = kb * 32 + lg4 * 8;
        const float* xp = xbase + it * 64 + koff;
        const float* rp = RW1g + rt * 64 + koff;
        const float4 a = *(const float4*)xp;
        const float4 b = *(const float4*)(xp + 4);
        const float4 c = *(const float4*)rp;
        const float4 d = *(const float4*)(rp + 4);
        short8 f;
        f[0] = bf16rne(fmaxf(a.x + c.x, 0.0f));
        f[1] = bf16rne(fmaxf(a.y + c.y, 0.0f));
        f[2] = bf16rne(fmaxf(a.z + c.z, 0.0f));
        f[3] = bf16rne(fmaxf(a.w + c.w, 0.0f));
        f[4] = bf16rne(fmaxf(b.x + d.x, 0.0f));
        f[5] = bf16rne(fmaxf(b.y + d.y, 0.0f));
        f[6] = bf16rne(fmaxf(b.z + d.z, 0.0f));
        f[7] = bf16rne(fmaxf(b.w + d.w, 0.0f));
        xa[kb] = f;
      }
      // att1: H1 = relu(X @ A1a + uA1), one N-block at a time
#pragma unroll
      for (int nb = 0; nb < 4; ++nb) {
        const float ui = __shfl(uA1v, nb * 16 + l15);
        f32x4 acc = {ui, ui, ui, ui};
        acc = __builtin_amdgcn_mfma_f32_16x16x32_bf16(xa[0], b1f[0 * 4 + nb], acc, 0, 0, 0);
        acc = __builtin_amdgcn_mfma_f32_16x16x32_bf16(xa[1], b1f[1 * 4 + nb], acc, 0, 0, 0);
#pragma unroll
        for (int r = 0; r < 4; ++r)
          h1w[(lg4 * 4 + r) * 80 + nb * 16 + l15] = bf16rne(fmaxf(acc[r], 0.0f));
      }
      wave_fence();
      // att2 + logit
      short8 ha[2];
      ha[0] = *(const short8*)(h1w + l15 * 80 + lg4 * 8);
      ha[1] = *(const short8*)(h1w + l15 * 80 + 32 + lg4 * 8);
      float t0 = 0.0f, t1 = 0.0f, t2 = 0.0f, t3 = 0.0f;
#pragma unroll
      for (int nb = 0; nb < 4; ++nb) {
        const float b2 = __shfl(a2bv, nb * 16 + l15);
        f32x4 acc = {b2, b2, b2, b2};
        acc = __builtin_amdgcn_mfma_f32_16x16x32_bf16(ha[0], b2f[0 * 4 + nb], acc, 0, 0, 0);
        acc = __builtin_amdgcn_mfma_f32_16x16x32_bf16(ha[1], b2f[1 * 4 + nb], acc, 0, 0, 0);
        const float a3c = __shfl(a3v, nb * 16 + l15);
        t0 = fmaf(fmaxf(acc[0], 0.0f), a3c, t0);
        t1 = fmaf(fmaxf(acc[1], 0.0f), a3c, t1);
        t2 = fmaf(fmaxf(acc[2], 0.0f), a3c, t2);
        t3 = fmaf(fmaxf(acc[3], 0.0f), a3c, t3);
      }
      t0 = rsum16(t0); t1 = rsum16(t1); t2 = rsum16(t2); t3 = rsum16(t3);
      if (l15 == 0) {
        const int jb = mc * 16 + lg4 * 4;
        lgw[jb + 0] = t0;
        lgw[jb + 1] = t1;
        lgw[jb + 2] = t2;
        lgw[jb + 3] = t3;
      }
    }
    wave_fence();

    // ---- softmax over lanes (lane j holds logit_j; b3 dropped: invariant) ----
    const bool valid = (lane < nact);
    float lv = valid ? lgw[lane] : -1e30f;
    float mx = wmax(lv);
    float e = valid ? __expf(lv - mx) : 0.0f;
    float s = wsum(e);
    const float alpha = e / s;

    // ---- hI = sum_j alpha_j * x_j  (exact f32 re-gather) ----
    float hi = 0.0f;
    for (int j = 0; j < nact; ++j) {
      const float aj = __shfl(alpha, j);
      const int p = cw[j];
      const float xv =
          fmaxf(xbase[(long)(p >> 3) * 64 + lane] + RW1g[(p & 7) * 64 + lane], 0.0f);
      hi = fmaf(aj, xv, hi);
    }
    hvecbuf[(long)idx * 64 + lane] = hi;
  }
}

// ---------------------------------------------------------------------------
// K6: hI2buf[idx] = relu(hvecbuf[idx] @ i_ln2 + b).  64 rows / block.
// ---------------------------------------------------------------------------
__global__ __launch_bounds__(256, 2)
void hI2_kernel(const float* __restrict__ hvecbuf,
                const float* __restrict__ W2w, const float* __restrict__ W2b,
                const int* __restrict__ nActp, float* __restrict__ hI2buf) {
  const int tid = threadIdx.x, lane = tid & 63, w = tid >> 6;
  const int i0 = blockIdx.x * 64;
  const int nA = nActp[0];
  if (i0 >= nA) return;
  __shared__ float sW[64][64], sX[64][64];
  __shared__ float sb[64];
  for (int i = tid; i < 4096; i += 256) sW[i >> 6][i & 63] = W2w[i];
  if (tid < 64) sb[tid] = W2b[tid];
  for (int i = tid; i < 4096; i += 256) {
    int r = i >> 6, c = i & 63;
    sX[r][c] = (i0 + r < nA) ? hvecbuf[(long)(i0 + r) * 64 + c] : 0.0f;
  }
  __syncthreads();
  float acc[16];
#pragma unroll
  for (int r = 0; r < 16; ++r) acc[r] = sb[lane];
  for (int k = 0; k < 64; k += 4) {
    float wv0 = sW[k][lane], wv1 = sW[k + 1][lane];
    float wv2 = sW[k + 2][lane], wv3 = sW[k + 3][lane];
#pragma unroll
    for (int r = 0; r < 16; ++r) {
      const float4 xv = *(const float4*)(&sX[w * 16 + r][k]);
      acc[r] = fmaf(xv.x, wv0, acc[r]);
      acc[r] = fmaf(xv.y, wv1, acc[r]);
      acc[r] = fmaf(xv.z, wv2, acc[r]);
      acc[r] = fmaf(xv.w, wv3, acc[r]);
    }
  }
#pragma unroll
  for (int r = 0; r < 16; ++r) {
    int row = i0 + w * 16 + r;
    if (row < nA) hI2buf[(long)row * 64 + lane] = fmaxf(acc[r], 0.0f);
  }
}

// ---------------------------------------------------------------------------
// K7: hIbuf[inst] = relu([u ; hI2] @ i_ln3 + b).  32 rows / block (k=128).
// ---------------------------------------------------------------------------
__global__ __launch_bounds__(256, 2)
void final_kernel(const float* __restrict__ hI2buf,
                  const float* __restrict__ user_w,
                  const float* __restrict__ W3w, const float* __restrict__ W3b,
                  const int* __restrict__ list, const int* __restrict__ aUid,
                  const int* __restrict__ nActp, float* __restrict__ hIbuf) {
  const int tid = threadIdx.x, lane = tid & 63, w = tid >> 6;
  const int i0 = blockIdx.x * 32;
  const int nA = nActp[0];
  if (i0 >= nA) return;
  __shared__ float sW[128][64];
  __shared__ float sX[32][128];
  __shared__ float sb[64];
  __shared__ int sUid[32], sInst[32];
  for (int i = tid; i < 8192; i += 256) sW[i >> 6][i & 63] = W3w[i];
  if (tid < 64) sb[tid] = W3b[tid];
  if (tid < 32) {
    bool ok = (i0 + tid) < nA;
    sUid[tid] = ok ? aUid[i0 + tid] : 0;
    sInst[tid] = ok ? list[i0 + tid] : 0;
  }
  __syncthreads();
  for (int i = tid; i < 4096; i += 256) {
    int r = i >> 7, c = i & 127;
    sX[r][c] = (c < 64) ? user_w[(long)sUid[r] * 64 + c]
                        : hI2buf[(long)(i0 + r) * 64 + (c - 64)];
  }
  __syncthreads();
  float acc[8];
#pragma unroll
  for (int r = 0; r < 8; ++r) acc[r] = sb[lane];
  for (int k = 0; k < 128; k += 4) {
    float wv0 = sW[k][lane], wv1 = sW[k + 1][lane];
    float wv2 = sW[k + 2][lane], wv3 = sW[k + 3][lane];
#pragma unroll
    for (int r = 0; r < 8; ++r) {
      const float4 xv = *(const float4*)(&sX[w * 8 + r][k]);
      acc[r] = fmaf(xv.x, wv0, acc[r]);
      acc[r] = fmaf(xv.y, wv1, acc[r]);
      acc[r] = fmaf(xv.z, wv2, acc[r]);
      acc[r] = fmaf(xv.w, wv3, acc[r]);
    }
  }
#pragma unroll
  for (int r = 0; r < 8; ++r) {
    int row = i0 + w * 8 + r;
    if (row < nA)
      hIbuf[(long)sInst[w * 8 + r] * 64 + lane] = fmaxf(acc[r], 0.0f);
  }
}

// ---------------------------------------------------------------------------
// K8: social attention — wave-per-batch-element, MFMA bf16 logits,
// zero barriers. 128 blocks x 256 thr = 512 waves (one per b).
// ---------------------------------------------------------------------------
__global__ __launch_bounds__(256)
void social_attn_kernel(const float* __restrict__ hIbuf,
                        const float* __restrict__ uA1Sbuf,
                        const short* __restrict__ S1img,
                        const short* __restrict__ S2img,
                        const float* __restrict__ A2b,
                        const float* __restrict__ A3w,
                        const int* __restrict__ nodes,
                        const void* __restrict__ social_mask,
                        const int* __restrict__ flagp,
                        float* __restrict__ hSbuf) {
  __shared__ __align__(16) char smem[4][3072];
  const int tid = threadIdx.x, lane = tid & 63, w = tid >> 6;
  short* h1w = (short*)(smem[w]);          // [16][80] bf16
  float* lgw = (float*)(smem[w] + 2560);   // [32] logits
  int* cw = (int*)(smem[w] + 2816);        // [32] neighbor slots

  const int mode = flagp[0];
  const int l15 = lane & 15;
  const int lg4 = lane >> 4;
  const float a2bv = A2b[lane];
  const float a3v = A3w[lane];

  short8 s1f[8], s2f[8];
#pragma unroll
  for (int q = 0; q < 8; ++q) {
    s1f[q] = *(const short8*)(S1img + (q * 64 + lane) * 8);
    s2f[q] = *(const short8*)(S2img + (q * 64 + lane) * 8);
  }

  const int b = blockIdx.x * 4 + w;        // grid is exactly 128*4 = 512
  const long uid = nodes[b];

  bool m = (lane < LSS) ? mread(social_mask, uid * LSS + lane, mode) : false;
  unsigned long long bal = __ballot(m);
  const int nval = (int)__popcll(bal);
  int pos = (int)__popcll(bal & ((1ull << lane) - 1ull));
  if (m) cw[pos] = lane;
  const float uA1v = uA1Sbuf[(long)b * 64 + lane];
  wave_fence();

  const long hbase = 512L + (long)b * 32;
  const int ng = (nval + 15) >> 4;
  for (int mc = 0; mc < ng; ++mc) {
    wave_fence();
    int row = mc * 16 + l15;
    if (row >= nval) row = nval - 1;
    const long hrow = hbase + cw[row];
    short8 xa[2];
#pragma unroll
    for (int kb = 0; kb < 2; ++kb) {
      const float* xp = hIbuf + hrow * 64 + kb * 32 + lg4 * 8;
      const float4 a = *(const float4*)xp;
      const float4 bb = *(const float4*)(xp + 4);
      short8 f;
      f[0] = bf16rne(a.x);  f[1] = bf16rne(a.y);
      f[2] = bf16rne(a.z);  f[3] = bf16rne(a.w);
      f[4] = bf16rne(bb.x); f[5] = bf16rne(bb.y);
      f[6] = bf16rne(bb.z); f[7] = bf16rne(bb.w);
      xa[kb] = f;
    }
#pragma unroll
    for (int nb = 0; nb < 4; ++nb) {
      const float ui = __shfl(uA1v, nb * 16 + l15);
      f32x4 acc = {ui, ui, ui, ui};
      acc = __builtin_amdgcn_mfma_f32_16x16x32_bf16(xa[0], s1f[0 * 4 + nb], acc, 0, 0, 0);
      acc = __builtin_amdgcn_mfma_f32_16x16x32_bf16(xa[1], s1f[1 * 4 + nb], acc, 0, 0, 0);
#pragma unroll
      for (int r = 0; r < 4; ++r)
        h1w[(lg4 * 4 + r) * 80 + nb * 16 + l15] = bf16rne(fmaxf(acc[r], 0.0f));
    }
    wave_fence();
    short8 ha[2];
    ha[0] = *(const short8*)(h1w + l15 * 80 + lg4 * 8);
    ha[1] = *(const short8*)(h1w + l15 * 80 + 32 + lg4 * 8);
    float t0 = 0.0f, t1 = 0.0f, t2 = 0.0f, t3 = 0.0f;
#pragma unroll
    for (int nb = 0; nb < 4; ++nb) {
      const float b2 = __shfl(a2bv, nb * 16 + l15);
      f32x4 acc = {b2, b2, b2, b2};
      acc = __builtin_amdgcn_mfma_f32_16x16x32_bf16(ha[0], s2f[0 * 4 + nb], acc, 0, 0, 0);
      acc = __builtin_amdgcn_mfma_f32_16x16x32_bf16(ha[1], s2f[1 * 4 + nb], acc, 0, 0, 0);
      const float a3c = __shfl(a3v, nb * 16 + l15);
      t0 = fmaf(fmaxf(acc[0], 0.0f), a3c, t0);
      t1 = fmaf(fmaxf(acc[1], 0.0f), a3c, t1);
      t2 = fmaf(fmaxf(acc[2], 0.0f), a3c, t2);
      t3 = fmaf(fmaxf(acc[3], 0.0f), a3c, t3);
    }
    t0 = rsum16(t0); t1 = rsum16(t1); t2 = rsum16(t2); t3 = rsum16(t3);
    if (l15 == 0) {
      const int jb = mc * 16 + lg4 * 4;
      lgw[jb + 0] = t0;
      lgw[jb + 1] = t1;
      lgw[jb + 2] = t2;
      lgw[jb + 3] = t3;
    }
  }
  wave_fence();

  const bool valid = (lane < nval);
  float lv = valid ? lgw[lane] : -1e30f;
  float mx = wmax(lv);
  float e = valid ? __expf(lv - mx) : 0.0f;
  float s = wsum(e);
  const float beta = e / s;

  float hs = 0.0f;
  for (int j = 0; j < nval; ++j) {
    const float bj = __shfl(beta, j);
    hs = fmaf(bj, hIbuf[(hbase + cw[j]) * 64 + lane], hs);
  }
  hSbuf[(long)b * 64 + lane] = hs;
}

// ---------------------------------------------------------------------------
// K9: social tail — 3-stage batched GEMM: vecB = relu(hS@L1+b1);
// f = relu([self;vecB]@L2+b2); out = relu(f@L3+b3). 32 rows / block.
// ---------------------------------------------------------------------------
__global__ __launch_bounds__(256)
void social_tail_kernel(const float* __restrict__ hSbuf,
                        const float* __restrict__ hIbuf,
                        const float* __restrict__ L1w, const float* __restrict__ L1b,
                        const float* __restrict__ L2w, const float* __restrict__ L2b,
                        const float* __restrict__ L3w, const float* __restrict__ L3b,
                        float* __restrict__ out) {
  __shared__ float sW[128][64];   // 32KB, reloaded per stage
  __shared__ float sX[32][128];   // 16KB: cols 0:64 = self, 64:128 = stage io
  const int tid = threadIdx.x, lane = tid & 63, w = tid >> 6;
  const int b0 = blockIdx.x * 32;

  for (int i = tid; i < 4096; i += 256) sW[i >> 6][i & 63] = L1w[i];
  for (int i = tid; i < 2048; i += 256) {
    int r = i >> 6, c = i & 63;
    sX[r][64 + c] = hSbuf[(long)(b0 + r) * 64 + c];
    sX[r][c] = hIbuf[(long)(b0 + r) * 64 + c];
  }
  __syncthreads();

  float acc[8];
  // stage 1: vecB = relu(hS @ L1 + b1)
  {
    const float bv = L1b[lane];
#pragma unroll
    for (int r = 0; r < 8; ++r) acc[r] = bv;
    for (int k = 0; k < 64; k += 4) {
      float wv0 = sW[k][lane], wv1 = sW[k + 1][lane];
      float wv2 = sW[k + 2][lane], wv3 = sW[k + 3][lane];
#pragma unroll
      for (int r = 0; r < 8; ++r) {
        const float4 xv = *(const float4*)(&sX[w * 8 + r][64 + k]);
        acc[r] = fmaf(xv.x, wv0, acc[r]);
        acc[r] = fmaf(xv.y, wv1, acc[r]);
        acc[r] = fmaf(xv.z, wv2, acc[r]);
        acc[r] = fmaf(xv.w, wv3, acc[r]);
      }
    }
  }
  __syncthreads();
#pragma unroll
  for (int r = 0; r < 8; ++r) sX[w * 8 + r][64 + lane] = fmaxf(acc[r], 0.0f);
  for (int i = tid; i < 8192; i += 256) sW[i >> 6][i & 63] = L2w[i];
  __syncthreads();

  // stage 2: f = relu([self ; vecB] @ L2 + b2)
  {
    const float bv = L2b[lane];
#pragma unroll
    for (int r = 0; r < 8; ++r) acc[r] = bv;
    for (int k = 0; k < 128; k += 4) {
      float wv0 = sW[k][lane], wv1 = sW[k + 1][lane];
      float wv2 = sW[k + 2][lane], wv3 = sW[k + 3][lane];
#pragma unroll
      for (int r = 0; r < 8; ++r) {
        const float4 xv = *(const float4*)(&sX[w * 8 + r][k]);
        acc[r] = fmaf(xv.x, wv0, acc[r]);
        acc[r] = fmaf(xv.y, wv1, acc[r]);
        acc[r] = fmaf(xv.z, wv2, acc[r]);
        acc[r] = fmaf(xv.w, wv3, acc[r]);
      }
    }
  }
  __syncthreads();
#pragma unroll
  for (int r = 0; r < 8; ++r) sX[w * 8 + r][64 + lane] = fmaxf(acc[r], 0.0f);
  for (int i = tid; i < 4096; i += 256) sW[i >> 6][i & 63] = L3w[i];
  __syncthreads();

  // stage 3: out = relu(f @ L3 + b3)
  {
    const float bv = L3b[lane];
#pragma unroll
    for (int r = 0; r < 8; ++r) acc[r] = bv;
    for (int k = 0; k < 64; k += 4) {
      float wv0 = sW[k][lane], wv1 = sW[k + 1][lane];
      float wv2 = sW[k + 2][lane], wv3 = sW[k + 3][lane];
#pragma unroll
      for (int r = 0; r < 8; ++r) {
        const float4 xv = *(const float4*)(&sX[w * 8 + r][64 + k]);
        acc[r] = fmaf(xv.x, wv0, acc[r]);
        acc[r] = fmaf(xv.y, wv1, acc[r]);
        acc[r] = fmaf(xv.z, wv2, acc[r]);
        acc[r] = fmaf(xv.w, wv3, acc[r]);
      }
    }
#pragma unroll
    for (int r = 0; r < 8; ++r)
      out[(long)(b0 + w * 8 + r) * 64 + lane] = fmaxf(acc[r], 0.0f);
  }
}

// ---------------------------------------------------------------------------
extern "C" void kernel_launch(void* const* d_in, const int* in_sizes, int n_in,
                              void* d_out, int out_size, void* d_ws, size_t ws_size,
                              hipStream_t stream) {
  const float* user_w   = (const float*)d_in[0];
  const float* item_w   = (const float*)d_in[1];
  const float* rating_w = (const float*)d_in[2];
  const float* i_ln1_w  = (const float*)d_in[3];
  const float* i_ln1_b  = (const float*)d_in[4];
  const float* i_ln2_w  = (const float*)d_in[5];
  const float* i_ln2_b  = (const float*)d_in[6];
  const float* i_ln3_w  = (const float*)d_in[7];
  const float* i_ln3_b  = (const float*)d_in[8];
  const float* i_att1_w = (const float*)d_in[9];
  const float* i_att1_b = (const float*)d_in[10];
  const float* i_att2_w = (const float*)d_in[11];
  const float* i_att2_b = (const float*)d_in[12];
  const float* i_att3_w = (const float*)d_in[13];
  const float* i_att3_b = (const float*)d_in[14];
  const float* s_ln1_w  = (const float*)d_in[15];
  const float* s_ln1_b  = (const float*)d_in[16];
  const float* s_ln2_w  = (const float*)d_in[17];
  const float* s_ln2_b  = (const float*)d_in[18];
  const float* s_ln3_w  = (const float*)d_in[19];
  const float* s_ln3_b  = (const float*)d_in[20];
  const float* s_att1_w = (const float*)d_in[21];
  const float* s_att1_b = (const float*)d_in[22];
  const float* s_att2_w = (const float*)d_in[23];
  const float* s_att2_b = (const float*)d_in[24];
  const float* s_att3_w = (const float*)d_in[25];
  const float* s_att3_b = (const float*)d_in[26];
  const int*  nodes       = (const int*)d_in[27];
  const int*  social_hist = (const int*)d_in[28];
  const void* social_mask = d_in[29];
  const int*  item_hist   = (const int*)d_in[30];
  const int*  rating_hist = (const int*)d_in[31];
  const void* item_mask   = d_in[32];

  // workspace layout (bytes) — total 21,604,096 (proven cap; do not exceed).
  // Aliases (stream-serial liveness):
  //  - W1hi/W1lo in hvecbuf[0:16KB]: prepack -> pre_xbase, dead before core.
  //  - S1img/S2img in xbase[0:16KB]: prepack2 (after core) -> social_attn.
  //  - uA1Sbuf/hSbuf in uA1buf region: written after final consumed hI2buf.
  char* ws = (char*)d_ws;
  int*   flag    = (int*)(ws + 0);          // 256 (flag[0]=mode, flag[1]=512)
  int*   counter = (int*)(ws + 256);        // 256
  int*   list    = (int*)(ws + 512);        // NT*4 = 67584
  int*   aUid    = (int*)(ws + 68096);      // 67584
  float* uA1buf  = (float*)(ws + 135680);   // NT*64*4 = 4325376
  float* hI2buf  = uA1buf;                  // alias: uA1 dead before K6
  float* uA1Sbuf = (float*)(ws + 135680);             // 131072 (after final)
  float* hSbuf   = (float*)(ws + 135680 + 131072);    // 131072 (after final)
  float* hvecbuf = (float*)(ws + 4461056);  // 4325376
  float* hIbuf   = hvecbuf;                 // alias: hvec dead before K7
  short* W1hi    = (short*)(ws + 4461056);  // 8192  (alias hvecbuf[0:2048])
  short* W1lo    = (short*)(ws + 4469248);  // 8192  (alias hvecbuf[2048:4096])
  float* xbase   = (float*)(ws + 8786432);  // 50000*64*4 = 12800000
  short* S1img   = (short*)(ws + 8786432);  // 8192  (alias xbase, after core)
  short* S2img   = (short*)(ws + 8794624);  // 8192  (alias xbase, after core)
  float* RW1g    = (float*)(ws + 21586432); // 1280
  short* Bimg1   = (short*)(ws + 21587712); // 8192
  short* Bimg2   = (short*)(ws + 21595904); // 8192

  hipMemsetAsync(counter, 0, 4, stream);
  detect_mask_kernel<<<1, 256, 0, stream>>>((const unsigned int*)social_mask, flag);
  pre_rw_kernel<<<1, 320, 0, stream>>>(rating_w, i_ln1_w, i_ln1_b, RW1g);
  prepack_kernel<<<1, 256, 0, stream>>>(i_att1_w, i_att2_w, i_ln1_w,
                                        Bimg1, Bimg2, W1hi, W1lo);
  pre_xbase_mfma_kernel<<<512, 256, 0, stream>>>(item_w, W1hi, W1lo, xbase);
  build_active_kernel<<<NT / 256, 256, 0, stream>>>(
      nodes, social_hist, social_mask, flag, counter, list, aUid);
  uA1_kernel<<<NT / 64, 256, 0, stream>>>(user_w, i_att1_w, i_att1_b,
                                          aUid, counter, uA1buf);
  core_mfma_kernel<<<NT / 4, 256, 0, stream>>>(
      xbase, RW1g, uA1buf, Bimg1, Bimg2, i_att2_b, i_att3_w,
      item_hist, rating_hist, item_mask, flag, aUid, counter, hvecbuf);
  prepack2_kernel<<<1, 256, 0, stream>>>(s_att1_w, s_att2_w, S1img, S2img);
  hI2_kernel<<<NT / 64, 256, 0, stream>>>(hvecbuf, i_ln2_w, i_ln2_b, counter, hI2buf);
  final_kernel<<<NT / 32, 256, 0, stream>>>(hI2buf, user_w, i_ln3_w, i_ln3_b,
                                            list, aUid, counter, hIbuf);
  uA1_kernel<<<BB / 64, 256, 0, stream>>>(user_w, s_att1_w, s_att1_b,
                                          nodes, flag + 1, uA1Sbuf);
  social_attn_kernel<<<BB / 4, 256, 0, stream>>>(
      hIbuf, uA1Sbuf, S1img, S2img, s_att2_b, s_att3_w,
      nodes, social_mask, flag, hSbuf);
  social_tail_kernel<<<BB / 32, 256, 0, stream>>>(
      hSbuf, hIbuf, s_ln1_w, s_ln1_b, s_ln2_w, s_ln2_b, s_ln3_w, s_ln3_b,
      (float*)d_out);
}

// Round 8
// 130.008 us; speedup vs baseline: 6.9424x; 1.3257x over previous
//
#include <hip/hip_runtime.h>
#include <math.h>

// ---------------------------------------------------------------------------
// Aggre_social on MI355X — round 8: core occupancy fix (B-images in LDS,
// 8-wave blocks, <=64 VGPR) + tail fusions (hI2+final; uA1S+attn+tail;
// setup kernels merged). Workspace layout byte-identical to round 7.
// Sizes: NU=NI=50000, NR=5, D=64, B=512, LS=32, LI=64.
// ---------------------------------------------------------------------------

#define NII 50000
#define BB 512
#define LSS 32
#define NT 16896   // 512 self + 16384 neighbor instances

typedef short short8 __attribute__((ext_vector_type(8)));
typedef float f32x4 __attribute__((ext_vector_type(4)));

static __device__ __forceinline__ bool mread(const void* p, long i, int mode) {
  if (mode == 0) return ((const int*)p)[i] != 0;       // int32 storage
  if (mode == 2) return ((const float*)p)[i] != 0.0f;  // f32 storage
  return ((const unsigned char*)p)[i] != 0;            // byte storage
}

static __device__ __forceinline__ float wsum(float v) {
#pragma unroll
  for (int s = 1; s < 64; s <<= 1) v += __shfl_xor(v, s);
  return v;
}
static __device__ __forceinline__ float wmax(float v) {
#pragma unroll
  for (int s = 1; s < 64; s <<= 1) v = fmaxf(v, __shfl_xor(v, s));
  return v;
}
static __device__ __forceinline__ float rsum16(float v) {
#pragma unroll
  for (int s = 1; s < 16; s <<= 1) v += __shfl_xor(v, s);
  return v;
}

// f32 -> bf16 (round-to-nearest-even), as raw short.
static __device__ __forceinline__ short bf16rne(float f) {
  unsigned u = __float_as_uint(f);
  u = (u + 0x7FFFu + ((u >> 16) & 1u)) >> 16;
  return (short)u;
}
static __device__ __forceinline__ float bf16tof(short h) {
  return __uint_as_float(((unsigned)(unsigned short)h) << 16);
}

// Intra-wave LDS write->read fence.
static __device__ __forceinline__ void wave_fence() {
  asm volatile("s_waitcnt lgkmcnt(0)" ::: "memory");
  __builtin_amdgcn_sched_barrier(0);
}

// ---------------------------------------------------------------------------
// K0: fused setup. block 0: mask-format detect; block 1: RW1g matvec;
// block 2: prepack item-att B-images + W1 hi/lo split.   <<<3,256>>>
// ---------------------------------------------------------------------------
__global__ void setup_kernel(const unsigned int* __restrict__ sm,
                             int* __restrict__ flag,
                             const float* __restrict__ rating_w,
                             const float* __restrict__ w1,
                             const float* __restrict__ b1,
                             float* __restrict__ RW1g,
                             const float* __restrict__ A1w,
                             const float* __restrict__ A2w,
                             short* __restrict__ B1,
                             short* __restrict__ B2,
                             short* __restrict__ W1hi,
                             short* __restrict__ W1lo) {
  const int tid = threadIdx.x;
  if (blockIdx.x == 0) {
    __shared__ int notInt, notFloat;
    if (tid == 0) { notInt = 0; notFloat = 0; }
    __syncthreads();
    int ni = 0, nf = 0;
    for (int i = tid; i < 4096; i += 256) {
      unsigned int x = sm[i];
      if (x > 1u) ni = 1;
      if (x != 0u && x != 0x3F800000u) nf = 1;
    }
    if (ni) atomicOr(&notInt, 1);
    if (nf) atomicOr(&notFloat, 1);
    __syncthreads();
    if (tid == 0) flag[0] = notInt ? (notFloat ? 1 : 2) : 0;
  } else if (blockIdx.x == 1) {
    for (int t = tid; t < 320; t += 256) {
      const int r = t >> 6, c = t & 63;
      float acc = b1[c];
      for (int k = 0; k < 64; ++k)
        acc = fmaf(rating_w[r * 64 + k], w1[(64 + k) * 64 + c], acc);
      RW1g[r * 64 + c] = acc;
    }
  } else {
    for (int idx = tid; idx < 4096; idx += 256) {
      int e = idx & 7, g = idx >> 3;
      int l = g & 63, q = g >> 6;        // q = kb*4+nb
      int kb = q >> 2, nb = q & 3;
      int k = kb * 32 + ((l >> 4) & 3) * 8 + e;
      int col = nb * 16 + (l & 15);
      B1[idx] = bf16rne(A1w[k * 64 + col]);
      B2[idx] = bf16rne(A2w[k * 64 + col]);
      float a = w1[k * 64 + col];
      short h = bf16rne(a);
      W1hi[idx] = h;
      W1lo[idx] = bf16rne(a - bf16tof(h));
    }
  }
}

// ---------------------------------------------------------------------------
// K1c: pre-pack social att B-images. Runs AFTER core (outputs alias xbase).
// ---------------------------------------------------------------------------
__global__ void prepack2_kernel(const float* __restrict__ S1w,
                                const float* __restrict__ S2w,
                                short* __restrict__ B1,
                                short* __restrict__ B2) {
  for (int idx = threadIdx.x; idx < 4096; idx += 256) {
    int e = idx & 7, g = idx >> 3;
    int l = g & 63, q = g >> 6;
    int kb = q >> 2, nb = q & 3;
    int k = kb * 32 + ((l >> 4) & 3) * 8 + e;
    int col = nb * 16 + (l & 15);
    B1[idx] = bf16rne(S1w[k * 64 + col]);
    B2[idx] = bf16rne(S2w[k * 64 + col]);
  }
}

// ---------------------------------------------------------------------------
// K2: xbase[50000][64] = item_w @ W1[0:64] via split-bf16 MFMA.
// ---------------------------------------------------------------------------
__global__ __launch_bounds__(256)
void pre_xbase_mfma_kernel(const float* __restrict__ item_w,
                           const short* __restrict__ W1hi,
                           const short* __restrict__ W1lo,
                           float* __restrict__ xbase) {
  const int lane = threadIdx.x & 63, w = threadIdx.x >> 6;
  const int l15 = lane & 15, lg4 = lane >> 4;
  short8 bh[8], bl[8];                     // [kb*4+nb]
#pragma unroll
  for (int q = 0; q < 8; ++q) {
    bh[q] = *(const short8*)(W1hi + (q * 64 + lane) * 8);
    bl[q] = *(const short8*)(W1lo + (q * 64 + lane) * 8);
  }
  const int wid = blockIdx.x * 4 + w;
  const int nw = gridDim.x * 4;
  for (int tile = wid; tile < 3125; tile += nw) {
    const long r0 = (long)tile * 16;
    const float* ap = item_w + (r0 + l15) * 64 + lg4 * 8;
    short8 ah[2], al[2];
#pragma unroll
    for (int kb = 0; kb < 2; ++kb) {
      const float4 a = *(const float4*)(ap + kb * 32);
      const float4 b = *(const float4*)(ap + kb * 32 + 4);
      float v[8] = {a.x, a.y, a.z, a.w, b.x, b.y, b.z, b.w};
      short8 hi, lo;
#pragma unroll
      for (int e = 0; e < 8; ++e) {
        short h = bf16rne(v[e]);
        hi[e] = h;
        lo[e] = bf16rne(v[e] - bf16tof(h));
      }
      ah[kb] = hi;
      al[kb] = lo;
    }
#pragma unroll
    for (int nb = 0; nb < 4; ++nb) {
      f32x4 acc = {0.0f, 0.0f, 0.0f, 0.0f};
      acc = __builtin_amdgcn_mfma_f32_16x16x32_bf16(ah[0], bh[0 * 4 + nb], acc, 0, 0, 0);
      acc = __builtin_amdgcn_mfma_f32_16x16x32_bf16(ah[1], bh[1 * 4 + nb], acc, 0, 0, 0);
      acc = __builtin_amdgcn_mfma_f32_16x16x32_bf16(ah[0], bl[0 * 4 + nb], acc, 0, 0, 0);
      acc = __builtin_amdgcn_mfma_f32_16x16x32_bf16(ah[1], bl[1 * 4 + nb], acc, 0, 0, 0);
      acc = __builtin_amdgcn_mfma_f32_16x16x32_bf16(al[0], bh[0 * 4 + nb], acc, 0, 0, 0);
      acc = __builtin_amdgcn_mfma_f32_16x16x32_bf16(al[1], bh[1 * 4 + nb], acc, 0, 0, 0);
#pragma unroll
      for (int r = 0; r < 4; ++r)
        xbase[(r0 + lg4 * 4 + r) * 64 + nb * 16 + l15] = acc[r];
    }
  }
}

// ---------------------------------------------------------------------------
// K3: compact active instance list.  <<<66,256>>>
// ---------------------------------------------------------------------------
__global__ void build_active_kernel(const int* __restrict__ nodes,
                                    const int* __restrict__ social_hist,
                                    const void* __restrict__ social_mask,
                                    const int* __restrict__ flagp,
                                    int* __restrict__ counter,
                                    int* __restrict__ list,
                                    int* __restrict__ aUid) {
  const int t = blockIdx.x * 256 + threadIdx.x;
  if (t >= NT) return;
  const int mode = flagp[0];
  int uid;
  bool active;
  if (t < BB) {
    active = true;
    uid = nodes[t];
  } else {
    int nb = t - BB;
    int b = nb >> 5, l = nb & 31;
    long mi = (long)nodes[b] * LSS + l;
    active = mread(social_mask, mi, mode);
    uid = active ? social_hist[mi] : 0;
  }
  if (active) {
    int pos = atomicAdd(counter, 1);
    list[pos] = t;
    aUid[pos] = uid;
  }
}

// ---------------------------------------------------------------------------
// K4: uA1buf[idx] = user_w[aUid[idx]] @ A1w[64:128] + A1b.  64 rows/block.
// ---------------------------------------------------------------------------
__global__ __launch_bounds__(256, 2)
void uA1_kernel(const float* __restrict__ user_w,
                const float* __restrict__ A1w, const float* __restrict__ A1b,
                const int* __restrict__ idxsrc, const int* __restrict__ nActp,
                float* __restrict__ uA1buf) {
  const int tid = threadIdx.x, lane = tid & 63, w = tid >> 6;
  const int i0 = blockIdx.x * 64;
  const int nA = nActp[0];
  if (i0 >= nA) return;
  __shared__ float sW[64][64], sU[64][64];
  __shared__ float sb[64];
  __shared__ int sUid[64];
  for (int i = tid; i < 4096; i += 256) sW[i >> 6][i & 63] = A1w[4096 + i];
  if (tid < 64) {
    sb[tid] = A1b[tid];
    sUid[tid] = (i0 + tid < nA) ? idxsrc[i0 + tid] : 0;
  }
  __syncthreads();
  for (int i = tid; i < 4096; i += 256) {
    int r = i >> 6, c = i & 63;
    sU[r][c] = user_w[(long)sUid[r] * 64 + c];
  }
  __syncthreads();
  float acc[16];
#pragma unroll
  for (int r = 0; r < 16; ++r) acc[r] = sb[lane];
  for (int k = 0; k < 64; k += 4) {
    float wv0 = sW[k][lane], wv1 = sW[k + 1][lane];
    float wv2 = sW[k + 2][lane], wv3 = sW[k + 3][lane];
#pragma unroll
    for (int r = 0; r < 16; ++r) {
      const float4 xv = *(const float4*)(&sU[w * 16 + r][k]);
      acc[r] = fmaf(xv.x, wv0, acc[r]);
      acc[r] = fmaf(xv.y, wv1, acc[r]);
      acc[r] = fmaf(xv.z, wv2, acc[r]);
      acc[r] = fmaf(xv.w, wv3, acc[r]);
    }
  }
#pragma unroll
  for (int r = 0; r < 16; ++r) {
    int row = i0 + w * 16 + r;
    if (row < nA) uA1buf[(long)row * 64 + lane] = acc[r];
  }
}

// ---------------------------------------------------------------------------
// K5: CORE — wave-per-instance attention, MFMA bf16 logits.
// 512 threads = 8 independent waves; B-images staged once in LDS (shared);
// __launch_bounds__(512,8) caps VGPR at 64 -> up to 4 blocks/CU (LDS 40KB).
// ---------------------------------------------------------------------------
__global__ __launch_bounds__(512, 8)
void core_mfma_kernel(const float* __restrict__ xbase,
                      const float* __restrict__ RW1g,
                      const float* __restrict__ uA1buf,
                      const short* __restrict__ Bimg1,
                      const short* __restrict__ Bimg2,
                      const float* __restrict__ A2b,
                      const float* __restrict__ A3w,
                      const int* __restrict__ item_hist,
                      const int* __restrict__ rating_hist,
                      const void* __restrict__ item_mask,
                      const int* __restrict__ flagp,
                      const int* __restrict__ aUid,
                      const int* __restrict__ nActp,
                      float* __restrict__ hvecbuf) {
  __shared__ __align__(16) short sB1[4096], sB2[4096];   // 16KB images
  __shared__ __align__(16) char smem[8][3072];           // 24KB wave scratch
  const int tid = threadIdx.x, lane = tid & 63, w = tid >> 6;
  short* h1w = (short*)(smem[w]);          // [16][80] bf16
  float* lgw = (float*)(smem[w] + 2560);   // [64] logits
  int* cw = (int*)(smem[w] + 2816);        // [64] packed (item<<3)|rating

  ((int4*)sB1)[tid] = ((const int4*)Bimg1)[tid];   // 512 * 16B = 8KB each
  ((int4*)sB2)[tid] = ((const int4*)Bimg2)[tid];
  __syncthreads();   // the only block-wide barrier

  const int mode = flagp[0];
  const int nA = nActp[0];
  const float a2bv = A2b[lane];
  const float a3v = A3w[lane];
  const int l15 = lane & 15;
  const int lg4 = lane >> 4;

#define B1F(q) (*(const short8*)(sB1 + ((q) * 64 + lane) * 8))
#define B2F(q) (*(const short8*)(sB2 + ((q) * 64 + lane) * 8))

  for (int idx = blockIdx.x * 8 + w; idx < nA; idx += gridDim.x * 8) {
    wave_fence();  // prior-instance LDS reads complete before overwrite
    const long uid = aUid[idx];

    // ---- compact item history (lane covers LI=64) ----
    const long mbase = uid * 64;
    bool m = mread(item_mask, mbase + lane, mode);
    unsigned long long bal = __ballot(m);
    const int nact = (int)__popcll(bal);
    int pos = (int)__popcll(bal & ((1ull << lane) - 1ull));
    if (m) cw[pos] = (item_hist[mbase + lane] << 3) | rating_hist[mbase + lane];
    const float uA1v = uA1buf[(long)idx * 64 + lane];
    wave_fence();

    // ---- logits via MFMA, 16-row chunks ----
    const int ng = (nact + 15) >> 4;
    for (int mc = 0; mc < ng; ++mc) {
      wave_fence();  // prior chunk's H1 reads done before overwrite
      int row = mc * 16 + l15;
      if (row >= nact) row = nact - 1;
      const int p = cw[row];
      const long it = p >> 3;
      const int rt = p & 7;
      short8 xa[2];
#pragma unroll
      for (int kb = 0; kb < 2; ++kb) {
        const int koff = kb * 32 + lg4 * 8;
        const float* xp = xbase + it * 64 + koff;
        const float* rp = RW1g + rt * 64 + koff;
        const float4 a = *(const float4*)xp;
        const float4 b = *(const float4*)(xp + 4);
        const float4 c = *(const float4*)rp;
        const float4 d = *(const float4*)(rp + 4);
        short8 f;
        f[0] = bf16rne(fmaxf(a.x + c.x, 0.0f));
        f[1] = bf16rne(fmaxf(a.y + c.y, 0.0f));
        f[2] = bf16rne(fmaxf(a.z + c.z, 0.0f));
        f[3] = bf16rne(fmaxf(a.w + c.w, 0.0f));
        f[4] = bf16rne(fmaxf(b.x + d.x, 0.0f));
        f[5] = bf16rne(fmaxf(b.y + d.y, 0.0f));
        f[6] = bf16rne(fmaxf(b.z + d.z, 0.0f));
        f[7] = bf16rne(fmaxf(b.w + d.w, 0.0f));
        xa[kb] = f;
      }
      // att1: H1 = relu(X @ A1a + uA1)
#pragma unroll
      for (int nb = 0; nb < 4; ++nb) {
        const float ui = __shfl(uA1v, nb * 16 + l15);
        f32x4 acc = {ui, ui, ui, ui};
        acc = __builtin_amdgcn_mfma_f32_16x16x32_bf16(xa[0], B1F(0 * 4 + nb), acc, 0, 0, 0);
        acc = __builtin_amdgcn_mfma_f32_16x16x32_bf16(xa[1], B1F(1 * 4 + nb), acc, 0, 0, 0);
#pragma unroll
        for (int r = 0; r < 4; ++r)
          h1w[(lg4 * 4 + r) * 80 + nb * 16 + l15] = bf16rne(fmaxf(acc[r], 0.0f));
      }
      wave_fence();
      // att2 + logit
      short8 ha[2];
      ha[0] = *(const short8*)(h1w + l15 * 80 + lg4 * 8);
      ha[1] = *(const short8*)(h1w + l15 * 80 + 32 + lg4 * 8);
      float t0 = 0.0f, t1 = 0.0f, t2 = 0.0f, t3 = 0.0f;
#pragma unroll
      for (int nb = 0; nb < 4; ++nb) {
        const float b2 = __shfl(a2bv, nb * 16 + l15);
        f32x4 acc = {b2, b2, b2, b2};
        acc = __builtin_amdgcn_mfma_f32_16x16x32_bf16(ha[0], B2F(0 * 4 + nb), acc, 0, 0, 0);
        acc = __builtin_amdgcn_mfma_f32_16x16x32_bf16(ha[1], B2F(1 * 4 + nb), acc, 0, 0, 0);
        const float a3c = __shfl(a3v, nb * 16 + l15);
        t0 = fmaf(fmaxf(acc[0], 0.0f), a3c, t0);
        t1 = fmaf(fmaxf(acc[1], 0.0f), a3c, t1);
        t2 = fmaf(fmaxf(acc[2], 0.0f), a3c, t2);
        t3 = fmaf(fmaxf(acc[3], 0.0f), a3c, t3);
      }
      t0 = rsum16(t0); t1 = rsum16(t1); t2 = rsum16(t2); t3 = rsum16(t3);
      if (l15 == 0) {
        const int jb = mc * 16 + lg4 * 4;
        lgw[jb + 0] = t0;
        lgw[jb + 1] = t1;
        lgw[jb + 2] = t2;
        lgw[jb + 3] = t3;
      }
    }
    wave_fence();

    // ---- softmax over lanes ----
    const bool valid = (lane < nact);
    float lv = valid ? lgw[lane] : -1e30f;
    float mx = wmax(lv);
    float e = valid ? __expf(lv - mx) : 0.0f;
    float s = wsum(e);
    const float alpha = e / s;

    // ---- hI = sum_j alpha_j * x_j  (exact f32 re-gather) ----
    float hi = 0.0f;
    for (int j = 0; j < nact; ++j) {
      const float aj = __shfl(alpha, j);
      const int p = cw[j];
      const float xv =
          fmaxf(xbase[(long)(p >> 3) * 64 + lane] + RW1g[(p & 7) * 64 + lane], 0.0f);
      hi = fmaf(aj, xv, hi);
    }
    hvecbuf[(long)idx * 64 + lane] = hi;
  }
#undef B1F
#undef B2F
}

// ---------------------------------------------------------------------------
// K6: fused hI2 + final: hIbuf[inst] = relu([u ; relu(hvec@W2+b2)] @ W3 + b3).
// 32 rows / block, two stages, W buffer reloaded between stages.
// ---------------------------------------------------------------------------
__global__ __launch_bounds__(256, 2)
void hI2final_kernel(const float* __restrict__ hvecbuf,
                     const float* __restrict__ user_w,
                     const float* __restrict__ W2w, const float* __restrict__ W2b,
                     const float* __restrict__ W3w, const float* __restrict__ W3b,
                     const int* __restrict__ list, const int* __restrict__ aUid,
                     const int* __restrict__ nActp, float* __restrict__ hIbuf) {
  const int tid = threadIdx.x, lane = tid & 63, w = tid >> 6;
  const int i0 = blockIdx.x * 32;
  const int nA = nActp[0];
  if (i0 >= nA) return;
  __shared__ float sW[128][64];   // 32KB: W2 (rows 0..63) then W3 (0..127)
  __shared__ float sX[32][128];   // cols 0:64 = u, 64:128 = hvec then hI2
  __shared__ float sb[64];
  __shared__ int sUid[32], sInst[32];
  for (int i = tid; i < 4096; i += 256) sW[i >> 6][i & 63] = W2w[i];
  if (tid < 64) sb[tid] = W2b[tid];
  if (tid < 32) {
    bool ok = (i0 + tid) < nA;
    sUid[tid] = ok ? aUid[i0 + tid] : 0;
    sInst[tid] = ok ? list[i0 + tid] : 0;
  }
  __syncthreads();
  for (int i = tid; i < 2048; i += 256) {
    int r = i >> 6, c = i & 63;
    sX[r][64 + c] = (i0 + r < nA) ? hvecbuf[(long)(i0 + r) * 64 + c] : 0.0f;
    sX[r][c] = user_w[(long)sUid[r] * 64 + c];
  }
  __syncthreads();

  float acc[8];
  // stage A: hI2 = relu(hvec @ W2 + b2) -> sX[r][64:]
  {
    const float bv = sb[lane];
#pragma unroll
    for (int r = 0; r < 8; ++r) acc[r] = bv;
    for (int k = 0; k < 64; k += 4) {
      float wv0 = sW[k][lane], wv1 = sW[k + 1][lane];
      float wv2 = sW[k + 2][lane], wv3 = sW[k + 3][lane];
#pragma unroll
      for (int r = 0; r < 8; ++r) {
        const float4 xv = *(const float4*)(&sX[w * 8 + r][64 + k]);
        acc[r] = fmaf(xv.x, wv0, acc[r]);
        acc[r] = fmaf(xv.y, wv1, acc[r]);
        acc[r] = fmaf(xv.z, wv2, acc[r]);
        acc[r] = fmaf(xv.w, wv3, acc[r]);
      }
    }
#pragma unroll
    for (int r = 0; r < 8; ++r) sX[w * 8 + r][64 + lane] = fmaxf(acc[r], 0.0f);
  }
  __syncthreads();
  for (int i = tid; i < 8192; i += 256) sW[i >> 6][i & 63] = W3w[i];
  if (tid < 64) sb[tid] = W3b[tid];
  __syncthreads();

  // stage B: out = relu([u ; hI2] @ W3 + b3)
  {
    const float bv = sb[lane];
#pragma unroll
    for (int r = 0; r < 8; ++r) acc[r] = bv;
    for (int k = 0; k < 128; k += 4) {
      float wv0 = sW[k][lane], wv1 = sW[k + 1][lane];
      float wv2 = sW[k + 2][lane], wv3 = sW[k + 3][lane];
#pragma unroll
      for (int r = 0; r < 8; ++r) {
        const float4 xv = *(const float4*)(&sX[w * 8 + r][k]);
        acc[r] = fmaf(xv.x, wv0, acc[r]);
        acc[r] = fmaf(xv.y, wv1, acc[r]);
        acc[r] = fmaf(xv.z, wv2, acc[r]);
        acc[r] = fmaf(xv.w, wv3, acc[r]);
      }
    }
#pragma unroll
    for (int r = 0; r < 8; ++r) {
      int row = i0 + w * 8 + r;
      if (row < nA)
        hIbuf[(long)sInst[w * 8 + r] * 64 + lane] = fmaxf(acc[r], 0.0f);
    }
  }
}

// ---------------------------------------------------------------------------
// K7: fully fused social phase — one wave per batch element b:
// inline uA1S matvec, MFMA attention over neighbors, beta-weighted hS,
// then the 3-stage tail matvecs. Zero barriers after image staging.
// ---------------------------------------------------------------------------
__global__ __launch_bounds__(256, 8)
void social_fused_kernel(const float* __restrict__ hIbuf,
                         const float* __restrict__ user_w,
                         const float* __restrict__ S1w,   // s_att1_w [128][64]
                         const float* __restrict__ S1b,
                         const short* __restrict__ S1img,
                         const short* __restrict__ S2img,
                         const float* __restrict__ S2b,
                         const float* __restrict__ S3w,
                         const float* __restrict__ L1w, const float* __restrict__ L1b,
                         const float* __restrict__ L2w, const float* __restrict__ L2b,
                         const float* __restrict__ L3w, const float* __restrict__ L3b,
                         const int* __restrict__ nodes,
                         const void* __restrict__ social_mask,
                         const int* __restrict__ flagp,
                         float* __restrict__ out) {
  __shared__ __align__(16) short sB1[4096], sB2[4096];   // 16KB images
  __shared__ __align__(16) char smem[4][3584];           // 14KB wave scratch
  const int tid = threadIdx.x, lane = tid & 63, w = tid >> 6;
  short* h1w = (short*)(smem[w]);          // [16][80] bf16
  float* lgw = (float*)(smem[w] + 2560);   // [32] logits
  int* cw = (int*)(smem[w] + 2816);        // [32] neighbor slots
  float* vA = (float*)(smem[w] + 3072);    // [64]
  float* vB = (float*)(smem[w] + 3328);    // [64]

  for (int i = tid; i < 512; i += 256) {
    ((int4*)sB1)[i] = ((const int4*)S1img)[i];
    ((int4*)sB2)[i] = ((const int4*)S2img)[i];
  }
  __syncthreads();

  const int mode = flagp[0];
  const int l15 = lane & 15;
  const int lg4 = lane >> 4;
  const int b = blockIdx.x * 4 + w;        // grid 128*4 = 512 exactly
  const long uid = nodes[b];

  bool m = (lane < LSS) ? mread(social_mask, uid * LSS + lane, mode) : false;
  unsigned long long bal = __ballot(m);
  const int nval = (int)__popcll(bal);
  int pos = (int)__popcll(bal & ((1ull << lane) - 1ull));
  if (m) cw[pos] = lane;

  // inline uA1S = u @ S1w[64:128] + S1b  (weights L1/L2-hot across waves)
  const float uv = user_w[uid * 64 + lane];
  float uA1v = S1b[lane];
#pragma unroll 8
  for (int k = 0; k < 64; ++k)
    uA1v = fmaf(__shfl(uv, k), S1w[(64 + k) * 64 + lane], uA1v);
  const float a2bv = S2b[lane];
  const float a3v = S3w[lane];
  wave_fence();

  const long hbase = 512L + (long)b * 32;
  const int ng = (nval + 15) >> 4;
  for (int mc = 0; mc < ng; ++mc) {
    wave_fence();
    int row = mc * 16 + l15;
    if (row >= nval) row = nval - 1;
    const long hrow = hbase + cw[row];
    short8 xa[2];
#pragma unroll
    for (int kb = 0; kb < 2; ++kb) {
      const float* xp = hIbuf + hrow * 64 + kb * 32 + lg4 * 8;
      const float4 a = *(const float4*)xp;
      const float4 bb = *(const float4*)(xp + 4);
      short8 f;
      f[0] = bf16rne(a.x);  f[1] = bf16rne(a.y);
      f[2] = bf16rne(a.z);  f[3] = bf16rne(a.w);
      f[4] = bf16rne(bb.x); f[5] = bf16rne(bb.y);
      f[6] = bf16rne(bb.z); f[7] = bf16rne(bb.w);
      xa[kb] = f;
    }
#pragma unroll
    for (int nb = 0; nb < 4; ++nb) {
      const float ui = __shfl(uA1v, nb * 16 + l15);
      f32x4 acc = {ui, ui, ui, ui};
      acc = __builtin_amdgcn_mfma_f32_16x16x32_bf16(
          xa[0], *(const short8*)(sB1 + ((0 * 4 + nb) * 64 + lane) * 8), acc, 0, 0, 0);
      acc = __builtin_amdgcn_mfma_f32_16x16x32_bf16(
          xa[1], *(const short8*)(sB1 + ((1 * 4 + nb) * 64 + lane) * 8), acc, 0, 0, 0);
#pragma unroll
      for (int r = 0; r < 4; ++r)
        h1w[(lg4 * 4 + r) * 80 + nb * 16 + l15] = bf16rne(fmaxf(acc[r], 0.0f));
    }
    wave_fence();
    short8 ha[2];
    ha[0] = *(const short8*)(h1w + l15 * 80 + lg4 * 8);
    ha[1] = *(const short8*)(h1w + l15 * 80 + 32 + lg4 * 8);
    float t0 = 0.0f, t1 = 0.0f, t2 = 0.0f, t3 = 0.0f;
#pragma unroll
    for (int nb = 0; nb < 4; ++nb) {
      const float b2 = __shfl(a2bv, nb * 16 + l15);
      f32x4 acc = {b2, b2, b2, b2};
      acc = __builtin_amdgcn_mfma_f32_16x16x32_bf16(
          ha[0], *(const short8*)(sB2 + ((0 * 4 + nb) * 64 + lane) * 8), acc, 0, 0, 0);
      acc = __builtin_amdgcn_mfma_f32_16x16x32_bf16(
          ha[1], *(const short8*)(sB2 + ((1 * 4 + nb) * 64 + lane) * 8), acc, 0, 0, 0);
      const float a3c = __shfl(a3v, nb * 16 + l15);
      t0 = fmaf(fmaxf(acc[0], 0.0f), a3c, t0);
      t1 = fmaf(fmaxf(acc[1], 0.0f), a3c, t1);
      t2 = fmaf(fmaxf(acc[2], 0.0f), a3c, t2);
      t3 = fmaf(fmaxf(acc[3], 0.0f), a3c, t3);
    }
    t0 = rsum16(t0); t1 = rsum16(t1); t2 = rsum16(t2); t3 = rsum16(t3);
    if (l15 == 0) {
      const int jb = mc * 16 + lg4 * 4;
      lgw[jb + 0] = t0;
      lgw[jb + 1] = t1;
      lgw[jb + 2] = t2;
      lgw[jb + 3] = t3;
    }
  }
  wave_fence();

  const bool valid = (lane < nval);
  float lv = valid ? lgw[lane] : -1e30f;
  float mx = wmax(lv);
  float e = valid ? __expf(lv - mx) : 0.0f;
  float s = wsum(e);
  const float beta = e / s;

  float hs = 0.0f;
  for (int j = 0; j < nval; ++j) {
    const float bj = __shfl(beta, j);
    hs = fmaf(bj, hIbuf[(hbase + cw[j]) * 64 + lane], hs);
  }

  // ---- tail: vecB = relu(hS@L1+b1); f = relu([self;vecB]@L2+b2);
  //            out = relu(f@L3+b3)  — per-wave matvecs, LDS broadcasts.
  vA[lane] = hs;
  wave_fence();
  float acc = L1b[lane];
#pragma unroll 8
  for (int k = 0; k < 64; ++k) acc = fmaf(vA[k], L1w[k * 64 + lane], acc);
  const float vecB = fmaxf(acc, 0.0f);
  const float selfv = hIbuf[(long)b * 64 + lane];
  wave_fence();
  vA[lane] = selfv;
  vB[lane] = vecB;
  wave_fence();
  acc = L2b[lane];
#pragma unroll 8
  for (int k = 0; k < 64; ++k) acc = fmaf(vA[k], L2w[k * 64 + lane], acc);
#pragma unroll 8
  for (int k = 0; k < 64; ++k) acc = fmaf(vB[k], L2w[(64 + k) * 64 + lane], acc);
  const float fv = fmaxf(acc, 0.0f);
  wave_fence();
  vA[lane] = fv;
  wave_fence();
  acc = L3b[lane];
#pragma unroll 8
  for (int k = 0; k < 64; ++k) acc = fmaf(vA[k], L3w[k * 64 + lane], acc);
  out[(long)b * 64 + lane] = fmaxf(acc, 0.0f);
}

// ---------------------------------------------------------------------------
extern "C" void kernel_launch(void* const* d_in, const int* in_sizes, int n_in,
                              void* d_out, int out_size, void* d_ws, size_t ws_size,
                              hipStream_t stream) {
  const float* user_w   = (const float*)d_in[0];
  const float* item_w   = (const float*)d_in[1];
  const float* rating_w = (const float*)d_in[2];
  const float* i_ln1_w  = (const float*)d_in[3];
  const float* i_ln1_b  = (const float*)d_in[4];
  const float* i_ln2_w  = (const float*)d_in[5];
  const float* i_ln2_b  = (const float*)d_in[6];
  const float* i_ln3_w  = (const float*)d_in[7];
  const float* i_ln3_b  = (const float*)d_in[8];
  const float* i_att1_w = (const float*)d_in[9];
  const float* i_att1_b = (const float*)d_in[10];
  const float* i_att2_w = (const float*)d_in[11];
  const float* i_att2_b = (const float*)d_in[12];
  const float* i_att3_w = (const float*)d_in[13];
  const float* i_att3_b = (const float*)d_in[14];
  const float* s_ln1_w  = (const float*)d_in[15];
  const float* s_ln1_b  = (const float*)d_in[16];
  const float* s_ln2_w  = (const float*)d_in[17];
  const float* s_ln2_b  = (const float*)d_in[18];
  const float* s_ln3_w  = (const float*)d_in[19];
  const float* s_ln3_b  = (const float*)d_in[20];
  const float* s_att1_w = (const float*)d_in[21];
  const float* s_att1_b = (const float*)d_in[22];
  const float* s_att2_w = (const float*)d_in[23];
  const float* s_att2_b = (const float*)d_in[24];
  const float* s_att3_w = (const float*)d_in[25];
  const float* s_att3_b = (const float*)d_in[26];
  const int*  nodes       = (const int*)d_in[27];
  const int*  social_hist = (const int*)d_in[28];
  const void* social_mask = d_in[29];
  const int*  item_hist   = (const int*)d_in[30];
  const int*  rating_hist = (const int*)d_in[31];
  const void* item_mask   = d_in[32];

  // workspace layout (bytes) — total 21,604,096 (proven cap; do not exceed).
  // Aliases (stream-serial liveness):
  //  - W1hi/W1lo in hvecbuf[0:16KB]: setup -> pre_xbase, dead before core.
  //  - S1img/S2img in xbase[0:16KB]: prepack2 (after core) -> social_fused.
  char* ws = (char*)d_ws;
  int*   flag    = (int*)(ws + 0);          // 256
  int*   counter = (int*)(ws + 256);        // 256
  int*   list    = (int*)(ws + 512);        // NT*4 = 67584
  int*   aUid    = (int*)(ws + 68096);      // 67584
  float* uA1buf  = (float*)(ws + 135680);   // NT*64*4 = 4325376
  float* hvecbuf = (float*)(ws + 4461056);  // 4325376
  float* hIbuf   = hvecbuf;                 // alias: hvec dead before K6 write
  short* W1hi    = (short*)(ws + 4461056);  // 8192  (alias hvecbuf[0:2048])
  short* W1lo    = (short*)(ws + 4469248);  // 8192  (alias hvecbuf[2048:4096])
  float* xbase   = (float*)(ws + 8786432);  // 50000*64*4 = 12800000
  short* S1img   = (short*)(ws + 8786432);  // 8192  (alias xbase, after core)
  short* S2img   = (short*)(ws + 8794624);  // 8192  (alias xbase, after core)
  float* RW1g    = (float*)(ws + 21586432); // 1280
  short* Bimg1   = (short*)(ws + 21587712); // 8192
  short* Bimg2   = (short*)(ws + 21595904); // 8192

  hipMemsetAsync(counter, 0, 4, stream);
  setup_kernel<<<3, 256, 0, stream>>>((const unsigned int*)social_mask, flag,
                                      rating_w, i_ln1_w, i_ln1_b, RW1g,
                                      i_att1_w, i_att2_w, Bimg1, Bimg2, W1hi, W1lo);
  pre_xbase_mfma_kernel<<<512, 256, 0, stream>>>(item_w, W1hi, W1lo, xbase);
  build_active_kernel<<<NT / 256, 256, 0, stream>>>(
      nodes, social_hist, social_mask, flag, counter, list, aUid);
  uA1_kernel<<<NT / 64, 256, 0, stream>>>(user_w, i_att1_w, i_att1_b,
                                          aUid, counter, uA1buf);
  core_mfma_kernel<<<NT / 16, 512, 0, stream>>>(
      xbase, RW1g, uA1buf, Bimg1, Bimg2, i_att2_b, i_att3_w,
      item_hist, rating_hist, item_mask, flag, aUid, counter, hvecbuf);
  prepack2_kernel<<<1, 256, 0, stream>>>(s_att1_w, s_att2_w, S1img, S2img);
  hI2final_kernel<<<NT / 32, 256, 0, stream>>>(
      hvecbuf, user_w, i_ln2_w, i_ln2_b, i_ln3_w, i_ln3_b,
      list, aUid, counter, hIbuf);
  social_fused_kernel<<<BB / 4, 256, 0, stream>>>(
      hIbuf, user_w, s_att1_w, s_att1_b, S1img, S2img, s_att2_b, s_att3_w,
      s_ln1_w, s_ln1_b, s_ln2_w, s_ln2_b, s_ln3_w, s_ln3_b,
      nodes, social_mask, flag, (float*)d_out);
}

// Round 9
// 127.929 us; speedup vs baseline: 7.0552x; 1.0162x over previous
//
#include <hip/hip_runtime.h>
#include <math.h>

// ---------------------------------------------------------------------------
// Aggre_social on MI355X — round 9: online-softmax hI in the core (no
// alpha re-gather pass; halves xbase traffic, kills the serial tail loop).
// Everything else identical to round 8. ws layout unchanged (21,604,096 B).
// Sizes: NU=NI=50000, NR=5, D=64, B=512, LS=32, LI=64.
// ---------------------------------------------------------------------------

#define NII 50000
#define BB 512
#define LSS 32
#define NT 16896   // 512 self + 16384 neighbor instances

typedef short short8 __attribute__((ext_vector_type(8)));
typedef float f32x4 __attribute__((ext_vector_type(4)));

static __device__ __forceinline__ bool mread(const void* p, long i, int mode) {
  if (mode == 0) return ((const int*)p)[i] != 0;       // int32 storage
  if (mode == 2) return ((const float*)p)[i] != 0.0f;  // f32 storage
  return ((const unsigned char*)p)[i] != 0;            // byte storage
}

static __device__ __forceinline__ float wsum(float v) {
#pragma unroll
  for (int s = 1; s < 64; s <<= 1) v += __shfl_xor(v, s);
  return v;
}
static __device__ __forceinline__ float wmax(float v) {
#pragma unroll
  for (int s = 1; s < 64; s <<= 1) v = fmaxf(v, __shfl_xor(v, s));
  return v;
}
static __device__ __forceinline__ float rsum16(float v) {
#pragma unroll
  for (int s = 1; s < 16; s <<= 1) v += __shfl_xor(v, s);
  return v;
}
static __device__ __forceinline__ float rmax16(float v) {
#pragma unroll
  for (int s = 1; s < 16; s <<= 1) v = fmaxf(v, __shfl_xor(v, s));
  return v;
}

// f32 -> bf16 (round-to-nearest-even), as raw short.
static __device__ __forceinline__ short bf16rne(float f) {
  unsigned u = __float_as_uint(f);
  u = (u + 0x7FFFu + ((u >> 16) & 1u)) >> 16;
  return (short)u;
}
static __device__ __forceinline__ float bf16tof(short h) {
  return __uint_as_float(((unsigned)(unsigned short)h) << 16);
}

// Intra-wave LDS write->read fence.
static __device__ __forceinline__ void wave_fence() {
  asm volatile("s_waitcnt lgkmcnt(0)" ::: "memory");
  __builtin_amdgcn_sched_barrier(0);
}

// ---------------------------------------------------------------------------
// K0: fused setup. block 0: mask-format detect; block 1: RW1g matvec;
// block 2: prepack item-att B-images + W1 hi/lo split.   <<<3,256>>>
// ---------------------------------------------------------------------------
__global__ void setup_kernel(const unsigned int* __restrict__ sm,
                             int* __restrict__ flag,
                             const float* __restrict__ rating_w,
                             const float* __restrict__ w1,
                             const float* __restrict__ b1,
                             float* __restrict__ RW1g,
                             const float* __restrict__ A1w,
                             const float* __restrict__ A2w,
                             short* __restrict__ B1,
                             short* __restrict__ B2,
                             short* __restrict__ W1hi,
                             short* __restrict__ W1lo) {
  const int tid = threadIdx.x;
  if (blockIdx.x == 0) {
    __shared__ int notInt, notFloat;
    if (tid == 0) { notInt = 0; notFloat = 0; }
    __syncthreads();
    int ni = 0, nf = 0;
    for (int i = tid; i < 4096; i += 256) {
      unsigned int x = sm[i];
      if (x > 1u) ni = 1;
      if (x != 0u && x != 0x3F800000u) nf = 1;
    }
    if (ni) atomicOr(&notInt, 1);
    if (nf) atomicOr(&notFloat, 1);
    __syncthreads();
    if (tid == 0) flag[0] = notInt ? (notFloat ? 1 : 2) : 0;
  } else if (blockIdx.x == 1) {
    for (int t = tid; t < 320; t += 256) {
      const int r = t >> 6, c = t & 63;
      float acc = b1[c];
      for (int k = 0; k < 64; ++k)
        acc = fmaf(rating_w[r * 64 + k], w1[(64 + k) * 64 + c], acc);
      RW1g[r * 64 + c] = acc;
    }
  } else {
    for (int idx = tid; idx < 4096; idx += 256) {
      int e = idx & 7, g = idx >> 3;
      int l = g & 63, q = g >> 6;        // q = kb*4+nb
      int kb = q >> 2, nb = q & 3;
      int k = kb * 32 + ((l >> 4) & 3) * 8 + e;
      int col = nb * 16 + (l & 15);
      B1[idx] = bf16rne(A1w[k * 64 + col]);
      B2[idx] = bf16rne(A2w[k * 64 + col]);
      float a = w1[k * 64 + col];
      short h = bf16rne(a);
      W1hi[idx] = h;
      W1lo[idx] = bf16rne(a - bf16tof(h));
    }
  }
}

// ---------------------------------------------------------------------------
// K1c: pre-pack social att B-images. Runs AFTER core (outputs alias xbase).
// ---------------------------------------------------------------------------
__global__ void prepack2_kernel(const float* __restrict__ S1w,
                                const float* __restrict__ S2w,
                                short* __restrict__ B1,
                                short* __restrict__ B2) {
  for (int idx = threadIdx.x; idx < 4096; idx += 256) {
    int e = idx & 7, g = idx >> 3;
    int l = g & 63, q = g >> 6;
    int kb = q >> 2, nb = q & 3;
    int k = kb * 32 + ((l >> 4) & 3) * 8 + e;
    int col = nb * 16 + (l & 15);
    B1[idx] = bf16rne(S1w[k * 64 + col]);
    B2[idx] = bf16rne(S2w[k * 64 + col]);
  }
}

// ---------------------------------------------------------------------------
// K2: xbase[50000][64] = item_w @ W1[0:64] via split-bf16 MFMA.
// ---------------------------------------------------------------------------
__global__ __launch_bounds__(256)
void pre_xbase_mfma_kernel(const float* __restrict__ item_w,
                           const short* __restrict__ W1hi,
                           const short* __restrict__ W1lo,
                           float* __restrict__ xbase) {
  const int lane = threadIdx.x & 63, w = threadIdx.x >> 6;
  const int l15 = lane & 15, lg4 = lane >> 4;
  short8 bh[8], bl[8];                     // [kb*4+nb]
#pragma unroll
  for (int q = 0; q < 8; ++q) {
    bh[q] = *(const short8*)(W1hi + (q * 64 + lane) * 8);
    bl[q] = *(const short8*)(W1lo + (q * 64 + lane) * 8);
  }
  const int wid = blockIdx.x * 4 + w;
  const int nw = gridDim.x * 4;
  for (int tile = wid; tile < 3125; tile += nw) {
    const long r0 = (long)tile * 16;
    const float* ap = item_w + (r0 + l15) * 64 + lg4 * 8;
    short8 ah[2], al[2];
#pragma unroll
    for (int kb = 0; kb < 2; ++kb) {
      const float4 a = *(const float4*)(ap + kb * 32);
      const float4 b = *(const float4*)(ap + kb * 32 + 4);
      float v[8] = {a.x, a.y, a.z, a.w, b.x, b.y, b.z, b.w};
      short8 hi, lo;
#pragma unroll
      for (int e = 0; e < 8; ++e) {
        short h = bf16rne(v[e]);
        hi[e] = h;
        lo[e] = bf16rne(v[e] - bf16tof(h));
      }
      ah[kb] = hi;
      al[kb] = lo;
    }
#pragma unroll
    for (int nb = 0; nb < 4; ++nb) {
      f32x4 acc = {0.0f, 0.0f, 0.0f, 0.0f};
      acc = __builtin_amdgcn_mfma_f32_16x16x32_bf16(ah[0], bh[0 * 4 + nb], acc, 0, 0, 0);
      acc = __builtin_amdgcn_mfma_f32_16x16x32_bf16(ah[1], bh[1 * 4 + nb], acc, 0, 0, 0);
      acc = __builtin_amdgcn_mfma_f32_16x16x32_bf16(ah[0], bl[0 * 4 + nb], acc, 0, 0, 0);
      acc = __builtin_amdgcn_mfma_f32_16x16x32_bf16(ah[1], bl[1 * 4 + nb], acc, 0, 0, 0);
      acc = __builtin_amdgcn_mfma_f32_16x16x32_bf16(al[0], bh[0 * 4 + nb], acc, 0, 0, 0);
      acc = __builtin_amdgcn_mfma_f32_16x16x32_bf16(al[1], bh[1 * 4 + nb], acc, 0, 0, 0);
#pragma unroll
      for (int r = 0; r < 4; ++r)
        xbase[(r0 + lg4 * 4 + r) * 64 + nb * 16 + l15] = acc[r];
    }
  }
}

// ---------------------------------------------------------------------------
// K3: compact active instance list.  <<<66,256>>>
// ---------------------------------------------------------------------------
__global__ void build_active_kernel(const int* __restrict__ nodes,
                                    const int* __restrict__ social_hist,
                                    const void* __restrict__ social_mask,
                                    const int* __restrict__ flagp,
                                    int* __restrict__ counter,
                                    int* __restrict__ list,
                                    int* __restrict__ aUid) {
  const int t = blockIdx.x * 256 + threadIdx.x;
  if (t >= NT) return;
  const int mode = flagp[0];
  int uid;
  bool active;
  if (t < BB) {
    active = true;
    uid = nodes[t];
  } else {
    int nb = t - BB;
    int b = nb >> 5, l = nb & 31;
    long mi = (long)nodes[b] * LSS + l;
    active = mread(social_mask, mi, mode);
    uid = active ? social_hist[mi] : 0;
  }
  if (active) {
    int pos = atomicAdd(counter, 1);
    list[pos] = t;
    aUid[pos] = uid;
  }
}

// ---------------------------------------------------------------------------
// K4: uA1buf[idx] = user_w[aUid[idx]] @ A1w[64:128] + A1b.  64 rows/block.
// ---------------------------------------------------------------------------
__global__ __launch_bounds__(256, 2)
void uA1_kernel(const float* __restrict__ user_w,
                const float* __restrict__ A1w, const float* __restrict__ A1b,
                const int* __restrict__ idxsrc, const int* __restrict__ nActp,
                float* __restrict__ uA1buf) {
  const int tid = threadIdx.x, lane = tid & 63, w = tid >> 6;
  const int i0 = blockIdx.x * 64;
  const int nA = nActp[0];
  if (i0 >= nA) return;
  __shared__ float sW[64][64], sU[64][64];
  __shared__ float sb[64];
  __shared__ int sUid[64];
  for (int i = tid; i < 4096; i += 256) sW[i >> 6][i & 63] = A1w[4096 + i];
  if (tid < 64) {
    sb[tid] = A1b[tid];
    sUid[tid] = (i0 + tid < nA) ? idxsrc[i0 + tid] : 0;
  }
  __syncthreads();
  for (int i = tid; i < 4096; i += 256) {
    int r = i >> 6, c = i & 63;
    sU[r][c] = user_w[(long)sUid[r] * 64 + c];
  }
  __syncthreads();
  float acc[16];
#pragma unroll
  for (int r = 0; r < 16; ++r) acc[r] = sb[lane];
  for (int k = 0; k < 64; k += 4) {
    float wv0 = sW[k][lane], wv1 = sW[k + 1][lane];
    float wv2 = sW[k + 2][lane], wv3 = sW[k + 3][lane];
#pragma unroll
    for (int r = 0; r < 16; ++r) {
      const float4 xv = *(const float4*)(&sU[w * 16 + r][k]);
      acc[r] = fmaf(xv.x, wv0, acc[r]);
      acc[r] = fmaf(xv.y, wv1, acc[r]);
      acc[r] = fmaf(xv.z, wv2, acc[r]);
      acc[r] = fmaf(xv.w, wv3, acc[r]);
    }
  }
#pragma unroll
  for (int r = 0; r < 16; ++r) {
    int row = i0 + w * 16 + r;
    if (row < nA) uA1buf[(long)row * 64 + lane] = acc[r];
  }
}

// ---------------------------------------------------------------------------
// K5: CORE — wave-per-instance attention, MFMA bf16 logits, ONLINE-softmax
// hI accumulation (x kept in f32 registers; no second gather pass).
// 512 threads = 8 waves; B-images in LDS; LDS 40KB -> 4 blocks/CU.
// ---------------------------------------------------------------------------
__global__ __launch_bounds__(512, 6)
void core_mfma_kernel(const float* __restrict__ xbase,
                      const float* __restrict__ RW1g,
                      const float* __restrict__ uA1buf,
                      const short* __restrict__ Bimg1,
                      const short* __restrict__ Bimg2,
                      const float* __restrict__ A2b,
                      const float* __restrict__ A3w,
                      const int* __restrict__ item_hist,
                      const int* __restrict__ rating_hist,
                      const void* __restrict__ item_mask,
                      const int* __restrict__ flagp,
                      const int* __restrict__ aUid,
                      const int* __restrict__ nActp,
                      float* __restrict__ hvecbuf) {
  __shared__ __align__(16) short sB1[4096], sB2[4096];   // 16KB images
  __shared__ __align__(16) char smem[8][3072];           // 24KB wave scratch
  const int tid = threadIdx.x, lane = tid & 63, w = tid >> 6;
  short* h1w = (short*)(smem[w]);          // [16][80] bf16
  float* lgw = (float*)(smem[w] + 2560);   // [16] chunk logits
  int* cw = (int*)(smem[w] + 2816);        // [64] packed (item<<3)|rating
  float* vAw = (float*)(smem[w]);          // [64] hI transpose (aliases h1w)

  ((int4*)sB1)[tid] = ((const int4*)Bimg1)[tid];   // 512 * 16B = 8KB each
  ((int4*)sB2)[tid] = ((const int4*)Bimg2)[tid];
  __syncthreads();   // the only block-wide barrier

  const int mode = flagp[0];
  const int nA = nActp[0];
  const float a2bv = A2b[lane];
  const float a3v = A3w[lane];
  const int l15 = lane & 15;
  const int lg4 = lane >> 4;

#define B1F(q) (*(const short8*)(sB1 + ((q) * 64 + lane) * 8))
#define B2F(q) (*(const short8*)(sB2 + ((q) * 64 + lane) * 8))

  for (int idx = blockIdx.x * 8 + w; idx < nA; idx += gridDim.x * 8) {
    wave_fence();  // prior-instance LDS reads complete before overwrite
    const long uid = aUid[idx];

    // ---- compact item history (lane covers LI=64) ----
    const long mbase = uid * 64;
    bool mk = mread(item_mask, mbase + lane, mode);
    unsigned long long bal = __ballot(mk);
    const int nact = (int)__popcll(bal);
    int pos = (int)__popcll(bal & ((1ull << lane) - 1ull));
    if (mk) cw[pos] = (item_hist[mbase + lane] << 3) | rating_hist[mbase + lane];
    const float uA1v = uA1buf[(long)idx * 64 + lane];
    wave_fence();

    // ---- online softmax state ----
    float m = -1e30f, s = 0.0f;
    float hIa[16];
#pragma unroll
    for (int q = 0; q < 16; ++q) hIa[q] = 0.0f;

    const int ng = (nact + 15) >> 4;
    for (int mc = 0; mc < ng; ++mc) {
      wave_fence();  // prior chunk's H1/lgw reads done before overwrite
      int row = mc * 16 + l15;
      const bool valid = (row < nact);
      if (row >= nact) row = nact - 1;
      const int p = cw[row];
      const long it = p >> 3;
      const int rt = p & 7;
      // gather x = relu(xbase + RW1g) into f32 regs (kept for hI)
      float xf[16];
#pragma unroll
      for (int kb = 0; kb < 2; ++kb) {
        const int koff = kb * 32 + lg4 * 8;
        const float* xp = xbase + it * 64 + koff;
        const float* rp = RW1g + rt * 64 + koff;
        const float4 a = *(const float4*)xp;
        const float4 b = *(const float4*)(xp + 4);
        const float4 c = *(const float4*)rp;
        const float4 d = *(const float4*)(rp + 4);
        xf[kb * 8 + 0] = fmaxf(a.x + c.x, 0.0f);
        xf[kb * 8 + 1] = fmaxf(a.y + c.y, 0.0f);
        xf[kb * 8 + 2] = fmaxf(a.z + c.z, 0.0f);
        xf[kb * 8 + 3] = fmaxf(a.w + c.w, 0.0f);
        xf[kb * 8 + 4] = fmaxf(b.x + d.x, 0.0f);
        xf[kb * 8 + 5] = fmaxf(b.y + d.y, 0.0f);
        xf[kb * 8 + 6] = fmaxf(b.z + d.z, 0.0f);
        xf[kb * 8 + 7] = fmaxf(b.w + d.w, 0.0f);
      }
      short8 xa[2];
#pragma unroll
      for (int kb = 0; kb < 2; ++kb) {
        short8 f;
#pragma unroll
        for (int e = 0; e < 8; ++e) f[e] = bf16rne(xf[kb * 8 + e]);
        xa[kb] = f;
      }
      // att1: H1 = relu(X @ A1a + uA1)
#pragma unroll
      for (int nb = 0; nb < 4; ++nb) {
        const float ui = __shfl(uA1v, nb * 16 + l15);
        f32x4 acc = {ui, ui, ui, ui};
        acc = __builtin_amdgcn_mfma_f32_16x16x32_bf16(xa[0], B1F(0 * 4 + nb), acc, 0, 0, 0);
        acc = __builtin_amdgcn_mfma_f32_16x16x32_bf16(xa[1], B1F(1 * 4 + nb), acc, 0, 0, 0);
#pragma unroll
        for (int r = 0; r < 4; ++r)
          h1w[(lg4 * 4 + r) * 80 + nb * 16 + l15] = bf16rne(fmaxf(acc[r], 0.0f));
      }
      wave_fence();
      // att2 + logit
      short8 ha[2];
      ha[0] = *(const short8*)(h1w + l15 * 80 + lg4 * 8);
      ha[1] = *(const short8*)(h1w + l15 * 80 + 32 + lg4 * 8);
      float t0 = 0.0f, t1 = 0.0f, t2 = 0.0f, t3 = 0.0f;
#pragma unroll
      for (int nb = 0; nb < 4; ++nb) {
        const float b2 = __shfl(a2bv, nb * 16 + l15);
        f32x4 acc = {b2, b2, b2, b2};
        acc = __builtin_amdgcn_mfma_f32_16x16x32_bf16(ha[0], B2F(0 * 4 + nb), acc, 0, 0, 0);
        acc = __builtin_amdgcn_mfma_f32_16x16x32_bf16(ha[1], B2F(1 * 4 + nb), acc, 0, 0, 0);
        const float a3c = __shfl(a3v, nb * 16 + l15);
        t0 = fmaf(fmaxf(acc[0], 0.0f), a3c, t0);
        t1 = fmaf(fmaxf(acc[1], 0.0f), a3c, t1);
        t2 = fmaf(fmaxf(acc[2], 0.0f), a3c, t2);
        t3 = fmaf(fmaxf(acc[3], 0.0f), a3c, t3);
      }
      t0 = rsum16(t0); t1 = rsum16(t1); t2 = rsum16(t2); t3 = rsum16(t3);
      if (l15 == 0) {
        const int jb = lg4 * 4;            // chunk-local row index
        lgw[jb + 0] = t0;
        lgw[jb + 1] = t1;
        lgw[jb + 2] = t2;
        lgw[jb + 3] = t3;
      }
      wave_fence();
      // ---- online update: m, s, hIa ----
      const float lv = valid ? lgw[l15] : -1e30f;
      const float cm = rmax16(lv);         // chunk max (wave-uniform)
      const float mn = fmaxf(m, cm);
      const float scale = __expf(m - mn);
      const float e = valid ? __expf(lv - mn) : 0.0f;
      const float cs = rsum16(e);          // chunk denom (group-uniform)
      s = s * scale + cs;
      m = mn;
#pragma unroll
      for (int q = 0; q < 16; ++q) hIa[q] = fmaf(hIa[q], scale, e * xf[q]);
    }
    wave_fence();

    // ---- finalize hI: normalize, reduce over the 16 rows, transpose ----
    const float inv = 1.0f / s;
#pragma unroll
    for (int q = 0; q < 16; ++q) hIa[q] = rsum16(hIa[q] * inv);
    if (l15 == 0) {
#pragma unroll
      for (int e = 0; e < 8; ++e) {
        vAw[lg4 * 8 + e] = hIa[e];
        vAw[32 + lg4 * 8 + e] = hIa[8 + e];
      }
    }
    wave_fence();
    hvecbuf[(long)idx * 64 + lane] = vAw[lane];
  }
#undef B1F
#undef B2F
}

// ---------------------------------------------------------------------------
// K6: fused hI2 + final: hIbuf[inst] = relu([u ; relu(hvec@W2+b2)] @ W3 + b3).
// 32 rows / block, two stages, W buffer reloaded between stages.
// ---------------------------------------------------------------------------
__global__ __launch_bounds__(256, 2)
void hI2final_kernel(const float* __restrict__ hvecbuf,
                     const float* __restrict__ user_w,
                     const float* __restrict__ W2w, const float* __restrict__ W2b,
                     const float* __restrict__ W3w, const float* __restrict__ W3b,
                     const int* __restrict__ list, const int* __restrict__ aUid,
                     const int* __restrict__ nActp, float* __restrict__ hIbuf) {
  const int tid = threadIdx.x, lane = tid & 63, w = tid >> 6;
  const int i0 = blockIdx.x * 32;
  const int nA = nActp[0];
  if (i0 >= nA) return;
  __shared__ float sW[128][64];   // 32KB: W2 (rows 0..63) then W3 (0..127)
  __shared__ float sX[32][128];   // cols 0:64 = u, 64:128 = hvec then hI2
  __shared__ float sb[64];
  __shared__ int sUid[32], sInst[32];
  for (int i = tid; i < 4096; i += 256) sW[i >> 6][i & 63] = W2w[i];
  if (tid < 64) sb[tid] = W2b[tid];
  if (tid < 32) {
    bool ok = (i0 + tid) < nA;
    sUid[tid] = ok ? aUid[i0 + tid] : 0;
    sInst[tid] = ok ? list[i0 + tid] : 0;
  }
  __syncthreads();
  for (int i = tid; i < 2048; i += 256) {
    int r = i >> 6, c = i & 63;
    sX[r][64 + c] = (i0 + r < nA) ? hvecbuf[(long)(i0 + r) * 64 + c] : 0.0f;
    sX[r][c] = user_w[(long)sUid[r] * 64 + c];
  }
  __syncthreads();

  float acc[8];
  // stage A: hI2 = relu(hvec @ W2 + b2) -> sX[r][64:]
  {
    const float bv = sb[lane];
#pragma unroll
    for (int r = 0; r < 8; ++r) acc[r] = bv;
    for (int k = 0; k < 64; k += 4) {
      float wv0 = sW[k][lane], wv1 = sW[k + 1][lane];
      float wv2 = sW[k + 2][lane], wv3 = sW[k + 3][lane];
#pragma unroll
      for (int r = 0; r < 8; ++r) {
        const float4 xv = *(const float4*)(&sX[w * 8 + r][64 + k]);
        acc[r] = fmaf(xv.x, wv0, acc[r]);
        acc[r] = fmaf(xv.y, wv1, acc[r]);
        acc[r] = fmaf(xv.z, wv2, acc[r]);
        acc[r] = fmaf(xv.w, wv3, acc[r]);
      }
    }
#pragma unroll
    for (int r = 0; r < 8; ++r) sX[w * 8 + r][64 + lane] = fmaxf(acc[r], 0.0f);
  }
  __syncthreads();
  for (int i = tid; i < 8192; i += 256) sW[i >> 6][i & 63] = W3w[i];
  if (tid < 64) sb[tid] = W3b[tid];
  __syncthreads();

  // stage B: out = relu([u ; hI2] @ W3 + b3)
  {
    const float bv = sb[lane];
#pragma unroll
    for (int r = 0; r < 8; ++r) acc[r] = bv;
    for (int k = 0; k < 128; k += 4) {
      float wv0 = sW[k][lane], wv1 = sW[k + 1][lane];
      float wv2 = sW[k + 2][lane], wv3 = sW[k + 3][lane];
#pragma unroll
      for (int r = 0; r < 8; ++r) {
        const float4 xv = *(const float4*)(&sX[w * 8 + r][k]);
        acc[r] = fmaf(xv.x, wv0, acc[r]);
        acc[r] = fmaf(xv.y, wv1, acc[r]);
        acc[r] = fmaf(xv.z, wv2, acc[r]);
        acc[r] = fmaf(xv.w, wv3, acc[r]);
      }
    }
#pragma unroll
    for (int r = 0; r < 8; ++r) {
      int row = i0 + w * 8 + r;
      if (row < nA)
        hIbuf[(long)sInst[w * 8 + r] * 64 + lane] = fmaxf(acc[r], 0.0f);
    }
  }
}

// ---------------------------------------------------------------------------
// K7: fully fused social phase — one wave per batch element b.
// ---------------------------------------------------------------------------
__global__ __launch_bounds__(256, 8)
void social_fused_kernel(const float* __restrict__ hIbuf,
                         const float* __restrict__ user_w,
                         const float* __restrict__ S1w,   // s_att1_w [128][64]
                         const float* __restrict__ S1b,
                         const short* __restrict__ S1img,
                         const short* __restrict__ S2img,
                         const float* __restrict__ S2b,
                         const float* __restrict__ S3w,
                         const float* __restrict__ L1w, const float* __restrict__ L1b,
                         const float* __restrict__ L2w, const float* __restrict__ L2b,
                         const float* __restrict__ L3w, const float* __restrict__ L3b,
                         const int* __restrict__ nodes,
                         const void* __restrict__ social_mask,
                         const int* __restrict__ flagp,
                         float* __restrict__ out) {
  __shared__ __align__(16) short sB1[4096], sB2[4096];   // 16KB images
  __shared__ __align__(16) char smem[4][3584];           // 14KB wave scratch
  const int tid = threadIdx.x, lane = tid & 63, w = tid >> 6;
  short* h1w = (short*)(smem[w]);          // [16][80] bf16
  float* lgw = (float*)(smem[w] + 2560);   // [32] logits
  int* cw = (int*)(smem[w] + 2816);        // [32] neighbor slots
  float* vA = (float*)(smem[w] + 3072);    // [64]
  float* vB = (float*)(smem[w] + 3328);    // [64]

  for (int i = tid; i < 512; i += 256) {
    ((int4*)sB1)[i] = ((const int4*)S1img)[i];
    ((int4*)sB2)[i] = ((const int4*)S2img)[i];
  }
  __syncthreads();

  const int mode = flagp[0];
  const int l15 = lane & 15;
  const int lg4 = lane >> 4;
  const int b = blockIdx.x * 4 + w;        // grid 128*4 = 512 exactly
  const long uid = nodes[b];

  bool m = (lane < LSS) ? mread(social_mask, uid * LSS + lane, mode) : false;
  unsigned long long bal = __ballot(m);
  const int nval = (int)__popcll(bal);
  int pos = (int)__popcll(bal & ((1ull << lane) - 1ull));
  if (m) cw[pos] = lane;

  // inline uA1S = u @ S1w[64:128] + S1b  (weights L1/L2-hot across waves)
  const float uv = user_w[uid * 64 + lane];
  float uA1v = S1b[lane];
#pragma unroll 8
  for (int k = 0; k < 64; ++k)
    uA1v = fmaf(__shfl(uv, k), S1w[(64 + k) * 64 + lane], uA1v);
  const float a2bv = S2b[lane];
  const float a3v = S3w[lane];
  wave_fence();

  const long hbase = 512L + (long)b * 32;
  const int ng = (nval + 15) >> 4;
  for (int mc = 0; mc < ng; ++mc) {
    wave_fence();
    int row = mc * 16 + l15;
    if (row >= nval) row = nval - 1;
    const long hrow = hbase + cw[row];
    short8 xa[2];
#pragma unroll
    for (int kb = 0; kb < 2; ++kb) {
      const float* xp = hIbuf + hrow * 64 + kb * 32 + lg4 * 8;
      const float4 a = *(const float4*)xp;
      const float4 bb = *(const float4*)(xp + 4);
      short8 f;
      f[0] = bf16rne(a.x);  f[1] = bf16rne(a.y);
      f[2] = bf16rne(a.z);  f[3] = bf16rne(a.w);
      f[4] = bf16rne(bb.x); f[5] = bf16rne(bb.y);
      f[6] = bf16rne(bb.z); f[7] = bf16rne(bb.w);
      xa[kb] = f;
    }
#pragma unroll
    for (int nb = 0; nb < 4; ++nb) {
      const float ui = __shfl(uA1v, nb * 16 + l15);
      f32x4 acc = {ui, ui, ui, ui};
      acc = __builtin_amdgcn_mfma_f32_16x16x32_bf16(
          xa[0], *(const short8*)(sB1 + ((0 * 4 + nb) * 64 + lane) * 8), acc, 0, 0, 0);
      acc = __builtin_amdgcn_mfma_f32_16x16x32_bf16(
          xa[1], *(const short8*)(sB1 + ((1 * 4 + nb) * 64 + lane) * 8), acc, 0, 0, 0);
#pragma unroll
      for (int r = 0; r < 4; ++r)
        h1w[(lg4 * 4 + r) * 80 + nb * 16 + l15] = bf16rne(fmaxf(acc[r], 0.0f));
    }
    wave_fence();
    short8 ha[2];
    ha[0] = *(const short8*)(h1w + l15 * 80 + lg4 * 8);
    ha[1] = *(const short8*)(h1w + l15 * 80 + 32 + lg4 * 8);
    float t0 = 0.0f, t1 = 0.0f, t2 = 0.0f, t3 = 0.0f;
#pragma unroll
    for (int nb = 0; nb < 4; ++nb) {
      const float b2 = __shfl(a2bv, nb * 16 + l15);
      f32x4 acc = {b2, b2, b2, b2};
      acc = __builtin_amdgcn_mfma_f32_16x16x32_bf16(
          ha[0], *(const short8*)(sB2 + ((0 * 4 + nb) * 64 + lane) * 8), acc, 0, 0, 0);
      acc = __builtin_amdgcn_mfma_f32_16x16x32_bf16(
          ha[1], *(const short8*)(sB2 + ((1 * 4 + nb) * 64 + lane) * 8), acc, 0, 0, 0);
      const float a3c = __shfl(a3v, nb * 16 + l15);
      t0 = fmaf(fmaxf(acc[0], 0.0f), a3c, t0);
      t1 = fmaf(fmaxf(acc[1], 0.0f), a3c, t1);
      t2 = fmaf(fmaxf(acc[2], 0.0f), a3c, t2);
      t3 = fmaf(fmaxf(acc[3], 0.0f), a3c, t3);
    }
    t0 = rsum16(t0); t1 = rsum16(t1); t2 = rsum16(t2); t3 = rsum16(t3);
    if (l15 == 0) {
      const int jb = mc * 16 + lg4 * 4;
      lgw[jb + 0] = t0;
      lgw[jb + 1] = t1;
      lgw[jb + 2] = t2;
      lgw[jb + 3] = t3;
    }
  }
  wave_fence();

  const bool valid = (lane < nval);
  float lv = valid ? lgw[lane] : -1e30f;
  float mx = wmax(lv);
  float e = valid ? __expf(lv - mx) : 0.0f;
  float s = wsum(e);
  const float beta = e / s;

  float hs = 0.0f;
  for (int j = 0; j < nval; ++j) {
    const float bj = __shfl(beta, j);
    hs = fmaf(bj, hIbuf[(hbase + cw[j]) * 64 + lane], hs);
  }

  // ---- tail: vecB = relu(hS@L1+b1); f = relu([self;vecB]@L2+b2);
  //            out = relu(f@L3+b3)  — per-wave matvecs, LDS broadcasts.
  vA[lane] = hs;
  wave_fence();
  float acc = L1b[lane];
#pragma unroll 8
  for (int k = 0; k < 64; ++k) acc = fmaf(vA[k], L1w[k * 64 + lane], acc);
  const float vecB = fmaxf(acc, 0.0f);
  const float selfv = hIbuf[(long)b * 64 + lane];
  wave_fence();
  vA[lane] = selfv;
  vB[lane] = vecB;
  wave_fence();
  acc = L2b[lane];
#pragma unroll 8
  for (int k = 0; k < 64; ++k) acc = fmaf(vA[k], L2w[k * 64 + lane], acc);
#pragma unroll 8
  for (int k = 0; k < 64; ++k) acc = fmaf(vB[k], L2w[(64 + k) * 64 + lane], acc);
  const float fv = fmaxf(acc, 0.0f);
  wave_fence();
  vA[lane] = fv;
  wave_fence();
  acc = L3b[lane];
#pragma unroll 8
  for (int k = 0; k < 64; ++k) acc = fmaf(vA[k], L3w[k * 64 + lane], acc);
  out[(long)b * 64 + lane] = fmaxf(acc, 0.0f);
}

// ---------------------------------------------------------------------------
extern "C" void kernel_launch(void* const* d_in, const int* in_sizes, int n_in,
                              void* d_out, int out_size, void* d_ws, size_t ws_size,
                              hipStream_t stream) {
  const float* user_w   = (const float*)d_in[0];
  const float* item_w   = (const float*)d_in[1];
  const float* rating_w = (const float*)d_in[2];
  const float* i_ln1_w  = (const float*)d_in[3];
  const float* i_ln1_b  = (const float*)d_in[4];
  const float* i_ln2_w  = (const float*)d_in[5];
  const float* i_ln2_b  = (const float*)d_in[6];
  const float* i_ln3_w  = (const float*)d_in[7];
  const float* i_ln3_b  = (const float*)d_in[8];
  const float* i_att1_w = (const float*)d_in[9];
  const float* i_att1_b = (const float*)d_in[10];
  const float* i_att2_w = (const float*)d_in[11];
  const float* i_att2_b = (const float*)d_in[12];
  const float* i_att3_w = (const float*)d_in[13];
  const float* i_att3_b = (const float*)d_in[14];
  const float* s_ln1_w  = (const float*)d_in[15];
  const float* s_ln1_b  = (const float*)d_in[16];
  const float* s_ln2_w  = (const float*)d_in[17];
  const float* s_ln2_b  = (const float*)d_in[18];
  const float* s_ln3_w  = (const float*)d_in[19];
  const float* s_ln3_b  = (const float*)d_in[20];
  const float* s_att1_w = (const float*)d_in[21];
  const float* s_att1_b = (const float*)d_in[22];
  const float* s_att2_w = (const float*)d_in[23];
  const float* s_att2_b = (const float*)d_in[24];
  const float* s_att3_w = (const float*)d_in[25];
  const float* s_att3_b = (const float*)d_in[26];
  const int*  nodes       = (const int*)d_in[27];
  const int*  social_hist = (const int*)d_in[28];
  const void* social_mask = d_in[29];
  const int*  item_hist   = (const int*)d_in[30];
  const int*  rating_hist = (const int*)d_in[31];
  const void* item_mask   = d_in[32];

  // workspace layout (bytes) — total 21,604,096 (proven cap; do not exceed).
  char* ws = (char*)d_ws;
  int*   flag    = (int*)(ws + 0);          // 256
  int*   counter = (int*)(ws + 256);        // 256
  int*   list    = (int*)(ws + 512);        // NT*4 = 67584
  int*   aUid    = (int*)(ws + 68096);      // 67584
  float* uA1buf  = (float*)(ws + 135680);   // NT*64*4 = 4325376
  float* hvecbuf = (float*)(ws + 4461056);  // 4325376
  float* hIbuf   = hvecbuf;                 // alias: hvec dead before K6 write
  short* W1hi    = (short*)(ws + 4461056);  // 8192  (alias hvecbuf[0:2048])
  short* W1lo    = (short*)(ws + 4469248);  // 8192  (alias hvecbuf[2048:4096])
  float* xbase   = (float*)(ws + 8786432);  // 50000*64*4 = 12800000
  short* S1img   = (short*)(ws + 8786432);  // 8192  (alias xbase, after core)
  short* S2img   = (short*)(ws + 8794624);  // 8192  (alias xbase, after core)
  float* RW1g    = (float*)(ws + 21586432); // 1280
  short* Bimg1   = (short*)(ws + 21587712); // 8192
  short* Bimg2   = (short*)(ws + 21595904); // 8192

  hipMemsetAsync(counter, 0, 4, stream);
  setup_kernel<<<3, 256, 0, stream>>>((const unsigned int*)social_mask, flag,
                                      rating_w, i_ln1_w, i_ln1_b, RW1g,
                                      i_att1_w, i_att2_w, Bimg1, Bimg2, W1hi, W1lo);
  pre_xbase_mfma_kernel<<<512, 256, 0, stream>>>(item_w, W1hi, W1lo, xbase);
  build_active_kernel<<<NT / 256, 256, 0, stream>>>(
      nodes, social_hist, social_mask, flag, counter, list, aUid);
  uA1_kernel<<<NT / 64, 256, 0, stream>>>(user_w, i_att1_w, i_att1_b,
                                          aUid, counter, uA1buf);
  core_mfma_kernel<<<NT / 16, 512, 0, stream>>>(
      xbase, RW1g, uA1buf, Bimg1, Bimg2, i_att2_b, i_att3_w,
      item_hist, rating_hist, item_mask, flag, aUid, counter, hvecbuf);
  prepack2_kernel<<<1, 256, 0, stream>>>(s_att1_w, s_att2_w, S1img, S2img);
  hI2final_kernel<<<NT / 32, 256, 0, stream>>>(
      hvecbuf, user_w, i_ln2_w, i_ln2_b, i_ln3_w, i_ln3_b,
      list, aUid, counter, hIbuf);
  social_fused_kernel<<<BB / 4, 256, 0, stream>>>(
      hIbuf, user_w, s_att1_w, s_att1_b, S1img, S2img, s_att2_b, s_att3_w,
      s_ln1_w, s_ln1_b, s_ln2_w, s_ln2_b, s_ln3_w, s_ln3_b,
      nodes, social_mask, flag, (float*)d_out);
}